// Round 1
// baseline (2682.413 us; speedup 1.0000x reference)
//
#include <hip/hip_runtime.h>
#include <math.h>

// ---------------------------------------------------------------------------
// fp32 implementation of the hetero-GAT forward pass.
// Key structure:
//  - ed/es computed as x @ (W @ a) per head  -> skips the entire Wd GEMM.
//  - CSR (built on device per call) for atomic-free segment softmax+aggregate.
//  - GAT aggregation fuses softmax normalization, +bias, relu, head-mean.
// ---------------------------------------------------------------------------

// ---------------- GEMM: C = A(NxK) @ B(KxJ) [+ bias + emb[ids] ] ----------
// 128x128 block tile, BK=32, 256 threads, 8x8 per thread.
template<bool BIAS_EMB>
__global__ __launch_bounds__(256) void gemm128(
    const float* __restrict__ A, int lda,
    const float* __restrict__ B, int ldb,
    const float* __restrict__ bias,
    const float* __restrict__ emb,
    const int* __restrict__ ids,
    float* __restrict__ C, int ldc,
    int N, int K)
{
    __shared__ float As[128][33];
    __shared__ float Bs[32][128];
    const int tid = threadIdx.x;
    const int rowbase = blockIdx.x * 128;
    const int colbase = blockIdx.y * 128;
    const int rg = tid >> 4;   // 0..15
    const int cg = tid & 15;   // 0..15

    float acc[8][8];
#pragma unroll
    for (int r = 0; r < 8; ++r)
#pragma unroll
        for (int c = 0; c < 8; ++c) acc[r][c] = 0.f;

    for (int k0 = 0; k0 < K; k0 += 32) {
#pragma unroll
        for (int i = 0; i < 16; ++i) {
            int slot = tid + i * 256;       // 0..4095
            int r = slot >> 5, k = slot & 31;
            int row = rowbase + r, kk = k0 + k;
            As[r][k] = (row < N && kk < K) ? A[(size_t)row * lda + kk] : 0.f;
        }
#pragma unroll
        for (int i = 0; i < 4; ++i) {
            int slot = tid + i * 256;       // 0..1023 float4 slots
            int k = slot >> 5, c4 = slot & 31;
            int kk = k0 + k;
            float4 v = make_float4(0.f, 0.f, 0.f, 0.f);
            if (kk < K) v = *reinterpret_cast<const float4*>(&B[(size_t)kk * ldb + colbase + c4 * 4]);
            *reinterpret_cast<float4*>(&Bs[k][c4 * 4]) = v;
        }
        __syncthreads();
#pragma unroll
        for (int kk = 0; kk < 32; ++kk) {
            float a[8];
#pragma unroll
            for (int r = 0; r < 8; ++r) a[r] = As[rg * 8 + r][kk];
            float4 b0 = *reinterpret_cast<const float4*>(&Bs[kk][cg * 8]);
            float4 b1 = *reinterpret_cast<const float4*>(&Bs[kk][cg * 8 + 4]);
            float b[8] = {b0.x, b0.y, b0.z, b0.w, b1.x, b1.y, b1.z, b1.w};
#pragma unroll
            for (int r = 0; r < 8; ++r)
#pragma unroll
                for (int c = 0; c < 8; ++c)
                    acc[r][c] = fmaf(a[r], b[c], acc[r][c]);
        }
        __syncthreads();
    }

#pragma unroll
    for (int r = 0; r < 8; ++r) {
        int row = rowbase + rg * 8 + r;
        if (row >= N) continue;
        const float* ep = nullptr;
        if (BIAS_EMB) ep = emb + (size_t)ids[row] * 128;  // only used when J==128
#pragma unroll
        for (int c = 0; c < 8; ++c) {
            int col = colbase + cg * 8 + c;
            float v = acc[r][c];
            if (BIAS_EMB) v += bias[col] + ep[col];
            C[(size_t)row * ldc + col] = v;
        }
    }
}

// ---------------- U = [Ws @ a_s | Wd @ a_d] per head: (128 x 8) per GAT ----
struct UParams {
    const float* Ws[6];
    const float* Wd[6];
    const float* as_[6];
    const float* ad_[6];
    int C[6];
};

__global__ void compute_U(UParams P, float* __restrict__ U)
{
    int g = blockIdx.x;
    int C = P.C[g];
    int HC = 4 * C;
    for (int o = threadIdx.x; o < 1024; o += 256) {
        int k = o >> 3, j = o & 7;
        int h = j & 3;
        const float* W = (j < 4) ? P.Ws[g] : P.Wd[g];
        const float* a = (j < 4) ? P.as_[g] : P.ad_[g];
        float s = 0.f;
        for (int c = 0; c < C; ++c)
            s = fmaf(W[k * HC + h * C + c], a[h * C + c], s);
        U[g * 1024 + k * 8 + j] = s;
    }
}

// ---------------- es = Xs @ U[:,0:4], ed = Xd @ U[:,4:8] ------------------
__global__ void es_ed_kernel(const float* __restrict__ Xs, const float* __restrict__ Xd,
                             const float* __restrict__ U,
                             float* __restrict__ es, float* __restrict__ ed, int N)
{
    int t = blockIdx.x * blockDim.x + threadIdx.x;
    if (t >= N * 8) return;
    int n = t >> 3, j = t & 7;
    const float4* X4 = reinterpret_cast<const float4*>(((j < 4) ? Xs : Xd) + (size_t)n * 128);
    float s = 0.f;
#pragma unroll 8
    for (int k4 = 0; k4 < 32; ++k4) {
        float4 x = X4[k4];
        s = fmaf(x.x, U[(k4 * 4 + 0) * 8 + j], s);
        s = fmaf(x.y, U[(k4 * 4 + 1) * 8 + j], s);
        s = fmaf(x.z, U[(k4 * 4 + 2) * 8 + j], s);
        s = fmaf(x.w, U[(k4 * 4 + 3) * 8 + j], s);
    }
    if (j < 4) es[n * 4 + j] = s;
    else       ed[n * 4 + (j - 4)] = s;
}

// ---------------- CSR build ------------------------------------------------
__global__ void deg_kernel(const int* __restrict__ s, const int* __restrict__ t,
                           int* __restrict__ deg_t, int* __restrict__ deg_s, int E)
{
    int i = blockIdx.x * blockDim.x + threadIdx.x;
    if (i >= E) return;
    atomicAdd(&deg_t[t[i]], 1);
    atomicAdd(&deg_s[s[i]], 1);
}

__global__ void scan_partial(const int* dA, const int* dB, int* eA, int* eB,
                             int* bsA, int* bsB, int N)
{
    __shared__ int lds[256];
    const int* deg = blockIdx.y ? dB : dA;
    int* ex = blockIdx.y ? eB : eA;
    int* bs = blockIdx.y ? bsB : bsA;
    int i = blockIdx.x * 256 + threadIdx.x;
    int v = (i < N) ? deg[i] : 0;
    int x = v;
    lds[threadIdx.x] = x;
    __syncthreads();
    for (int off = 1; off < 256; off <<= 1) {
        int tv = (threadIdx.x >= off) ? lds[threadIdx.x - off] : 0;
        __syncthreads();
        x += tv;
        lds[threadIdx.x] = x;
        __syncthreads();
    }
    if (i < N) ex[i] = x - v;                 // block-local exclusive
    if (threadIdx.x == 255) bs[blockIdx.x] = x;  // block total
}

__global__ void scan_bsums(int* bsA, int* bsB, int* boA, int* boB, int nb)
{
    __shared__ int lds[256];
    int* bs = blockIdx.y ? bsB : bsA;
    int* bo = blockIdx.y ? boB : boA;
    int v = (threadIdx.x < nb) ? bs[threadIdx.x] : 0;
    int x = v;
    lds[threadIdx.x] = x;
    __syncthreads();
    for (int off = 1; off < 256; off <<= 1) {
        int tv = (threadIdx.x >= off) ? lds[threadIdx.x - off] : 0;
        __syncthreads();
        x += tv;
        lds[threadIdx.x] = x;
        __syncthreads();
    }
    if (threadIdx.x < nb) bo[threadIdx.x] = x - v;
    if (threadIdx.x == 255) bo[nb] = x;       // grand total
}

__global__ void scan_add(int* eA, int* eB, const int* boA, const int* boB, int N, int nb)
{
    int* ex = blockIdx.y ? eB : eA;
    const int* bo = blockIdx.y ? boB : boA;
    int i = blockIdx.x * 256 + threadIdx.x;
    if (i < N) ex[i] += bo[i >> 8];
    if (i == 0) ex[N] = bo[nb];
}

__global__ void fill_kernel(const int* __restrict__ s, const int* __restrict__ t,
                            const int* __restrict__ rpt_t, const int* __restrict__ rpt_s,
                            int* __restrict__ cur_t, int* __restrict__ cur_s,
                            int* __restrict__ eid_t, int* __restrict__ eid_s, int E)
{
    int i = blockIdx.x * blockDim.x + threadIdx.x;
    if (i >= E) return;
    int d = t[i];
    int p = atomicAdd(&cur_t[d], 1);
    eid_t[rpt_t[d] + p] = i;
    d = s[i];
    p = atomicAdd(&cur_s[d], 1);
    eid_s[rpt_s[d] + p] = i;
}

// ---------------- GAT aggregation + fused (/den, +bias, relu, head-mean) --
// One 64-lane wave per dst node. HC = 512 (C=128) or 128 (C=32).
template<int HC>
__global__ __launch_bounds__(256) void gat_agg(
    const int* __restrict__ rowptr, const int* __restrict__ eids,
    const int* __restrict__ srcid,
    const float* __restrict__ hs,     // Nsrc x HC
    const float* __restrict__ es,     // Nsrc x 4
    const float* __restrict__ edv,    // Ndst x 4
    const float* __restrict__ bias,   // HC
    float* __restrict__ out,          // Ndst x HC/4
    int Ndst)
{
    constexpr int R = HC / 64;
    int n = blockIdx.x * 4 + (threadIdx.x >> 6);
    if (n >= Ndst) return;
    int lane = threadIdx.x & 63;
    int beg = rowptr[n], end = rowptr[n + 1];
    const float4 ed4 = *reinterpret_cast<const float4*>(&edv[(size_t)n * 4]);

    float m0 = -1e30f, m1 = -1e30f, m2 = -1e30f, m3 = -1e30f;
    for (int i = beg; i < end; ++i) {
        int e = eids[i];
        int sn = srcid[e];
        float4 e4 = *reinterpret_cast<const float4*>(&es[(size_t)sn * 4]);
        float v0 = e4.x + ed4.x; v0 = v0 > 0.f ? v0 : 0.2f * v0;
        float v1 = e4.y + ed4.y; v1 = v1 > 0.f ? v1 : 0.2f * v1;
        float v2 = e4.z + ed4.z; v2 = v2 > 0.f ? v2 : 0.2f * v2;
        float v3 = e4.w + ed4.w; v3 = v3 > 0.f ? v3 : 0.2f * v3;
        m0 = fmaxf(m0, v0); m1 = fmaxf(m1, v1);
        m2 = fmaxf(m2, v2); m3 = fmaxf(m3, v3);
    }

    float den0 = 0.f, den1 = 0.f, den2 = 0.f, den3 = 0.f;
    float acc[R];
#pragma unroll
    for (int r = 0; r < R; ++r) acc[r] = 0.f;

    for (int i = beg; i < end; ++i) {
        int e = eids[i];
        int sn = srcid[e];
        float4 e4 = *reinterpret_cast<const float4*>(&es[(size_t)sn * 4]);
        float v0 = e4.x + ed4.x; v0 = v0 > 0.f ? v0 : 0.2f * v0;
        float v1 = e4.y + ed4.y; v1 = v1 > 0.f ? v1 : 0.2f * v1;
        float v2 = e4.z + ed4.z; v2 = v2 > 0.f ? v2 : 0.2f * v2;
        float v3 = e4.w + ed4.w; v3 = v3 > 0.f ? v3 : 0.2f * v3;
        float w0 = expf(v0 - m0); den0 += w0;
        float w1 = expf(v1 - m1); den1 += w1;
        float w2 = expf(v2 - m2); den2 += w2;
        float w3 = expf(v3 - m3); den3 += w3;
        const float* hp = hs + (size_t)sn * HC;
#pragma unroll
        for (int r = 0; r < R; ++r) {
            float w;
            if (HC == 512) {
                w = (r < 2) ? w0 : (r < 4) ? w1 : (r < 6) ? w2 : w3;
            } else {
                w = (r == 0) ? (lane < 32 ? w0 : w1) : (lane < 32 ? w2 : w3);
            }
            acc[r] = fmaf(w, hp[r * 64 + lane], acc[r]);
        }
    }

    den0 += 1e-16f; den1 += 1e-16f; den2 += 1e-16f; den3 += 1e-16f;

    if (HC == 512) {
        // col = r*64+lane, head h = r>>1, in-head channel c = (r&1)*64+lane
        float o0 = 0.f, o1 = 0.f;
#pragma unroll
        for (int r = 0; r < R; ++r) {
            float d = (r < 2) ? den0 : (r < 4) ? den1 : (r < 6) ? den2 : den3;
            float v = acc[r] / d + bias[r * 64 + lane];
            v = fmaxf(v, 0.f);
            if (r & 1) o1 += v; else o0 += v;
        }
        out[(size_t)n * 128 + lane] = 0.25f * o0;
        out[(size_t)n * 128 + 64 + lane] = 0.25f * o1;
    } else {
        // col = r*64+lane, head h = 2r + (lane>=32), channel c = lane&31
        float d0 = lane < 32 ? den0 : den1;
        float d1 = lane < 32 ? den2 : den3;
        float v0 = fmaxf(acc[0] / d0 + bias[lane], 0.f);
        float v1 = fmaxf(acc[1] / d1 + bias[64 + lane], 0.f);
        float sum = v0 + __shfl_xor(v0, 32, 64) + v1 + __shfl_xor(v1, 32, 64);
        if (lane < 32) out[(size_t)n * 32 + lane] = 0.25f * sum;
    }
}

// ---------------- penalty: x *= exp(x @ W + b), x is (N,32) ---------------
__global__ void penalty_kernel(float* __restrict__ xd, float* __restrict__ xl,
                               const float* __restrict__ Wd, const float* __restrict__ bd,
                               const float* __restrict__ Wl, const float* __restrict__ bl,
                               int N)
{
    int t = blockIdx.x * blockDim.x + threadIdx.x;
    if (t >= 2 * N * 32) return;
    int n = t >> 5, c = t & 31;
    float* x;
    const float* W;
    float b;
    if (n < N) { x = xd + (size_t)n * 32; W = Wd; b = bd[0]; }
    else       { x = xl + (size_t)(n - N) * 32; W = Wl; b = bl[0]; }
    float v = x[c];
    float p = v * W[c];
    p += __shfl_xor(p, 16, 32);
    p += __shfl_xor(p, 8, 32);
    p += __shfl_xor(p, 4, 32);
    p += __shfl_xor(p, 2, 32);
    p += __shfl_xor(p, 1, 32);
    x[c] = v * expf(p + b);
}

// ---------------- link classifier: one wave per label edge ----------------
__global__ __launch_bounds__(256) void classifier_kernel(
    const float* __restrict__ xd, const float* __restrict__ xl,
    const int* __restrict__ eli,   // 2 x EL
    const float* __restrict__ fc1W, const float* __restrict__ fc1b,
    const float* __restrict__ fc2W, const float* __restrict__ fc2b,
    float* __restrict__ out, int EL)
{
    int wid = (blockIdx.x * 256 + threadIdx.x) >> 6;
    int lane = threadIdx.x & 63;
    if (wid >= EL) return;
    float ef;
    if (lane < 32) {
        int i0 = eli[wid];
        ef = xd[(size_t)i0 * 32 + lane];
    } else {
        int i1 = eli[EL + wid];
        ef = xl[(size_t)i1 * 32 + (lane - 32)];
    }
    float acc = fc1b[lane];
#pragma unroll
    for (int k = 0; k < 64; ++k) {
        float v = __shfl(ef, k, 64);
        acc = fmaf(v, fc1W[k * 64 + lane], acc);
    }
    acc = fmaxf(acc, 0.f);
    float p = acc * fc2W[lane];
#pragma unroll
    for (int off = 32; off >= 1; off >>= 1) p += __shfl_xor(p, off, 64);
    if (lane == 0) out[wid] = p + fc2b[0];
}

// ---------------------------------------------------------------------------
extern "C" void kernel_launch(void* const* d_in, const int* in_sizes, int n_in,
                              void* d_out, int out_size, void* d_ws, size_t ws_size,
                              hipStream_t stream)
{
    const int N  = in_sizes[6] / 128;   // emb_d is (N,128)
    const int Kd = in_sizes[2] / 128;   // 412
    const int Kl = in_sizes[4] / 128;   // 240
    const int E  = in_sizes[48] / 2;
    const int EL = in_sizes[49] / 2;

    const float* x_d    = (const float*)d_in[0];
    const float* x_l    = (const float*)d_in[1];
    const float* Wd_lin = (const float*)d_in[2];
    const float* bd_lin = (const float*)d_in[3];
    const float* Wl_lin = (const float*)d_in[4];
    const float* bl_lin = (const float*)d_in[5];
    const float* emb_d  = (const float*)d_in[6];
    const float* emb_l  = (const float*)d_in[7];

    const float *gWs[6], *gWd[6], *gas[6], *gad[6], *gb[6];
    for (int g = 0; g < 6; ++g) {
        gWs[g] = (const float*)d_in[8 + 5 * g + 0];
        gWd[g] = (const float*)d_in[8 + 5 * g + 1];
        gas[g] = (const float*)d_in[8 + 5 * g + 2];
        gad[g] = (const float*)d_in[8 + 5 * g + 3];
        gb[g]  = (const float*)d_in[8 + 5 * g + 4];
    }
    const float* pen_Wd = (const float*)d_in[38];
    const float* pen_bd = (const float*)d_in[39];
    const float* pen_Wl = (const float*)d_in[40];
    const float* pen_bl = (const float*)d_in[41];
    const float* fc1W   = (const float*)d_in[42];
    const float* fc1b   = (const float*)d_in[43];
    const float* fc2W   = (const float*)d_in[44];
    const float* fc2b   = (const float*)d_in[45];
    const int* node_id_d = (const int*)d_in[46];
    const int* node_id_l = (const int*)d_in[47];
    const int* ei  = (const int*)d_in[48];
    const int* eli = (const int*)d_in[49];
    const int* s_arr = ei;        // edge_index[0]  (disease side)
    const int* t_arr = ei + E;    // edge_index[1]  (lncrna side)

    // ---- workspace carve-up (~210 MB) ----
    char* ws = (char*)d_ws;
    size_t off = 0;
    auto alloc = [&](size_t bytes) -> char* {
        char* p = ws + off;
        off = (off + bytes + 255) & ~(size_t)255;
        return p;
    };
    float* bufd0 = (float*)alloc((size_t)N * 128 * 4);
    float* bufd1 = (float*)alloc((size_t)N * 128 * 4);
    float* bufl0 = (float*)alloc((size_t)N * 128 * 4);
    float* bufl1 = (float*)alloc((size_t)N * 128 * 4);
    float* hs    = (float*)alloc((size_t)N * 512 * 4);
    float* esb   = (float*)alloc((size_t)N * 4 * 4);
    float* edb   = (float*)alloc((size_t)N * 4 * 4);
    float* Uall  = (float*)alloc((size_t)6 * 1024 * 4);
    int* rpt_t = (int*)alloc((size_t)(N + 1) * 4);
    int* rpt_s = (int*)alloc((size_t)(N + 1) * 4);
    int* deg_t = (int*)alloc((size_t)N * 4);
    int* deg_s = (int*)alloc((size_t)N * 4);
    int* cur_t = (int*)alloc((size_t)N * 4);
    int* cur_s = (int*)alloc((size_t)N * 4);
    int* eid_t = (int*)alloc((size_t)E * 4);
    int* eid_s = (int*)alloc((size_t)E * 4);
    int* bs_t  = (int*)alloc(256 * 4);
    int* bs_s  = (int*)alloc(256 * 4);
    int* bo_t  = (int*)alloc(257 * 4);
    int* bo_s  = (int*)alloc(257 * 4);
    (void)ws_size;

    hipMemsetAsync(deg_t, 0, (size_t)N * 4, stream);
    hipMemsetAsync(deg_s, 0, (size_t)N * 4, stream);
    hipMemsetAsync(cur_t, 0, (size_t)N * 4, stream);
    hipMemsetAsync(cur_s, 0, (size_t)N * 4, stream);

    dim3 blk(256);

    // input linears (+bias +embedding gather)
    {
        dim3 grid((N + 127) / 128, 1);
        gemm128<true><<<grid, blk, 0, stream>>>(x_d, Kd, Wd_lin, 128, bd_lin, emb_d,
                                                node_id_d, bufd0, 128, N, Kd);
        gemm128<true><<<grid, blk, 0, stream>>>(x_l, Kl, Wl_lin, 128, bl_lin, emb_l,
                                                node_id_l, bufl0, 128, N, Kl);
    }

    // attention projection vectors for all 6 GATs
    {
        UParams up;
        for (int g = 0; g < 6; ++g) {
            up.Ws[g] = gWs[g]; up.Wd[g] = gWd[g];
            up.as_[g] = gas[g]; up.ad_[g] = gad[g];
            up.C[g] = (g < 4) ? 128 : 32;
        }
        compute_U<<<dim3(6), blk, 0, stream>>>(up, Uall);
    }

    // CSR for both directions
    {
        deg_kernel<<<dim3((E + 255) / 256), blk, 0, stream>>>(s_arr, t_arr, deg_t, deg_s, E);
        int nb = (N + 255) / 256;
        scan_partial<<<dim3(nb, 2), blk, 0, stream>>>(deg_t, deg_s, rpt_t, rpt_s, bs_t, bs_s, N);
        scan_bsums<<<dim3(1, 2), blk, 0, stream>>>(bs_t, bs_s, bo_t, bo_s, nb);
        scan_add<<<dim3(nb, 2), blk, 0, stream>>>(rpt_t, rpt_s, bo_t, bo_s, N, nb);
        fill_kernel<<<dim3((E + 255) / 256), blk, 0, stream>>>(s_arr, t_arr, rpt_t, rpt_s,
                                                               cur_t, cur_s, eid_t, eid_s, E);
    }

    float* xd_cur = bufd0; float* xl_cur = bufl0;
    float* xd_nxt = bufd1; float* xl_nxt = bufl1;

    for (int L = 0; L < 3; ++L) {
        const int HC = (L < 2) ? 512 : 128;
        const int gd = 2 * L, gl = 2 * L + 1;
        dim3 ggrid((N + 127) / 128, HC / 128);

        // ---- d2l: src = s (xd side), dst = t (xl side) ----
        gemm128<false><<<ggrid, blk, 0, stream>>>(xd_cur, 128, gWs[gd], HC,
                                                  nullptr, nullptr, nullptr, hs, HC, N, 128);
        es_ed_kernel<<<dim3((N * 8 + 255) / 256), blk, 0, stream>>>(
            xd_cur, xl_cur, Uall + gd * 1024, esb, edb, N);
        if (HC == 512)
            gat_agg<512><<<dim3((N + 3) / 4), blk, 0, stream>>>(
                rpt_t, eid_t, s_arr, hs, esb, edb, gb[gd], xl_nxt, N);
        else
            gat_agg<128><<<dim3((N + 3) / 4), blk, 0, stream>>>(
                rpt_t, eid_t, s_arr, hs, esb, edb, gb[gd], xl_nxt, N);

        // ---- l2d: src = t (xl side), dst = s (xd side) ----
        gemm128<false><<<ggrid, blk, 0, stream>>>(xl_cur, 128, gWs[gl], HC,
                                                  nullptr, nullptr, nullptr, hs, HC, N, 128);
        es_ed_kernel<<<dim3((N * 8 + 255) / 256), blk, 0, stream>>>(
            xl_cur, xd_cur, Uall + gl * 1024, esb, edb, N);
        if (HC == 512)
            gat_agg<512><<<dim3((N + 3) / 4), blk, 0, stream>>>(
                rpt_s, eid_s, t_arr, hs, esb, edb, gb[gl], xd_nxt, N);
        else
            gat_agg<128><<<dim3((N + 3) / 4), blk, 0, stream>>>(
                rpt_s, eid_s, t_arr, hs, esb, edb, gb[gl], xd_nxt, N);

        // swap ping-pong
        float* tmp;
        tmp = xd_cur; xd_cur = xd_nxt; xd_nxt = tmp;
        tmp = xl_cur; xl_cur = xl_nxt; xl_nxt = tmp;
    }

    // penalty scaling on final (N,32) features, in place
    penalty_kernel<<<dim3((2 * N * 32 + 255) / 256), blk, 0, stream>>>(
        xd_cur, xl_cur, pen_Wd, pen_bd, pen_Wl, pen_bl, N);

    // link classifier
    classifier_kernel<<<dim3((EL + 3) / 4), blk, 0, stream>>>(
        xd_cur, xl_cur, eli, fc1W, fc1b, fc2W, fc2b, (float*)d_out, EL);
}

// Round 2
// 1546.547 us; speedup vs baseline: 1.7345x; 1.7345x over previous
//
#include <hip/hip_runtime.h>
#include <hip/hip_bf16.h>
#include <math.h>

typedef unsigned short u16;
typedef __bf16 bf16x8 __attribute__((ext_vector_type(8)));
typedef float f32x4 __attribute__((ext_vector_type(4)));

// ---------------------------------------------------------------------------
// bf16 hi/lo split MFMA GEMM implementation of the hetero-GAT forward pass.
//  - A,B split into bf16 hi+lo planes; C = Ahi*Bhi + Ahi*Blo + Alo*Bhi (fp32 acc)
//  - ed/es computed as x @ (W @ a) per head (fp32)  -> skips the Wd GEMM.
//  - CSR for atomic-free segment softmax+aggregate (fused /den,+bias,relu,mean)
// ---------------------------------------------------------------------------

__device__ inline float bfbits2f(u16 u) {
    unsigned int v = ((unsigned int)u) << 16;
    float f;
    __builtin_memcpy(&f, &v, 4);
    return f;
}
__device__ inline u16 f2bf(float x) {
    __hip_bfloat16 h = __float2bfloat16(x);
    u16 u;
    __builtin_memcpy(&u, &h, 2);
    return u;
}

#define GLD16(gp, lp) __builtin_amdgcn_global_load_lds( \
    (__attribute__((address_space(1))) void*)(gp),      \
    (__attribute__((address_space(3))) void*)(lp), 16, 0, 0)

// ---------------- split fp32 -> bf16 hi/lo planes (K padded to Kp) ---------
__global__ void splitX(const float* __restrict__ x, int N, int K, int Kp,
                       u16* __restrict__ hi)
{
    u16* lo = hi + (size_t)N * Kp;
    int nk4 = Kp >> 2;
    int t = blockIdx.x * 256 + threadIdx.x;
    if (t >= N * nk4) return;
    int n = t / nk4;
    int k4 = (t - n * nk4) << 2;
    u16 h[4], l[4];
#pragma unroll
    for (int j = 0; j < 4; ++j) {
        int k = k4 + j;
        float xv = (k < K) ? x[(size_t)n * K + k] : 0.f;
        u16 hb = f2bf(xv);
        h[j] = hb;
        l[j] = f2bf(xv - bfbits2f(hb));
    }
    uint2 hp, lp;
    hp.x = (unsigned)h[0] | ((unsigned)h[1] << 16);
    hp.y = (unsigned)h[2] | ((unsigned)h[3] << 16);
    lp.x = (unsigned)l[0] | ((unsigned)l[1] << 16);
    lp.y = (unsigned)l[2] | ((unsigned)l[3] << 16);
    *reinterpret_cast<uint2*>(&hi[(size_t)n * Kp + k4]) = hp;
    *reinterpret_cast<uint2*>(&lo[(size_t)n * Kp + k4]) = lp;
}

// ---------------- weight: (K x J) fp32 -> transposed bf16 planes (J x Kp) --
__global__ void splitBt(const float* __restrict__ B, int K, int Kp, int J,
                        u16* __restrict__ hi)
{
    int t = blockIdx.x * 256 + threadIdx.x;
    if (t >= J * Kp) return;
    int col = t / Kp, k = t - col * Kp;
    float v = (k < K) ? B[(size_t)k * J + col] : 0.f;
    u16 hb = f2bf(v);
    hi[t] = hb;
    hi[(size_t)J * Kp + t] = f2bf(v - bfbits2f(hb));
}

// ---------------- MFMA GEMM: C(NxJ) = A(NxKp) @ Bt(JxKp)^T, 3-term split ---
// 128x128 tile, BK=32, 4 waves (2x2), 4x4 fragments of 16x16x32 bf16.
template<bool BIAS_EMB>
__global__ __launch_bounds__(256) void gemm_mfma(
    const u16* __restrict__ Ahi,   // N x Kp, lo plane at +N*Kp
    const u16* __restrict__ Bhi,   // J x Kp (transposed), lo plane at +J*Kp
    const float* __restrict__ bias,
    const float* __restrict__ emb,
    const int* __restrict__ ids,
    float* __restrict__ C,
    int N, int Kp, int J)
{
    __shared__ __align__(16) u16 sA[4096];   // 128 rows x 32 bf16
    __shared__ __align__(16) u16 sB[4096];   // 128 cols x 32 bf16
    const int tid = threadIdx.x;
    const int lane = tid & 63;
    const int wid = tid >> 6;
    const int wr = wid >> 1, wc = wid & 1;
    const int rowbase = blockIdx.x * 128;
    const int colbase = blockIdx.y * 128;

    const size_t planeA = (size_t)N * Kp;
    const size_t planeB = (size_t)J * Kp;
    const int nk = Kp / 32;

    // staging indices: slot s in [0,512): row=s>>2, chunk kc=s&3 (chunk=8 bf16)
    const int akc = tid & 3;
    const int arow0 = tid >> 2;            // 0..63
    const int arow1 = 64 + (tid >> 2);     // 64..127
    const int swz = (arow0 >> 1) & 3;      // same for arow1 (row+64)
    int gr0 = rowbase + arow0; if (gr0 >= N) gr0 = N - 1;
    int gr1 = rowbase + arow1; if (gr1 >= N) gr1 = N - 1;
    const size_t aoff0 = (size_t)gr0 * Kp + (size_t)((akc ^ swz) * 8);
    const size_t aoff1 = (size_t)gr1 * Kp + (size_t)((akc ^ swz) * 8);
    const size_t boff0 = (size_t)(colbase + arow0) * Kp + (size_t)((akc ^ swz) * 8);
    const size_t boff1 = (size_t)(colbase + arow1) * Kp + (size_t)((akc ^ swz) * 8);

    // ds_read chunk swizzle: chunk = kg ^ ((row>>1)&3); row's low bits come
    // from (lane&15), fragment base rows are multiples of 16.
    const int kgs = ((lane >> 4) ^ ((lane >> 1) & 3)) * 8;   // ushort offset
    const int arow_rd = wr * 64 + (lane & 15);
    const int brow_rd = wc * 64 + (lane & 15);

    f32x4 acc[4][4] = {};

    for (int term = 0; term < 3; ++term) {
        const u16* Ap = (term < 2) ? Ahi : (Ahi + planeA);
        const u16* Bp = (term == 1) ? (Bhi + planeB) : Bhi;
        for (int ks = 0; ks < nk; ++ks) {
            const int k0 = ks * 32;
            GLD16(Ap + aoff0 + k0, &sA[(size_t)tid * 8]);
            GLD16(Ap + aoff1 + k0, &sA[(size_t)(tid + 256) * 8]);
            GLD16(Bp + boff0 + k0, &sB[(size_t)tid * 8]);
            GLD16(Bp + boff1 + k0, &sB[(size_t)(tid + 256) * 8]);
            __syncthreads();
            bf16x8 af[4], bfq[4];
#pragma unroll
            for (int m = 0; m < 4; ++m)
                af[m] = *reinterpret_cast<const bf16x8*>(&sA[(arow_rd + m * 16) * 32 + kgs]);
#pragma unroll
            for (int n = 0; n < 4; ++n)
                bfq[n] = *reinterpret_cast<const bf16x8*>(&sB[(brow_rd + n * 16) * 32 + kgs]);
#pragma unroll
            for (int m = 0; m < 4; ++m)
#pragma unroll
                for (int n = 0; n < 4; ++n)
                    acc[m][n] = __builtin_amdgcn_mfma_f32_16x16x32_bf16(
                        af[m], bfq[n], acc[m][n], 0, 0, 0);
            __syncthreads();
        }
    }

    // epilogue: C/D layout col=lane&15, row=(lane>>4)*4+i  (m89-verified)
#pragma unroll
    for (int m = 0; m < 4; ++m) {
        int rb = rowbase + wr * 64 + m * 16 + ((lane >> 4) << 2);
#pragma unroll
        for (int i = 0; i < 4; ++i) {
            int r = rb + i;
            if (r >= N) continue;
            const float* ep = nullptr;
            if (BIAS_EMB) ep = emb + (size_t)ids[r] * 128;
#pragma unroll
            for (int n = 0; n < 4; ++n) {
                int col = colbase + wc * 64 + n * 16 + (lane & 15);
                float v = acc[m][n][i];
                if (BIAS_EMB) v += bias[col] + ep[col];
                C[(size_t)r * J + col] = v;
            }
        }
    }
}

// ---------------- U = [Ws @ a_s | Wd @ a_d] per head: (128 x 8) per GAT ----
struct UParams {
    const float* Ws[6];
    const float* Wd[6];
    const float* as_[6];
    const float* ad_[6];
    int C[6];
};

__global__ void compute_U(UParams P, float* __restrict__ U)
{
    int g = blockIdx.x;
    int C = P.C[g];
    int HC = 4 * C;
    for (int o = threadIdx.x; o < 1024; o += 256) {
        int k = o >> 3, j = o & 7;
        int h = j & 3;
        const float* W = (j < 4) ? P.Ws[g] : P.Wd[g];
        const float* a = (j < 4) ? P.as_[g] : P.ad_[g];
        float s = 0.f;
        for (int c = 0; c < C; ++c)
            s = fmaf(W[k * HC + h * C + c], a[h * C + c], s);
        U[g * 1024 + k * 8 + j] = s;
    }
}

// ---------------- es = Xs @ U[:,0:4], ed = Xd @ U[:,4:8] ------------------
__global__ void es_ed_kernel(const float* __restrict__ Xs, const float* __restrict__ Xd,
                             const float* __restrict__ U,
                             float* __restrict__ es, float* __restrict__ ed, int N)
{
    int t = blockIdx.x * blockDim.x + threadIdx.x;
    if (t >= N * 8) return;
    int n = t >> 3, j = t & 7;
    const float4* X4 = reinterpret_cast<const float4*>(((j < 4) ? Xs : Xd) + (size_t)n * 128);
    float s = 0.f;
#pragma unroll 8
    for (int k4 = 0; k4 < 32; ++k4) {
        float4 x = X4[k4];
        s = fmaf(x.x, U[(k4 * 4 + 0) * 8 + j], s);
        s = fmaf(x.y, U[(k4 * 4 + 1) * 8 + j], s);
        s = fmaf(x.z, U[(k4 * 4 + 2) * 8 + j], s);
        s = fmaf(x.w, U[(k4 * 4 + 3) * 8 + j], s);
    }
    if (j < 4) es[n * 4 + j] = s;
    else       ed[n * 4 + (j - 4)] = s;
}

// ---------------- CSR build ------------------------------------------------
__global__ void deg_kernel(const int* __restrict__ s, const int* __restrict__ t,
                           int* __restrict__ deg_t, int* __restrict__ deg_s, int E)
{
    int i = blockIdx.x * blockDim.x + threadIdx.x;
    if (i >= E) return;
    atomicAdd(&deg_t[t[i]], 1);
    atomicAdd(&deg_s[s[i]], 1);
}

__global__ void scan_partial(const int* dA, const int* dB, int* eA, int* eB,
                             int* bsA, int* bsB, int N)
{
    __shared__ int lds[256];
    const int* deg = blockIdx.y ? dB : dA;
    int* ex = blockIdx.y ? eB : eA;
    int* bs = blockIdx.y ? bsB : bsA;
    int i = blockIdx.x * 256 + threadIdx.x;
    int v = (i < N) ? deg[i] : 0;
    int x = v;
    lds[threadIdx.x] = x;
    __syncthreads();
    for (int off = 1; off < 256; off <<= 1) {
        int tv = (threadIdx.x >= off) ? lds[threadIdx.x - off] : 0;
        __syncthreads();
        x += tv;
        lds[threadIdx.x] = x;
        __syncthreads();
    }
    if (i < N) ex[i] = x - v;
    if (threadIdx.x == 255) bs[blockIdx.x] = x;
}

__global__ void scan_bsums(int* bsA, int* bsB, int* boA, int* boB, int nb)
{
    __shared__ int lds[256];
    int* bs = blockIdx.y ? bsB : bsA;
    int* bo = blockIdx.y ? boB : boA;
    int v = (threadIdx.x < nb) ? bs[threadIdx.x] : 0;
    int x = v;
    lds[threadIdx.x] = x;
    __syncthreads();
    for (int off = 1; off < 256; off <<= 1) {
        int tv = (threadIdx.x >= off) ? lds[threadIdx.x - off] : 0;
        __syncthreads();
        x += tv;
        lds[threadIdx.x] = x;
        __syncthreads();
    }
    if (threadIdx.x < nb) bo[threadIdx.x] = x - v;
    if (threadIdx.x == 255) bo[nb] = x;
}

__global__ void scan_add(int* eA, int* eB, const int* boA, const int* boB, int N, int nb)
{
    int* ex = blockIdx.y ? eB : eA;
    const int* bo = blockIdx.y ? boB : boA;
    int i = blockIdx.x * 256 + threadIdx.x;
    if (i < N) ex[i] += bo[i >> 8];
    if (i == 0) ex[N] = bo[nb];
}

__global__ void fill_kernel(const int* __restrict__ s, const int* __restrict__ t,
                            const int* __restrict__ rpt_t, const int* __restrict__ rpt_s,
                            int* __restrict__ cur_t, int* __restrict__ cur_s,
                            int* __restrict__ eid_t, int* __restrict__ eid_s, int E)
{
    int i = blockIdx.x * blockDim.x + threadIdx.x;
    if (i >= E) return;
    int d = t[i];
    int p = atomicAdd(&cur_t[d], 1);
    eid_t[rpt_t[d] + p] = i;
    d = s[i];
    p = atomicAdd(&cur_s[d], 1);
    eid_s[rpt_s[d] + p] = i;
}

// ---------------- GAT aggregation + fused (/den, +bias, relu, head-mean) --
template<int HC>
__global__ __launch_bounds__(256) void gat_agg(
    const int* __restrict__ rowptr, const int* __restrict__ eids,
    const int* __restrict__ srcid,
    const float* __restrict__ hs,     // Nsrc x HC
    const float* __restrict__ es,     // Nsrc x 4
    const float* __restrict__ edv,    // Ndst x 4
    const float* __restrict__ bias,   // HC
    float* __restrict__ out,          // Ndst x HC/4
    int Ndst)
{
    constexpr int R = HC / 64;
    int n = blockIdx.x * 4 + (threadIdx.x >> 6);
    if (n >= Ndst) return;
    int lane = threadIdx.x & 63;
    int beg = rowptr[n], end = rowptr[n + 1];
    const float4 ed4 = *reinterpret_cast<const float4*>(&edv[(size_t)n * 4]);

    float m0 = -1e30f, m1 = -1e30f, m2 = -1e30f, m3 = -1e30f;
    for (int i = beg; i < end; ++i) {
        int e = eids[i];
        int sn = srcid[e];
        float4 e4 = *reinterpret_cast<const float4*>(&es[(size_t)sn * 4]);
        float v0 = e4.x + ed4.x; v0 = v0 > 0.f ? v0 : 0.2f * v0;
        float v1 = e4.y + ed4.y; v1 = v1 > 0.f ? v1 : 0.2f * v1;
        float v2 = e4.z + ed4.z; v2 = v2 > 0.f ? v2 : 0.2f * v2;
        float v3 = e4.w + ed4.w; v3 = v3 > 0.f ? v3 : 0.2f * v3;
        m0 = fmaxf(m0, v0); m1 = fmaxf(m1, v1);
        m2 = fmaxf(m2, v2); m3 = fmaxf(m3, v3);
    }

    float den0 = 0.f, den1 = 0.f, den2 = 0.f, den3 = 0.f;
    float acc[R];
#pragma unroll
    for (int r = 0; r < R; ++r) acc[r] = 0.f;

    for (int i = beg; i < end; ++i) {
        int e = eids[i];
        int sn = srcid[e];
        float4 e4 = *reinterpret_cast<const float4*>(&es[(size_t)sn * 4]);
        float v0 = e4.x + ed4.x; v0 = v0 > 0.f ? v0 : 0.2f * v0;
        float v1 = e4.y + ed4.y; v1 = v1 > 0.f ? v1 : 0.2f * v1;
        float v2 = e4.z + ed4.z; v2 = v2 > 0.f ? v2 : 0.2f * v2;
        float v3 = e4.w + ed4.w; v3 = v3 > 0.f ? v3 : 0.2f * v3;
        float w0 = expf(v0 - m0); den0 += w0;
        float w1 = expf(v1 - m1); den1 += w1;
        float w2 = expf(v2 - m2); den2 += w2;
        float w3 = expf(v3 - m3); den3 += w3;
        const float* hp = hs + (size_t)sn * HC;
#pragma unroll
        for (int r = 0; r < R; ++r) {
            float w;
            if (HC == 512) {
                w = (r < 2) ? w0 : (r < 4) ? w1 : (r < 6) ? w2 : w3;
            } else {
                w = (r == 0) ? (lane < 32 ? w0 : w1) : (lane < 32 ? w2 : w3);
            }
            acc[r] = fmaf(w, hp[r * 64 + lane], acc[r]);
        }
    }

    den0 += 1e-16f; den1 += 1e-16f; den2 += 1e-16f; den3 += 1e-16f;

    if (HC == 512) {
        float o0 = 0.f, o1 = 0.f;
#pragma unroll
        for (int r = 0; r < R; ++r) {
            float d = (r < 2) ? den0 : (r < 4) ? den1 : (r < 6) ? den2 : den3;
            float v = acc[r] / d + bias[r * 64 + lane];
            v = fmaxf(v, 0.f);
            if (r & 1) o1 += v; else o0 += v;
        }
        out[(size_t)n * 128 + lane] = 0.25f * o0;
        out[(size_t)n * 128 + 64 + lane] = 0.25f * o1;
    } else {
        float d0 = lane < 32 ? den0 : den1;
        float d1 = lane < 32 ? den2 : den3;
        float v0 = fmaxf(acc[0] / d0 + bias[lane], 0.f);
        float v1 = fmaxf(acc[1] / d1 + bias[64 + lane], 0.f);
        float sum = v0 + __shfl_xor(v0, 32, 64) + v1 + __shfl_xor(v1, 32, 64);
        if (lane < 32) out[(size_t)n * 32 + lane] = 0.25f * sum;
    }
}

// ---------------- penalty: x *= exp(x @ W + b), x is (N,32) ---------------
__global__ void penalty_kernel(float* __restrict__ xd, float* __restrict__ xl,
                               const float* __restrict__ Wd, const float* __restrict__ bd,
                               const float* __restrict__ Wl, const float* __restrict__ bl,
                               int N)
{
    int t = blockIdx.x * blockDim.x + threadIdx.x;
    if (t >= 2 * N * 32) return;
    int n = t >> 5, c = t & 31;
    float* x;
    const float* W;
    float b;
    if (n < N) { x = xd + (size_t)n * 32; W = Wd; b = bd[0]; }
    else       { x = xl + (size_t)(n - N) * 32; W = Wl; b = bl[0]; }
    float v = x[c];
    float p = v * W[c];
    p += __shfl_xor(p, 16, 32);
    p += __shfl_xor(p, 8, 32);
    p += __shfl_xor(p, 4, 32);
    p += __shfl_xor(p, 2, 32);
    p += __shfl_xor(p, 1, 32);
    x[c] = v * expf(p + b);
}

// ---------------- link classifier: one wave per label edge ----------------
__global__ __launch_bounds__(256) void classifier_kernel(
    const float* __restrict__ xd, const float* __restrict__ xl,
    const int* __restrict__ eli,
    const float* __restrict__ fc1W, const float* __restrict__ fc1b,
    const float* __restrict__ fc2W, const float* __restrict__ fc2b,
    float* __restrict__ out, int EL)
{
    int wid = (blockIdx.x * 256 + threadIdx.x) >> 6;
    int lane = threadIdx.x & 63;
    if (wid >= EL) return;
    float ef;
    if (lane < 32) {
        int i0 = eli[wid];
        ef = xd[(size_t)i0 * 32 + lane];
    } else {
        int i1 = eli[EL + wid];
        ef = xl[(size_t)i1 * 32 + (lane - 32)];
    }
    float acc = fc1b[lane];
#pragma unroll
    for (int k = 0; k < 64; ++k) {
        float v = __shfl(ef, k, 64);
        acc = fmaf(v, fc1W[k * 64 + lane], acc);
    }
    acc = fmaxf(acc, 0.f);
    float p = acc * fc2W[lane];
#pragma unroll
    for (int off = 32; off >= 1; off >>= 1) p += __shfl_xor(p, off, 64);
    if (lane == 0) out[wid] = p + fc2b[0];
}

// ---------------------------------------------------------------------------
extern "C" void kernel_launch(void* const* d_in, const int* in_sizes, int n_in,
                              void* d_out, int out_size, void* d_ws, size_t ws_size,
                              hipStream_t stream)
{
    const int N  = in_sizes[6] / 128;
    const int Kd = in_sizes[2] / 128;   // 412
    const int Kl = in_sizes[4] / 128;   // 240
    const int KdP = (Kd + 31) & ~31;    // 416
    const int KlP = (Kl + 31) & ~31;    // 256
    const int E  = in_sizes[48] / 2;
    const int EL = in_sizes[49] / 2;

    const float* x_d    = (const float*)d_in[0];
    const float* x_l    = (const float*)d_in[1];
    const float* Wd_lin = (const float*)d_in[2];
    const float* bd_lin = (const float*)d_in[3];
    const float* Wl_lin = (const float*)d_in[4];
    const float* bl_lin = (const float*)d_in[5];
    const float* emb_d  = (const float*)d_in[6];
    const float* emb_l  = (const float*)d_in[7];

    const float *gWs[6], *gWd[6], *gas[6], *gad[6], *gb[6];
    for (int g = 0; g < 6; ++g) {
        gWs[g] = (const float*)d_in[8 + 5 * g + 0];
        gWd[g] = (const float*)d_in[8 + 5 * g + 1];
        gas[g] = (const float*)d_in[8 + 5 * g + 2];
        gad[g] = (const float*)d_in[8 + 5 * g + 3];
        gb[g]  = (const float*)d_in[8 + 5 * g + 4];
    }
    const float* pen_Wd = (const float*)d_in[38];
    const float* pen_bd = (const float*)d_in[39];
    const float* pen_Wl = (const float*)d_in[40];
    const float* pen_bl = (const float*)d_in[41];
    const float* fc1W   = (const float*)d_in[42];
    const float* fc1b   = (const float*)d_in[43];
    const float* fc2W   = (const float*)d_in[44];
    const float* fc2b   = (const float*)d_in[45];
    const int* node_id_d = (const int*)d_in[46];
    const int* node_id_l = (const int*)d_in[47];
    const int* ei  = (const int*)d_in[48];
    const int* eli = (const int*)d_in[49];
    const int* s_arr = ei;
    const int* t_arr = ei + E;

    // ---- workspace carve-up (~262 MB) ----
    char* ws = (char*)d_ws;
    size_t off = 0;
    auto alloc = [&](size_t bytes) -> char* {
        char* p = ws + off;
        off = (off + bytes + 255) & ~(size_t)255;
        return p;
    };
    float* bufd0 = (float*)alloc((size_t)N * 128 * 4);
    float* bufd1 = (float*)alloc((size_t)N * 128 * 4);
    float* bufl0 = (float*)alloc((size_t)N * 128 * 4);
    float* bufl1 = (float*)alloc((size_t)N * 128 * 4);
    // region1: hs (N*512 f32)  ALIASED with input-d planes (2*N*KdP u16)
    char* region1 = alloc((size_t)N * 512 * 4);
    float* hs = (float*)region1;
    u16* pxd_in = (u16*)region1;
    // region2: input-l planes (2*N*KlP u16) ALIASED with per-layer planes
    char* region2 = alloc((size_t)N * 1024);
    u16* pxl_in = (u16*)region2;
    u16* pxd = (u16*)region2;                       // 2*N*128 u16 = N*512 B
    u16* pxl = (u16*)(region2 + (size_t)N * 512);
    // weight planes
    u16* btWd = (u16*)alloc((size_t)2 * 128 * KdP * 2);
    u16* btWl = (u16*)alloc((size_t)2 * 128 * KlP * 2);
    u16* btWs[6];
    for (int g = 0; g < 6; ++g) {
        int J = (g < 4) ? 512 : 128;
        btWs[g] = (u16*)alloc((size_t)2 * J * 128 * 2);
    }
    float* esb  = (float*)alloc((size_t)N * 4 * 4);
    float* edb  = (float*)alloc((size_t)N * 4 * 4);
    float* Uall = (float*)alloc((size_t)6 * 1024 * 4);
    int* rpt_t = (int*)alloc((size_t)(N + 1) * 4);
    int* rpt_s = (int*)alloc((size_t)(N + 1) * 4);
    int* deg_t = (int*)alloc((size_t)N * 4);
    int* deg_s = (int*)alloc((size_t)N * 4);
    int* cur_t = (int*)alloc((size_t)N * 4);
    int* cur_s = (int*)alloc((size_t)N * 4);
    int* eid_t = (int*)alloc((size_t)E * 4);
    int* eid_s = (int*)alloc((size_t)E * 4);
    int* bs_t  = (int*)alloc(256 * 4);
    int* bs_s  = (int*)alloc(256 * 4);
    int* bo_t  = (int*)alloc(257 * 4);
    int* bo_s  = (int*)alloc(257 * 4);
    (void)ws_size;

    hipMemsetAsync(deg_t, 0, (size_t)N * 4, stream);
    hipMemsetAsync(deg_s, 0, (size_t)N * 4, stream);
    hipMemsetAsync(cur_t, 0, (size_t)N * 4, stream);
    hipMemsetAsync(cur_s, 0, (size_t)N * 4, stream);

    dim3 blk(256);
    const int nMB = (N + 127) / 128;

    // ---- input splits (planes) ----
    splitX<<<dim3((N * (KdP >> 2) + 255) / 256), blk, 0, stream>>>(x_d, N, Kd, KdP, pxd_in);
    splitX<<<dim3((N * (KlP >> 2) + 255) / 256), blk, 0, stream>>>(x_l, N, Kl, KlP, pxl_in);
    splitBt<<<dim3((128 * KdP + 255) / 256), blk, 0, stream>>>(Wd_lin, Kd, KdP, 128, btWd);
    splitBt<<<dim3((128 * KlP + 255) / 256), blk, 0, stream>>>(Wl_lin, Kl, KlP, 128, btWl);
    for (int g = 0; g < 6; ++g) {
        int J = (g < 4) ? 512 : 128;
        splitBt<<<dim3((J * 128 + 255) / 256), blk, 0, stream>>>(gWs[g], 128, 128, J, btWs[g]);
    }

    // attention projection vectors for all 6 GATs
    {
        UParams up;
        for (int g = 0; g < 6; ++g) {
            up.Ws[g] = gWs[g]; up.Wd[g] = gWd[g];
            up.as_[g] = gas[g]; up.ad_[g] = gad[g];
            up.C[g] = (g < 4) ? 128 : 32;
        }
        compute_U<<<dim3(6), blk, 0, stream>>>(up, Uall);
    }

    // CSR for both directions
    {
        deg_kernel<<<dim3((E + 255) / 256), blk, 0, stream>>>(s_arr, t_arr, deg_t, deg_s, E);
        int nb = (N + 255) / 256;
        scan_partial<<<dim3(nb, 2), blk, 0, stream>>>(deg_t, deg_s, rpt_t, rpt_s, bs_t, bs_s, N);
        scan_bsums<<<dim3(1, 2), blk, 0, stream>>>(bs_t, bs_s, bo_t, bo_s, nb);
        scan_add<<<dim3(nb, 2), blk, 0, stream>>>(rpt_t, rpt_s, bo_t, bo_s, N, nb);
        fill_kernel<<<dim3((E + 255) / 256), blk, 0, stream>>>(s_arr, t_arr, rpt_t, rpt_s,
                                                               cur_t, cur_s, eid_t, eid_s, E);
    }

    // ---- input linears (+bias +embedding gather) ----
    gemm_mfma<true><<<dim3(nMB, 1), blk, 0, stream>>>(
        pxd_in, btWd, bd_lin, emb_d, node_id_d, bufd0, N, KdP, 128);
    gemm_mfma<true><<<dim3(nMB, 1), blk, 0, stream>>>(
        pxl_in, btWl, bl_lin, emb_l, node_id_l, bufl0, N, KlP, 128);

    float* xd_cur = bufd0; float* xl_cur = bufl0;
    float* xd_nxt = bufd1; float* xl_nxt = bufl1;

    for (int L = 0; L < 3; ++L) {
        const int HC = (L < 2) ? 512 : 128;
        const int gd = 2 * L, gl = 2 * L + 1;

        // split current features into bf16 planes
        splitX<<<dim3((N * 32 + 255) / 256), blk, 0, stream>>>(xd_cur, N, 128, 128, pxd);
        splitX<<<dim3((N * 32 + 255) / 256), blk, 0, stream>>>(xl_cur, N, 128, 128, pxl);

        // ---- d2l: src = s (xd side), dst = t (xl side) ----
        gemm_mfma<false><<<dim3(nMB, HC / 128), blk, 0, stream>>>(
            pxd, btWs[gd], nullptr, nullptr, nullptr, hs, N, 128, HC);
        es_ed_kernel<<<dim3((N * 8 + 255) / 256), blk, 0, stream>>>(
            xd_cur, xl_cur, Uall + gd * 1024, esb, edb, N);
        if (HC == 512)
            gat_agg<512><<<dim3((N + 3) / 4), blk, 0, stream>>>(
                rpt_t, eid_t, s_arr, hs, esb, edb, gb[gd], xl_nxt, N);
        else
            gat_agg<128><<<dim3((N + 3) / 4), blk, 0, stream>>>(
                rpt_t, eid_t, s_arr, hs, esb, edb, gb[gd], xl_nxt, N);

        // ---- l2d: src = t (xl side), dst = s (xd side) ----
        gemm_mfma<false><<<dim3(nMB, HC / 128), blk, 0, stream>>>(
            pxl, btWs[gl], nullptr, nullptr, nullptr, hs, N, 128, HC);
        es_ed_kernel<<<dim3((N * 8 + 255) / 256), blk, 0, stream>>>(
            xl_cur, xd_cur, Uall + gl * 1024, esb, edb, N);
        if (HC == 512)
            gat_agg<512><<<dim3((N + 3) / 4), blk, 0, stream>>>(
                rpt_s, eid_s, t_arr, hs, esb, edb, gb[gl], xd_nxt, N);
        else
            gat_agg<128><<<dim3((N + 3) / 4), blk, 0, stream>>>(
                rpt_s, eid_s, t_arr, hs, esb, edb, gb[gl], xd_nxt, N);

        float* tmp;
        tmp = xd_cur; xd_cur = xd_nxt; xd_nxt = tmp;
        tmp = xl_cur; xl_cur = xl_nxt; xl_nxt = tmp;
    }

    penalty_kernel<<<dim3((2 * N * 32 + 255) / 256), blk, 0, stream>>>(
        xd_cur, xl_cur, pen_Wd, pen_bd, pen_Wl, pen_bl, N);

    classifier_kernel<<<dim3((EL + 3) / 4), blk, 0, stream>>>(
        xd_cur, xl_cur, eli, fc1W, fc1b, fc2W, fc2b, (float*)d_out, EL);
}

// Round 3
// 1365.602 us; speedup vs baseline: 1.9643x; 1.1325x over previous
//
#include <hip/hip_runtime.h>
#include <hip/hip_bf16.h>
#include <math.h>

typedef unsigned short u16;
typedef __bf16 bf16x8 __attribute__((ext_vector_type(8)));
typedef float f32x4 __attribute__((ext_vector_type(4)));

// ---------------------------------------------------------------------------
// bf16 hi/lo split MFMA GEMM implementation of the hetero-GAT forward pass.
//  - A,B split into bf16 hi+lo planes; C = Ahi*Bhi + Ahi*Blo + Alo*Bhi (fp32 acc)
//  - ed/es computed as x @ (W @ a) per head (fp32)  -> skips the Wd GEMM.
//  - CSR (direct column indices) for atomic-free segment softmax+aggregate.
//  - classifier factored per-node: fc1(cat(a,b)) = a@W1t + b@W1b + b1;
//    penalty scaling folded into the per-node table build.
// ---------------------------------------------------------------------------

__device__ inline float bfbits2f(u16 u) {
    unsigned int v = ((unsigned int)u) << 16;
    float f;
    __builtin_memcpy(&f, &v, 4);
    return f;
}
__device__ inline u16 f2bf(float x) {
    __hip_bfloat16 h = __float2bfloat16(x);
    u16 u;
    __builtin_memcpy(&u, &h, 2);
    return u;
}

#define GLD16(gp, lp) __builtin_amdgcn_global_load_lds( \
    (__attribute__((address_space(1))) void*)(gp),      \
    (__attribute__((address_space(3))) void*)(lp), 16, 0, 0)

// ---------------- split fp32 -> bf16 hi/lo planes (K padded to Kp) ---------
__global__ void splitX(const float* __restrict__ x, int N, int K, int Kp,
                       u16* __restrict__ hi)
{
    u16* lo = hi + (size_t)N * Kp;
    int nk4 = Kp >> 2;
    int t = blockIdx.x * 256 + threadIdx.x;
    if (t >= N * nk4) return;
    int n = t / nk4;
    int k4 = (t - n * nk4) << 2;
    u16 h[4], l[4];
#pragma unroll
    for (int j = 0; j < 4; ++j) {
        int k = k4 + j;
        float xv = (k < K) ? x[(size_t)n * K + k] : 0.f;
        u16 hb = f2bf(xv);
        h[j] = hb;
        l[j] = f2bf(xv - bfbits2f(hb));
    }
    uint2 hp, lp;
    hp.x = (unsigned)h[0] | ((unsigned)h[1] << 16);
    hp.y = (unsigned)h[2] | ((unsigned)h[3] << 16);
    lp.x = (unsigned)l[0] | ((unsigned)l[1] << 16);
    lp.y = (unsigned)l[2] | ((unsigned)l[3] << 16);
    *reinterpret_cast<uint2*>(&hi[(size_t)n * Kp + k4]) = hp;
    *reinterpret_cast<uint2*>(&lo[(size_t)n * Kp + k4]) = lp;
}

// ---------------- weight: (K x J) fp32 -> transposed bf16 planes (J x Kp) --
__global__ void splitBt(const float* __restrict__ B, int K, int Kp, int J,
                        u16* __restrict__ hi)
{
    int t = blockIdx.x * 256 + threadIdx.x;
    if (t >= J * Kp) return;
    int col = t / Kp, k = t - col * Kp;
    float v = (k < K) ? B[(size_t)k * J + col] : 0.f;
    u16 hb = f2bf(v);
    hi[t] = hb;
    hi[(size_t)J * Kp + t] = f2bf(v - bfbits2f(hb));
}

// ---------------- MFMA GEMM: C(NxJ) = A(NxKp) @ Bt(JxKp)^T, 3-term split ---
template<bool BIAS_EMB>
__global__ __launch_bounds__(256) void gemm_mfma(
    const u16* __restrict__ Ahi,
    const u16* __restrict__ Bhi,
    const float* __restrict__ bias,
    const float* __restrict__ emb,
    const int* __restrict__ ids,
    float* __restrict__ C,
    int N, int Kp, int J)
{
    __shared__ __align__(16) u16 sA[4096];
    __shared__ __align__(16) u16 sB[4096];
    const int tid = threadIdx.x;
    const int lane = tid & 63;
    const int wid = tid >> 6;
    const int wr = wid >> 1, wc = wid & 1;
    const int rowbase = blockIdx.x * 128;
    const int colbase = blockIdx.y * 128;

    const size_t planeA = (size_t)N * Kp;
    const size_t planeB = (size_t)J * Kp;
    const int nk = Kp / 32;

    const int akc = tid & 3;
    const int arow0 = tid >> 2;
    const int arow1 = 64 + (tid >> 2);
    const int swz = (arow0 >> 1) & 3;
    int gr0 = rowbase + arow0; if (gr0 >= N) gr0 = N - 1;
    int gr1 = rowbase + arow1; if (gr1 >= N) gr1 = N - 1;
    const size_t aoff0 = (size_t)gr0 * Kp + (size_t)((akc ^ swz) * 8);
    const size_t aoff1 = (size_t)gr1 * Kp + (size_t)((akc ^ swz) * 8);
    const size_t boff0 = (size_t)(colbase + arow0) * Kp + (size_t)((akc ^ swz) * 8);
    const size_t boff1 = (size_t)(colbase + arow1) * Kp + (size_t)((akc ^ swz) * 8);

    const int kgs = ((lane >> 4) ^ ((lane >> 1) & 3)) * 8;
    const int arow_rd = wr * 64 + (lane & 15);
    const int brow_rd = wc * 64 + (lane & 15);

    f32x4 acc[4][4] = {};

    for (int term = 0; term < 3; ++term) {
        const u16* Ap = (term < 2) ? Ahi : (Ahi + planeA);
        const u16* Bp = (term == 1) ? (Bhi + planeB) : Bhi;
        for (int ks = 0; ks < nk; ++ks) {
            const int k0 = ks * 32;
            GLD16(Ap + aoff0 + k0, &sA[(size_t)tid * 8]);
            GLD16(Ap + aoff1 + k0, &sA[(size_t)(tid + 256) * 8]);
            GLD16(Bp + boff0 + k0, &sB[(size_t)tid * 8]);
            GLD16(Bp + boff1 + k0, &sB[(size_t)(tid + 256) * 8]);
            __syncthreads();
            bf16x8 af[4], bfq[4];
#pragma unroll
            for (int m = 0; m < 4; ++m)
                af[m] = *reinterpret_cast<const bf16x8*>(&sA[(arow_rd + m * 16) * 32 + kgs]);
#pragma unroll
            for (int n = 0; n < 4; ++n)
                bfq[n] = *reinterpret_cast<const bf16x8*>(&sB[(brow_rd + n * 16) * 32 + kgs]);
#pragma unroll
            for (int m = 0; m < 4; ++m)
#pragma unroll
                for (int n = 0; n < 4; ++n)
                    acc[m][n] = __builtin_amdgcn_mfma_f32_16x16x32_bf16(
                        af[m], bfq[n], acc[m][n], 0, 0, 0);
            __syncthreads();
        }
    }

#pragma unroll
    for (int m = 0; m < 4; ++m) {
        int rb = rowbase + wr * 64 + m * 16 + ((lane >> 4) << 2);
#pragma unroll
        for (int i = 0; i < 4; ++i) {
            int r = rb + i;
            if (r >= N) continue;
            const float* ep = nullptr;
            if (BIAS_EMB) ep = emb + (size_t)ids[r] * 128;
#pragma unroll
            for (int n = 0; n < 4; ++n) {
                int col = colbase + wc * 64 + n * 16 + (lane & 15);
                float v = acc[m][n][i];
                if (BIAS_EMB) v += bias[col] + ep[col];
                C[(size_t)r * J + col] = v;
            }
        }
    }
}

// ---------------- U = [Ws @ a_s | Wd @ a_d] per head: (128 x 8) per GAT ----
struct UParams {
    const float* Ws[6];
    const float* Wd[6];
    const float* as_[6];
    const float* ad_[6];
    int C[6];
};

__global__ void compute_U(UParams P, float* __restrict__ U)
{
    int g = blockIdx.x;
    int C = P.C[g];
    int HC = 4 * C;
    for (int o = threadIdx.x; o < 1024; o += 256) {
        int k = o >> 3, j = o & 7;
        int h = j & 3;
        const float* W = (j < 4) ? P.Ws[g] : P.Wd[g];
        const float* a = (j < 4) ? P.as_[g] : P.ad_[g];
        float s = 0.f;
        for (int c = 0; c < C; ++c)
            s = fmaf(W[k * HC + h * C + c], a[h * C + c], s);
        U[g * 1024 + k * 8 + j] = s;
    }
}

// ---------------- fused es/ed for BOTH directions of one layer ------------
// j 0-3 : es1 = xd @ U1[:,j]     (d2l source term)
// j 4-7 : ed2 = xd @ U2[:,j]     (l2d dest term)
// j 8-11: ed1 = xl @ U1[:,j-4]   (d2l dest term)
// j 12-15: es2 = xl @ U2[:,j-12] (l2d source term)
__global__ void es_ed2_kernel(const float* __restrict__ xd, const float* __restrict__ xl,
                              const float* __restrict__ U1, const float* __restrict__ U2,
                              float* __restrict__ es1, float* __restrict__ ed1,
                              float* __restrict__ es2, float* __restrict__ ed2, int N)
{
    int t = blockIdx.x * blockDim.x + threadIdx.x;
    if (t >= N * 16) return;
    int n = t >> 4, j = t & 15;
    const float4* X4 = reinterpret_cast<const float4*>(((j < 8) ? xd : xl) + (size_t)n * 128);
    const float* U;
    float* dst;
    int col;
    if (j < 4)       { U = U1; col = j;      dst = &es1[n * 4 + j]; }
    else if (j < 8)  { U = U2; col = j;      dst = &ed2[n * 4 + (j - 4)]; }
    else if (j < 12) { U = U1; col = j - 4;  dst = &ed1[n * 4 + (j - 8)]; }
    else             { U = U2; col = j - 12; dst = &es2[n * 4 + (j - 12)]; }
    float s = 0.f;
#pragma unroll 8
    for (int k4 = 0; k4 < 32; ++k4) {
        float4 x = X4[k4];
        s = fmaf(x.x, U[(k4 * 4 + 0) * 8 + col], s);
        s = fmaf(x.y, U[(k4 * 4 + 1) * 8 + col], s);
        s = fmaf(x.z, U[(k4 * 4 + 2) * 8 + col], s);
        s = fmaf(x.w, U[(k4 * 4 + 3) * 8 + col], s);
    }
    *dst = s;
}

// ---------------- CSR build (stores src-node column indices directly) -----
__global__ void deg_kernel(const int* __restrict__ s, const int* __restrict__ t,
                           int* __restrict__ deg_t, int* __restrict__ deg_s, int E)
{
    int i = blockIdx.x * blockDim.x + threadIdx.x;
    if (i >= E) return;
    atomicAdd(&deg_t[t[i]], 1);
    atomicAdd(&deg_s[s[i]], 1);
}

__global__ void scan_partial(const int* dA, const int* dB, int* eA, int* eB,
                             int* bsA, int* bsB, int N)
{
    __shared__ int lds[256];
    const int* deg = blockIdx.y ? dB : dA;
    int* ex = blockIdx.y ? eB : eA;
    int* bs = blockIdx.y ? bsB : bsA;
    int i = blockIdx.x * 256 + threadIdx.x;
    int v = (i < N) ? deg[i] : 0;
    int x = v;
    lds[threadIdx.x] = x;
    __syncthreads();
    for (int off = 1; off < 256; off <<= 1) {
        int tv = (threadIdx.x >= off) ? lds[threadIdx.x - off] : 0;
        __syncthreads();
        x += tv;
        lds[threadIdx.x] = x;
        __syncthreads();
    }
    if (i < N) ex[i] = x - v;
    if (threadIdx.x == 255) bs[blockIdx.x] = x;
}

__global__ void scan_bsums(int* bsA, int* bsB, int* boA, int* boB, int nb)
{
    __shared__ int lds[256];
    int* bs = blockIdx.y ? bsB : bsA;
    int* bo = blockIdx.y ? boB : boA;
    int v = (threadIdx.x < nb) ? bs[threadIdx.x] : 0;
    int x = v;
    lds[threadIdx.x] = x;
    __syncthreads();
    for (int off = 1; off < 256; off <<= 1) {
        int tv = (threadIdx.x >= off) ? lds[threadIdx.x - off] : 0;
        __syncthreads();
        x += tv;
        lds[threadIdx.x] = x;
        __syncthreads();
    }
    if (threadIdx.x < nb) bo[threadIdx.x] = x - v;
    if (threadIdx.x == 255) bo[nb] = x;
}

__global__ void scan_add(int* eA, int* eB, const int* boA, const int* boB, int N, int nb)
{
    int* ex = blockIdx.y ? eB : eA;
    const int* bo = blockIdx.y ? boB : boA;
    int i = blockIdx.x * 256 + threadIdx.x;
    if (i < N) ex[i] += bo[i >> 8];
    if (i == 0) ex[N] = bo[nb];
}

__global__ void fill_kernel(const int* __restrict__ s, const int* __restrict__ t,
                            const int* __restrict__ rpt_t, const int* __restrict__ rpt_s,
                            int* __restrict__ cur_t, int* __restrict__ cur_s,
                            int* __restrict__ col_t, int* __restrict__ col_s, int E)
{
    int i = blockIdx.x * blockDim.x + threadIdx.x;
    if (i >= E) return;
    int sv = s[i], tv = t[i];
    int p = atomicAdd(&cur_t[tv], 1);
    col_t[rpt_t[tv] + p] = sv;          // src node for d2l aggregation
    p = atomicAdd(&cur_s[sv], 1);
    col_s[rpt_s[sv] + p] = tv;          // src node for l2d aggregation
}

// ---------------- GAT aggregation + fused (/den, +bias, relu, head-mean) --
template<int HC>
__global__ __launch_bounds__(256) void gat_agg(
    const int* __restrict__ rowptr, const int* __restrict__ cols,
    const float* __restrict__ hs,     // Nsrc x HC
    const float* __restrict__ es,     // Nsrc x 4
    const float* __restrict__ edv,    // Ndst x 4
    const float* __restrict__ bias,   // HC
    float* __restrict__ out,          // Ndst x HC/4
    int Ndst)
{
    constexpr int R = HC / 64;
    int n = blockIdx.x * 4 + (threadIdx.x >> 6);
    if (n >= Ndst) return;
    int lane = threadIdx.x & 63;
    int beg = rowptr[n], end = rowptr[n + 1];
    const float4 ed4 = *reinterpret_cast<const float4*>(&edv[(size_t)n * 4]);

    float m0 = -1e30f, m1 = -1e30f, m2 = -1e30f, m3 = -1e30f;
    for (int i = beg; i < end; ++i) {
        int sn = cols[i];
        float4 e4 = *reinterpret_cast<const float4*>(&es[(size_t)sn * 4]);
        float v0 = e4.x + ed4.x; v0 = v0 > 0.f ? v0 : 0.2f * v0;
        float v1 = e4.y + ed4.y; v1 = v1 > 0.f ? v1 : 0.2f * v1;
        float v2 = e4.z + ed4.z; v2 = v2 > 0.f ? v2 : 0.2f * v2;
        float v3 = e4.w + ed4.w; v3 = v3 > 0.f ? v3 : 0.2f * v3;
        m0 = fmaxf(m0, v0); m1 = fmaxf(m1, v1);
        m2 = fmaxf(m2, v2); m3 = fmaxf(m3, v3);
    }

    float den0 = 0.f, den1 = 0.f, den2 = 0.f, den3 = 0.f;
    float acc[R];
#pragma unroll
    for (int r = 0; r < R; ++r) acc[r] = 0.f;

    for (int i = beg; i < end; ++i) {
        int sn = cols[i];
        float4 e4 = *reinterpret_cast<const float4*>(&es[(size_t)sn * 4]);
        float v0 = e4.x + ed4.x; v0 = v0 > 0.f ? v0 : 0.2f * v0;
        float v1 = e4.y + ed4.y; v1 = v1 > 0.f ? v1 : 0.2f * v1;
        float v2 = e4.z + ed4.z; v2 = v2 > 0.f ? v2 : 0.2f * v2;
        float v3 = e4.w + ed4.w; v3 = v3 > 0.f ? v3 : 0.2f * v3;
        float w0 = expf(v0 - m0); den0 += w0;
        float w1 = expf(v1 - m1); den1 += w1;
        float w2 = expf(v2 - m2); den2 += w2;
        float w3 = expf(v3 - m3); den3 += w3;
        const float* hp = hs + (size_t)sn * HC;
#pragma unroll
        for (int r = 0; r < R; ++r) {
            float w;
            if (HC == 512) {
                w = (r < 2) ? w0 : (r < 4) ? w1 : (r < 6) ? w2 : w3;
            } else {
                w = (r == 0) ? (lane < 32 ? w0 : w1) : (lane < 32 ? w2 : w3);
            }
            acc[r] = fmaf(w, hp[r * 64 + lane], acc[r]);
        }
    }

    den0 += 1e-16f; den1 += 1e-16f; den2 += 1e-16f; den3 += 1e-16f;

    if (HC == 512) {
        float o0 = 0.f, o1 = 0.f;
#pragma unroll
        for (int r = 0; r < R; ++r) {
            float d = (r < 2) ? den0 : (r < 4) ? den1 : (r < 6) ? den2 : den3;
            float v = acc[r] / d + bias[r * 64 + lane];
            v = fmaxf(v, 0.f);
            if (r & 1) o1 += v; else o0 += v;
        }
        out[(size_t)n * 128 + lane] = 0.25f * o0;
        out[(size_t)n * 128 + 64 + lane] = 0.25f * o1;
    } else {
        float d0 = lane < 32 ? den0 : den1;
        float d1 = lane < 32 ? den2 : den3;
        float v0 = fmaxf(acc[0] / d0 + bias[lane], 0.f);
        float v1 = fmaxf(acc[1] / d1 + bias[64 + lane], 0.f);
        float sum = v0 + __shfl_xor(v0, 32, 64) + v1 + __shfl_xor(v1, 32, 64);
        if (lane < 32) out[(size_t)n * 32 + lane] = 0.25f * sum;
    }
}

// ---------------- per-node classifier tables (penalty folded in) ----------
// Ad[n] = pen_scale(xd[n]) * (xd[n] @ fc1W[0:32 ,:])   (n < N)
// Bl[n] = pen_scale(xl[n]) * (xl[n] @ fc1W[32:64,:])   (n >= N side)
__global__ __launch_bounds__(256) void fc1_halves_kernel(
    const float* __restrict__ xd, const float* __restrict__ xl,
    const float* __restrict__ fc1W,
    const float* __restrict__ penWd, const float* __restrict__ penbd,
    const float* __restrict__ penWl, const float* __restrict__ penbl,
    float* __restrict__ Ad, float* __restrict__ Bl, int N)
{
    int wid = (blockIdx.x * 256 + threadIdx.x) >> 6;
    if (wid >= 2 * N) return;
    int lane = threadIdx.x & 63;
    bool isl = wid >= N;
    int n = isl ? wid - N : wid;
    const float* x = (isl ? xl : xd) + (size_t)n * 32;
    const float* pW = isl ? penWl : penWd;
    float pb = isl ? penbl[0] : penbd[0];

    // penalty logit: both 32-halves of the wave compute identical partials
    float pp = x[lane & 31] * pW[lane & 31];
    pp += __shfl_xor(pp, 1, 64);
    pp += __shfl_xor(pp, 2, 64);
    pp += __shfl_xor(pp, 4, 64);
    pp += __shfl_xor(pp, 8, 64);
    pp += __shfl_xor(pp, 16, 64);
    float s = expf(pp + pb);

    const float* W = fc1W + (isl ? 32 * 64 : 0);
    float acc = 0.f;
#pragma unroll
    for (int k = 0; k < 32; ++k)
        acc = fmaf(x[k], W[k * 64 + lane], acc);
    (isl ? Bl : Ad)[(size_t)n * 64 + lane] = s * acc;
}

// ---------------- link classifier: table gather + reduce ------------------
__global__ __launch_bounds__(256) void link_kernel(
    const float* __restrict__ Ad, const float* __restrict__ Bl,
    const int* __restrict__ eli,
    const float* __restrict__ fc1b, const float* __restrict__ fc2W,
    const float* __restrict__ fc2b,
    float* __restrict__ out, int EL)
{
    int wid = (blockIdx.x * 256 + threadIdx.x) >> 6;
    if (wid >= EL) return;
    int lane = threadIdx.x & 63;
    int e0 = eli[wid];
    int e1 = eli[EL + wid];
    float v = Ad[(size_t)e0 * 64 + lane] + Bl[(size_t)e1 * 64 + lane] + fc1b[lane];
    v = fmaxf(v, 0.f);
    float p = v * fc2W[lane];
#pragma unroll
    for (int off = 32; off >= 1; off >>= 1) p += __shfl_xor(p, off, 64);
    if (lane == 0) out[wid] = p + fc2b[0];
}

// ---------------------------------------------------------------------------
extern "C" void kernel_launch(void* const* d_in, const int* in_sizes, int n_in,
                              void* d_out, int out_size, void* d_ws, size_t ws_size,
                              hipStream_t stream)
{
    const int N  = in_sizes[6] / 128;
    const int Kd = in_sizes[2] / 128;   // 412
    const int Kl = in_sizes[4] / 128;   // 240
    const int KdP = (Kd + 31) & ~31;    // 416
    const int KlP = (Kl + 31) & ~31;    // 256
    const int E  = in_sizes[48] / 2;
    const int EL = in_sizes[49] / 2;

    const float* x_d    = (const float*)d_in[0];
    const float* x_l    = (const float*)d_in[1];
    const float* Wd_lin = (const float*)d_in[2];
    const float* bd_lin = (const float*)d_in[3];
    const float* Wl_lin = (const float*)d_in[4];
    const float* bl_lin = (const float*)d_in[5];
    const float* emb_d  = (const float*)d_in[6];
    const float* emb_l  = (const float*)d_in[7];

    const float *gWs[6], *gWd[6], *gas[6], *gad[6], *gb[6];
    for (int g = 0; g < 6; ++g) {
        gWs[g] = (const float*)d_in[8 + 5 * g + 0];
        gWd[g] = (const float*)d_in[8 + 5 * g + 1];
        gas[g] = (const float*)d_in[8 + 5 * g + 2];
        gad[g] = (const float*)d_in[8 + 5 * g + 3];
        gb[g]  = (const float*)d_in[8 + 5 * g + 4];
    }
    const float* pen_Wd = (const float*)d_in[38];
    const float* pen_bd = (const float*)d_in[39];
    const float* pen_Wl = (const float*)d_in[40];
    const float* pen_bl = (const float*)d_in[41];
    const float* fc1W   = (const float*)d_in[42];
    const float* fc1b   = (const float*)d_in[43];
    const float* fc2W   = (const float*)d_in[44];
    const float* fc2b   = (const float*)d_in[45];
    const int* node_id_d = (const int*)d_in[46];
    const int* node_id_l = (const int*)d_in[47];
    const int* ei  = (const int*)d_in[48];
    const int* eli = (const int*)d_in[49];
    const int* s_arr = ei;
    const int* t_arr = ei + E;

    // ---- workspace carve-up ----
    char* ws = (char*)d_ws;
    size_t off = 0;
    auto alloc = [&](size_t bytes) -> char* {
        char* p = ws + off;
        off = (off + bytes + 255) & ~(size_t)255;
        return p;
    };
    float* bufd0 = (float*)alloc((size_t)N * 128 * 4);
    float* bufd1 = (float*)alloc((size_t)N * 128 * 4);
    float* bufl0 = (float*)alloc((size_t)N * 128 * 4);
    float* bufl1 = (float*)alloc((size_t)N * 128 * 4);
    // region1: hs (N*512 f32)  ALIASED with input-d planes (2*N*KdP u16)
    char* region1 = alloc((size_t)N * 512 * 4);
    float* hs = (float*)region1;
    u16* pxd_in = (u16*)region1;
    // region2: input-l planes (2*N*KlP u16) ALIASED with per-layer planes
    char* region2 = alloc((size_t)N * 1024);
    u16* pxl_in = (u16*)region2;
    u16* pxd = (u16*)region2;
    u16* pxl = (u16*)(region2 + (size_t)N * 512);
    // weight planes
    u16* btWd = (u16*)alloc((size_t)2 * 128 * KdP * 2);
    u16* btWl = (u16*)alloc((size_t)2 * 128 * KlP * 2);
    u16* btWs[6];
    for (int g = 0; g < 6; ++g) {
        int J = (g < 4) ? 512 : 128;
        btWs[g] = (u16*)alloc((size_t)2 * J * 128 * 2);
    }
    float* es1  = (float*)alloc((size_t)N * 4 * 4);
    float* ed1  = (float*)alloc((size_t)N * 4 * 4);
    float* es2  = (float*)alloc((size_t)N * 4 * 4);
    float* ed2  = (float*)alloc((size_t)N * 4 * 4);
    float* Uall = (float*)alloc((size_t)6 * 1024 * 4);
    int* rpt_t = (int*)alloc((size_t)(N + 1) * 4);
    int* rpt_s = (int*)alloc((size_t)(N + 1) * 4);
    int* deg_t = (int*)alloc((size_t)N * 4);
    int* deg_s = (int*)alloc((size_t)N * 4);
    int* cur_t = (int*)alloc((size_t)N * 4);
    int* cur_s = (int*)alloc((size_t)N * 4);
    int* col_t = (int*)alloc((size_t)E * 4);
    int* col_s = (int*)alloc((size_t)E * 4);
    int* bs_t  = (int*)alloc(256 * 4);
    int* bs_s  = (int*)alloc(256 * 4);
    int* bo_t  = (int*)alloc(257 * 4);
    int* bo_s  = (int*)alloc(257 * 4);
    float* Ad  = (float*)alloc((size_t)N * 64 * 4);
    float* Bl  = (float*)alloc((size_t)N * 64 * 4);
    (void)ws_size;

    hipMemsetAsync(deg_t, 0, (size_t)N * 4, stream);
    hipMemsetAsync(deg_s, 0, (size_t)N * 4, stream);
    hipMemsetAsync(cur_t, 0, (size_t)N * 4, stream);
    hipMemsetAsync(cur_s, 0, (size_t)N * 4, stream);

    dim3 blk(256);
    const int nMB = (N + 127) / 128;

    // ---- input splits (planes) ----
    splitX<<<dim3((N * (KdP >> 2) + 255) / 256), blk, 0, stream>>>(x_d, N, Kd, KdP, pxd_in);
    splitX<<<dim3((N * (KlP >> 2) + 255) / 256), blk, 0, stream>>>(x_l, N, Kl, KlP, pxl_in);
    splitBt<<<dim3((128 * KdP + 255) / 256), blk, 0, stream>>>(Wd_lin, Kd, KdP, 128, btWd);
    splitBt<<<dim3((128 * KlP + 255) / 256), blk, 0, stream>>>(Wl_lin, Kl, KlP, 128, btWl);
    for (int g = 0; g < 6; ++g) {
        int J = (g < 4) ? 512 : 128;
        splitBt<<<dim3((J * 128 + 255) / 256), blk, 0, stream>>>(gWs[g], 128, 128, J, btWs[g]);
    }

    {
        UParams up;
        for (int g = 0; g < 6; ++g) {
            up.Ws[g] = gWs[g]; up.Wd[g] = gWd[g];
            up.as_[g] = gas[g]; up.ad_[g] = gad[g];
            up.C[g] = (g < 4) ? 128 : 32;
        }
        compute_U<<<dim3(6), blk, 0, stream>>>(up, Uall);
    }

    // CSR for both directions
    {
        deg_kernel<<<dim3((E + 255) / 256), blk, 0, stream>>>(s_arr, t_arr, deg_t, deg_s, E);
        int nb = (N + 255) / 256;
        scan_partial<<<dim3(nb, 2), blk, 0, stream>>>(deg_t, deg_s, rpt_t, rpt_s, bs_t, bs_s, N);
        scan_bsums<<<dim3(1, 2), blk, 0, stream>>>(bs_t, bs_s, bo_t, bo_s, nb);
        scan_add<<<dim3(nb, 2), blk, 0, stream>>>(rpt_t, rpt_s, bo_t, bo_s, N, nb);
        fill_kernel<<<dim3((E + 255) / 256), blk, 0, stream>>>(s_arr, t_arr, rpt_t, rpt_s,
                                                               cur_t, cur_s, col_t, col_s, E);
    }

    // ---- input linears (+bias +embedding gather) ----
    gemm_mfma<true><<<dim3(nMB, 1), blk, 0, stream>>>(
        pxd_in, btWd, bd_lin, emb_d, node_id_d, bufd0, N, KdP, 128);
    gemm_mfma<true><<<dim3(nMB, 1), blk, 0, stream>>>(
        pxl_in, btWl, bl_lin, emb_l, node_id_l, bufl0, N, KlP, 128);

    float* xd_cur = bufd0; float* xl_cur = bufl0;
    float* xd_nxt = bufd1; float* xl_nxt = bufl1;

    for (int L = 0; L < 3; ++L) {
        const int HC = (L < 2) ? 512 : 128;
        const int gd = 2 * L, gl = 2 * L + 1;

        splitX<<<dim3((N * 32 + 255) / 256), blk, 0, stream>>>(xd_cur, N, 128, 128, pxd);
        splitX<<<dim3((N * 32 + 255) / 256), blk, 0, stream>>>(xl_cur, N, 128, 128, pxl);

        es_ed2_kernel<<<dim3((N * 16 + 255) / 256), blk, 0, stream>>>(
            xd_cur, xl_cur, Uall + gd * 1024, Uall + gl * 1024,
            es1, ed1, es2, ed2, N);

        // ---- d2l: src = xd side, dst = xl side ----
        gemm_mfma<false><<<dim3(nMB, HC / 128), blk, 0, stream>>>(
            pxd, btWs[gd], nullptr, nullptr, nullptr, hs, N, 128, HC);
        if (HC == 512)
            gat_agg<512><<<dim3((N + 3) / 4), blk, 0, stream>>>(
                rpt_t, col_t, hs, es1, ed1, gb[gd], xl_nxt, N);
        else
            gat_agg<128><<<dim3((N + 3) / 4), blk, 0, stream>>>(
                rpt_t, col_t, hs, es1, ed1, gb[gd], xl_nxt, N);

        // ---- l2d: src = xl side, dst = xd side ----
        gemm_mfma<false><<<dim3(nMB, HC / 128), blk, 0, stream>>>(
            pxl, btWs[gl], nullptr, nullptr, nullptr, hs, N, 128, HC);
        if (HC == 512)
            gat_agg<512><<<dim3((N + 3) / 4), blk, 0, stream>>>(
                rpt_s, col_s, hs, es2, ed2, gb[gl], xd_nxt, N);
        else
            gat_agg<128><<<dim3((N + 3) / 4), blk, 0, stream>>>(
                rpt_s, col_s, hs, es2, ed2, gb[gl], xd_nxt, N);

        float* tmp;
        tmp = xd_cur; xd_cur = xd_nxt; xd_nxt = tmp;
        tmp = xl_cur; xl_cur = xl_nxt; xl_nxt = tmp;
    }

    // classifier: per-node tables (penalty folded), then per-edge gather
    fc1_halves_kernel<<<dim3((2 * N * 64 + 255) / 256), blk, 0, stream>>>(
        xd_cur, xl_cur, fc1W, pen_Wd, pen_bd, pen_Wl, pen_bl, Ad, Bl, N);
    link_kernel<<<dim3((EL + 3) / 4), blk, 0, stream>>>(
        Ad, Bl, eli, fc1b, fc2W, fc2b, (float*)d_out, EL);
}

// Round 4
// 1280.254 us; speedup vs baseline: 2.0952x; 1.0667x over previous
//
#include <hip/hip_runtime.h>
#include <hip/hip_bf16.h>
#include <math.h>

typedef unsigned short u16;
typedef __bf16 bf16x8 __attribute__((ext_vector_type(8)));
typedef float f32x4 __attribute__((ext_vector_type(4)));

// ---------------------------------------------------------------------------
// Hetero-GAT forward, bf16 hi/lo split MFMA.
// Key algebra: alpha depends only on es/ed (linear in x), so for layers 1-2
//   out[dst] = (sum_e alpha_e x[src_e]) @ Ws      (commute agg <-> GEMM)
// -> aggregate 128-dim x per head (512B/edge gather, 25.6MB table), then a
//    head-blocked GEMM with fused +bias/relu/head-mean epilogue.
// hs (N x 512) is never materialized for layers 1-2.
// ---------------------------------------------------------------------------

__device__ inline float bfbits2f(u16 u) {
    unsigned int v = ((unsigned int)u) << 16;
    float f;
    __builtin_memcpy(&f, &v, 4);
    return f;
}
__device__ inline u16 f2bf(float x) {
    __hip_bfloat16 h = __float2bfloat16(x);
    u16 u;
    __builtin_memcpy(&u, &h, 2);
    return u;
}

#define GLD16(gp, lp) __builtin_amdgcn_global_load_lds( \
    (__attribute__((address_space(1))) void*)(gp),      \
    (__attribute__((address_space(3))) void*)(lp), 16, 0, 0)

// ---------------- split fp32 -> bf16 hi/lo planes (K padded to Kp) ---------
__global__ void splitX(const float* __restrict__ x, int N, int K, int Kp,
                       u16* __restrict__ hi)
{
    u16* lo = hi + (size_t)N * Kp;
    int nk4 = Kp >> 2;
    int t = blockIdx.x * 256 + threadIdx.x;
    if (t >= N * nk4) return;
    int n = t / nk4;
    int k4 = (t - n * nk4) << 2;
    u16 h[4], l[4];
#pragma unroll
    for (int j = 0; j < 4; ++j) {
        int k = k4 + j;
        float xv = (k < K) ? x[(size_t)n * K + k] : 0.f;
        u16 hb = f2bf(xv);
        h[j] = hb;
        l[j] = f2bf(xv - bfbits2f(hb));
    }
    uint2 hp, lp;
    hp.x = (unsigned)h[0] | ((unsigned)h[1] << 16);
    hp.y = (unsigned)h[2] | ((unsigned)h[3] << 16);
    lp.x = (unsigned)l[0] | ((unsigned)l[1] << 16);
    lp.y = (unsigned)l[2] | ((unsigned)l[3] << 16);
    *reinterpret_cast<uint2*>(&hi[(size_t)n * Kp + k4]) = hp;
    *reinterpret_cast<uint2*>(&lo[(size_t)n * Kp + k4]) = lp;
}

// ---------------- weight: (K x J) fp32 -> transposed bf16 planes (J x Kp) --
__global__ void splitBt(const float* __restrict__ B, int K, int Kp, int J,
                        u16* __restrict__ hi)
{
    int t = blockIdx.x * 256 + threadIdx.x;
    if (t >= J * Kp) return;
    int col = t / Kp, k = t - col * Kp;
    float v = (k < K) ? B[(size_t)k * J + col] : 0.f;
    u16 hb = f2bf(v);
    hi[t] = hb;
    hi[(size_t)J * Kp + t] = f2bf(v - bfbits2f(hb));
}

// ---------------- MFMA GEMM: C(NxJ) = A(NxKp) @ Bt(JxKp)^T, 3-term split ---
template<bool BIAS_EMB>
__global__ __launch_bounds__(256) void gemm_mfma(
    const u16* __restrict__ Ahi,
    const u16* __restrict__ Bhi,
    const float* __restrict__ bias,
    const float* __restrict__ emb,
    const int* __restrict__ ids,
    float* __restrict__ C,
    int N, int Kp, int J)
{
    __shared__ __align__(16) u16 sA[4096];
    __shared__ __align__(16) u16 sB[4096];
    const int tid = threadIdx.x;
    const int lane = tid & 63;
    const int wid = tid >> 6;
    const int wr = wid >> 1, wc = wid & 1;
    const int rowbase = blockIdx.x * 128;
    const int colbase = blockIdx.y * 128;

    const size_t planeA = (size_t)N * Kp;
    const size_t planeB = (size_t)J * Kp;
    const int nk = Kp / 32;

    const int akc = tid & 3;
    const int arow0 = tid >> 2;
    const int arow1 = 64 + (tid >> 2);
    const int swz = (arow0 >> 1) & 3;
    int gr0 = rowbase + arow0; if (gr0 >= N) gr0 = N - 1;
    int gr1 = rowbase + arow1; if (gr1 >= N) gr1 = N - 1;
    const size_t aoff0 = (size_t)gr0 * Kp + (size_t)((akc ^ swz) * 8);
    const size_t aoff1 = (size_t)gr1 * Kp + (size_t)((akc ^ swz) * 8);
    const size_t boff0 = (size_t)(colbase + arow0) * Kp + (size_t)((akc ^ swz) * 8);
    const size_t boff1 = (size_t)(colbase + arow1) * Kp + (size_t)((akc ^ swz) * 8);

    const int kgs = ((lane >> 4) ^ ((lane >> 1) & 3)) * 8;
    const int arow_rd = wr * 64 + (lane & 15);
    const int brow_rd = wc * 64 + (lane & 15);

    f32x4 acc[4][4] = {};

    for (int term = 0; term < 3; ++term) {
        const u16* Ap = (term < 2) ? Ahi : (Ahi + planeA);
        const u16* Bp = (term == 1) ? (Bhi + planeB) : Bhi;
        for (int ks = 0; ks < nk; ++ks) {
            const int k0 = ks * 32;
            GLD16(Ap + aoff0 + k0, &sA[(size_t)tid * 8]);
            GLD16(Ap + aoff1 + k0, &sA[(size_t)(tid + 256) * 8]);
            GLD16(Bp + boff0 + k0, &sB[(size_t)tid * 8]);
            GLD16(Bp + boff1 + k0, &sB[(size_t)(tid + 256) * 8]);
            __syncthreads();
            bf16x8 af[4], bfq[4];
#pragma unroll
            for (int m = 0; m < 4; ++m)
                af[m] = *reinterpret_cast<const bf16x8*>(&sA[(arow_rd + m * 16) * 32 + kgs]);
#pragma unroll
            for (int n = 0; n < 4; ++n)
                bfq[n] = *reinterpret_cast<const bf16x8*>(&sB[(brow_rd + n * 16) * 32 + kgs]);
#pragma unroll
            for (int m = 0; m < 4; ++m)
#pragma unroll
                for (int n = 0; n < 4; ++n)
                    acc[m][n] = __builtin_amdgcn_mfma_f32_16x16x32_bf16(
                        af[m], bfq[n], acc[m][n], 0, 0, 0);
            __syncthreads();
        }
    }

#pragma unroll
    for (int m = 0; m < 4; ++m) {
        int rb = rowbase + wr * 64 + m * 16 + ((lane >> 4) << 2);
#pragma unroll
        for (int i = 0; i < 4; ++i) {
            int r = rb + i;
            if (r >= N) continue;
            const float* ep = nullptr;
            if (BIAS_EMB) ep = emb + (size_t)ids[r] * 128;
#pragma unroll
            for (int n = 0; n < 4; ++n) {
                int col = colbase + wc * 64 + n * 16 + (lane & 15);
                float v = acc[m][n][i];
                if (BIAS_EMB) v += bias[col] + ep[col];
                C[(size_t)r * J + col] = v;
            }
        }
    }
}

// ---------------- head-blocked GEMM with fused relu/head-mean epilogue -----
// out[r,c] = 0.25 * sum_h relu( agg[r, h*128: (h+1)*128] @ Wh + bias[h*128+c] )
// A planes: N x 512 (lo at +N*512). B planes: 512 x 128 transposed (btWs).
__global__ __launch_bounds__(256) void gemm_heads(
    const u16* __restrict__ Ahi,
    const u16* __restrict__ Bhi,
    const float* __restrict__ bias,
    float* __restrict__ C,
    int N)
{
    __shared__ __align__(16) u16 sAh[4096];
    __shared__ __align__(16) u16 sAl[4096];
    __shared__ __align__(16) u16 sBh[4096];
    __shared__ __align__(16) u16 sBl[4096];
    const int tid = threadIdx.x;
    const int lane = tid & 63;
    const int wid = tid >> 6;
    const int wr = wid >> 1, wc = wid & 1;
    const int rowbase = blockIdx.x * 128;

    const u16* Alo = Ahi + (size_t)N * 512;
    const u16* Blo = Bhi + (size_t)512 * 128;

    const int akc = tid & 3;
    const int arow0 = tid >> 2;
    const int arow1 = 64 + arow0;
    const int swz = (arow0 >> 1) & 3;
    int gr0 = rowbase + arow0; if (gr0 >= N) gr0 = N - 1;
    int gr1 = rowbase + arow1; if (gr1 >= N) gr1 = N - 1;
    const size_t aoff0 = (size_t)gr0 * 512 + (size_t)((akc ^ swz) * 8);
    const size_t aoff1 = (size_t)gr1 * 512 + (size_t)((akc ^ swz) * 8);
    const size_t boff0 = (size_t)arow0 * 128 + (size_t)((akc ^ swz) * 8);
    const size_t boff1 = (size_t)arow1 * 128 + (size_t)((akc ^ swz) * 8);

    const int kgs = ((lane >> 4) ^ ((lane >> 1) & 3)) * 8;
    const int arow_rd = wr * 64 + (lane & 15);
    const int brow_rd = wc * 64 + (lane & 15);

    f32x4 acc[4][4] = {};
    f32x4 runsum[4][4] = {};

    for (int h = 0; h < 4; ++h) {
        const size_t ha = (size_t)h * 128;          // A k-offset
        const size_t hb = (size_t)h * 128 * 128;    // B row-block offset
#pragma unroll
        for (int ks = 0; ks < 4; ++ks) {
            const int k0 = ks * 32;
            GLD16(Ahi + aoff0 + ha + k0, &sAh[(size_t)tid * 8]);
            GLD16(Ahi + aoff1 + ha + k0, &sAh[(size_t)(tid + 256) * 8]);
            GLD16(Alo + aoff0 + ha + k0, &sAl[(size_t)tid * 8]);
            GLD16(Alo + aoff1 + ha + k0, &sAl[(size_t)(tid + 256) * 8]);
            GLD16(Bhi + boff0 + hb + k0, &sBh[(size_t)tid * 8]);
            GLD16(Bhi + boff1 + hb + k0, &sBh[(size_t)(tid + 256) * 8]);
            GLD16(Blo + boff0 + hb + k0, &sBl[(size_t)tid * 8]);
            GLD16(Blo + boff1 + hb + k0, &sBl[(size_t)(tid + 256) * 8]);
            __syncthreads();
            bf16x8 bh[4], bl[4];
#pragma unroll
            for (int n = 0; n < 4; ++n) {
                bh[n] = *reinterpret_cast<const bf16x8*>(&sBh[(brow_rd + n * 16) * 32 + kgs]);
                bl[n] = *reinterpret_cast<const bf16x8*>(&sBl[(brow_rd + n * 16) * 32 + kgs]);
            }
#pragma unroll
            for (int m = 0; m < 4; ++m) {
                bf16x8 ah = *reinterpret_cast<const bf16x8*>(&sAh[(arow_rd + m * 16) * 32 + kgs]);
                bf16x8 al = *reinterpret_cast<const bf16x8*>(&sAl[(arow_rd + m * 16) * 32 + kgs]);
#pragma unroll
                for (int n = 0; n < 4; ++n) {
                    acc[m][n] = __builtin_amdgcn_mfma_f32_16x16x32_bf16(ah, bh[n], acc[m][n], 0, 0, 0);
                    acc[m][n] = __builtin_amdgcn_mfma_f32_16x16x32_bf16(ah, bl[n], acc[m][n], 0, 0, 0);
                    acc[m][n] = __builtin_amdgcn_mfma_f32_16x16x32_bf16(al, bh[n], acc[m][n], 0, 0, 0);
                }
            }
            __syncthreads();
        }
        // head epilogue: +bias, relu, accumulate into runsum; reset acc
#pragma unroll
        for (int m = 0; m < 4; ++m)
#pragma unroll
            for (int n = 0; n < 4; ++n) {
                int col = wc * 64 + n * 16 + (lane & 15);
                float b = bias[h * 128 + col];
#pragma unroll
                for (int i = 0; i < 4; ++i) {
                    runsum[m][n][i] += fmaxf(acc[m][n][i] + b, 0.f);
                    acc[m][n][i] = 0.f;
                }
            }
    }

#pragma unroll
    for (int m = 0; m < 4; ++m) {
        int rb = rowbase + wr * 64 + m * 16 + ((lane >> 4) << 2);
#pragma unroll
        for (int i = 0; i < 4; ++i) {
            int r = rb + i;
            if (r >= N) continue;
#pragma unroll
            for (int n = 0; n < 4; ++n) {
                int col = wc * 64 + n * 16 + (lane & 15);
                C[(size_t)r * 128 + col] = 0.25f * runsum[m][n][i];
            }
        }
    }
}

// ---------------- U = [Ws @ a_s | Wd @ a_d] per head: (128 x 8) per GAT ----
struct UParams {
    const float* Ws[6];
    const float* Wd[6];
    const float* as_[6];
    const float* ad_[6];
    int C[6];
};

__global__ void compute_U(UParams P, float* __restrict__ U)
{
    int g = blockIdx.x;
    int C = P.C[g];
    int HC = 4 * C;
    for (int o = threadIdx.x; o < 1024; o += 256) {
        int k = o >> 3, j = o & 7;
        int h = j & 3;
        const float* W = (j < 4) ? P.Ws[g] : P.Wd[g];
        const float* a = (j < 4) ? P.as_[g] : P.ad_[g];
        float s = 0.f;
        for (int c = 0; c < C; ++c)
            s = fmaf(W[k * HC + h * C + c], a[h * C + c], s);
        U[g * 1024 + k * 8 + j] = s;
    }
}

// ---------------- fused es/ed for BOTH directions of one layer ------------
__global__ void es_ed2_kernel(const float* __restrict__ xd, const float* __restrict__ xl,
                              const float* __restrict__ U1, const float* __restrict__ U2,
                              float* __restrict__ es1, float* __restrict__ ed1,
                              float* __restrict__ es2, float* __restrict__ ed2, int N)
{
    int t = blockIdx.x * blockDim.x + threadIdx.x;
    if (t >= N * 16) return;
    int n = t >> 4, j = t & 15;
    const float4* X4 = reinterpret_cast<const float4*>(((j < 8) ? xd : xl) + (size_t)n * 128);
    const float* U;
    float* dst;
    int col;
    if (j < 4)       { U = U1; col = j;      dst = &es1[n * 4 + j]; }
    else if (j < 8)  { U = U2; col = j;      dst = &ed2[n * 4 + (j - 4)]; }
    else if (j < 12) { U = U1; col = j - 4;  dst = &ed1[n * 4 + (j - 8)]; }
    else             { U = U2; col = j - 12; dst = &es2[n * 4 + (j - 12)]; }
    float s = 0.f;
#pragma unroll 8
    for (int k4 = 0; k4 < 32; ++k4) {
        float4 x = X4[k4];
        s = fmaf(x.x, U[(k4 * 4 + 0) * 8 + col], s);
        s = fmaf(x.y, U[(k4 * 4 + 1) * 8 + col], s);
        s = fmaf(x.z, U[(k4 * 4 + 2) * 8 + col], s);
        s = fmaf(x.w, U[(k4 * 4 + 3) * 8 + col], s);
    }
    *dst = s;
}

// ---------------- CSR build (stores src-node column indices directly) -----
__global__ void deg_kernel(const int* __restrict__ s, const int* __restrict__ t,
                           int* __restrict__ deg_t, int* __restrict__ deg_s, int E)
{
    int i = blockIdx.x * blockDim.x + threadIdx.x;
    if (i >= E) return;
    atomicAdd(&deg_t[t[i]], 1);
    atomicAdd(&deg_s[s[i]], 1);
}

__global__ void scan_partial(const int* dA, const int* dB, int* eA, int* eB,
                             int* bsA, int* bsB, int N)
{
    __shared__ int lds[256];
    const int* deg = blockIdx.y ? dB : dA;
    int* ex = blockIdx.y ? eB : eA;
    int* bs = blockIdx.y ? bsB : bsA;
    int i = blockIdx.x * 256 + threadIdx.x;
    int v = (i < N) ? deg[i] : 0;
    int x = v;
    lds[threadIdx.x] = x;
    __syncthreads();
    for (int off = 1; off < 256; off <<= 1) {
        int tv = (threadIdx.x >= off) ? lds[threadIdx.x - off] : 0;
        __syncthreads();
        x += tv;
        lds[threadIdx.x] = x;
        __syncthreads();
    }
    if (i < N) ex[i] = x - v;
    if (threadIdx.x == 255) bs[blockIdx.x] = x;
}

__global__ void scan_bsums(int* bsA, int* bsB, int* boA, int* boB, int nb)
{
    __shared__ int lds[256];
    int* bs = blockIdx.y ? bsB : bsA;
    int* bo = blockIdx.y ? boB : boA;
    int v = (threadIdx.x < nb) ? bs[threadIdx.x] : 0;
    int x = v;
    lds[threadIdx.x] = x;
    __syncthreads();
    for (int off = 1; off < 256; off <<= 1) {
        int tv = (threadIdx.x >= off) ? lds[threadIdx.x - off] : 0;
        __syncthreads();
        x += tv;
        lds[threadIdx.x] = x;
        __syncthreads();
    }
    if (threadIdx.x < nb) bo[threadIdx.x] = x - v;
    if (threadIdx.x == 255) bo[nb] = x;
}

__global__ void scan_add(int* eA, int* eB, const int* boA, const int* boB, int N, int nb)
{
    int* ex = blockIdx.y ? eB : eA;
    const int* bo = blockIdx.y ? boB : boA;
    int i = blockIdx.x * 256 + threadIdx.x;
    if (i < N) ex[i] += bo[i >> 8];
    if (i == 0) ex[N] = bo[nb];
}

__global__ void fill_kernel(const int* __restrict__ s, const int* __restrict__ t,
                            const int* __restrict__ rpt_t, const int* __restrict__ rpt_s,
                            int* __restrict__ cur_t, int* __restrict__ cur_s,
                            int* __restrict__ col_t, int* __restrict__ col_s, int E)
{
    int i = blockIdx.x * blockDim.x + threadIdx.x;
    if (i >= E) return;
    int sv = s[i], tv = t[i];
    int p = atomicAdd(&cur_t[tv], 1);
    col_t[rpt_t[tv] + p] = sv;
    p = atomicAdd(&cur_s[sv], 1);
    col_s[rpt_s[sv] + p] = tv;
}

// ---------------- per-head x-aggregation (layers 1-2) ---------------------
// agg[n, h, c] = (sum_e w_e^h x[src_e, c]) / den_h, written as bf16 hi/lo.
__global__ __launch_bounds__(256) void agg_x(
    const int* __restrict__ rowptr, const int* __restrict__ cols,
    const float* __restrict__ xsrc,   // Nsrc x 128 fp32
    const float* __restrict__ es,     // Nsrc x 4
    const float* __restrict__ edv,    // Ndst x 4
    u16* __restrict__ aggp,           // hi plane; lo at +Ndst*512
    int Ndst)
{
    int n = blockIdx.x * 4 + (threadIdx.x >> 6);
    if (n >= Ndst) return;
    int lane = threadIdx.x & 63;
    int beg = rowptr[n], end = rowptr[n + 1];
    const float4 ed4 = *reinterpret_cast<const float4*>(&edv[(size_t)n * 4]);

    float m0 = -1e30f, m1 = -1e30f, m2 = -1e30f, m3 = -1e30f;
    for (int i = beg; i < end; ++i) {
        int sn = cols[i];
        float4 e4 = *reinterpret_cast<const float4*>(&es[(size_t)sn * 4]);
        float v0 = e4.x + ed4.x; v0 = v0 > 0.f ? v0 : 0.2f * v0;
        float v1 = e4.y + ed4.y; v1 = v1 > 0.f ? v1 : 0.2f * v1;
        float v2 = e4.z + ed4.z; v2 = v2 > 0.f ? v2 : 0.2f * v2;
        float v3 = e4.w + ed4.w; v3 = v3 > 0.f ? v3 : 0.2f * v3;
        m0 = fmaxf(m0, v0); m1 = fmaxf(m1, v1);
        m2 = fmaxf(m2, v2); m3 = fmaxf(m3, v3);
    }

    float den0 = 0.f, den1 = 0.f, den2 = 0.f, den3 = 0.f;
    float a00 = 0.f, a01 = 0.f, a02 = 0.f, a03 = 0.f;   // c = lane
    float a10 = 0.f, a11 = 0.f, a12 = 0.f, a13 = 0.f;   // c = 64+lane

    for (int i = beg; i < end; ++i) {
        int sn = cols[i];
        float4 e4 = *reinterpret_cast<const float4*>(&es[(size_t)sn * 4]);
        float v0 = e4.x + ed4.x; v0 = v0 > 0.f ? v0 : 0.2f * v0;
        float v1 = e4.y + ed4.y; v1 = v1 > 0.f ? v1 : 0.2f * v1;
        float v2 = e4.z + ed4.z; v2 = v2 > 0.f ? v2 : 0.2f * v2;
        float v3 = e4.w + ed4.w; v3 = v3 > 0.f ? v3 : 0.2f * v3;
        float w0 = expf(v0 - m0); den0 += w0;
        float w1 = expf(v1 - m1); den1 += w1;
        float w2 = expf(v2 - m2); den2 += w2;
        float w3 = expf(v3 - m3); den3 += w3;
        const float* xp = xsrc + (size_t)sn * 128;
        float x0 = xp[lane];
        float x1 = xp[64 + lane];
        a00 = fmaf(w0, x0, a00); a10 = fmaf(w0, x1, a10);
        a01 = fmaf(w1, x0, a01); a11 = fmaf(w1, x1, a11);
        a02 = fmaf(w2, x0, a02); a12 = fmaf(w2, x1, a12);
        a03 = fmaf(w3, x0, a03); a13 = fmaf(w3, x1, a13);
    }

    float i0 = 1.f / (den0 + 1e-16f);
    float i1 = 1.f / (den1 + 1e-16f);
    float i2 = 1.f / (den2 + 1e-16f);
    float i3 = 1.f / (den3 + 1e-16f);
    u16* lo = aggp + (size_t)Ndst * 512;
    size_t base = (size_t)n * 512 + lane;
    float va[8] = {a00 * i0, a01 * i1, a02 * i2, a03 * i3,
                   a10 * i0, a11 * i1, a12 * i2, a13 * i3};
#pragma unroll
    for (int h = 0; h < 4; ++h) {
        float v = va[h];
        u16 hb = f2bf(v);
        aggp[base + h * 128] = hb;
        lo[base + h * 128] = f2bf(v - bfbits2f(hb));
        float v1 = va[4 + h];
        u16 hb1 = f2bf(v1);
        aggp[base + h * 128 + 64] = hb1;
        lo[base + h * 128 + 64] = f2bf(v1 - bfbits2f(hb1));
    }
}

// ---------------- GAT aggregation for layer 3 (direct hs, HC=128) ---------
__global__ __launch_bounds__(256) void gat_agg128(
    const int* __restrict__ rowptr, const int* __restrict__ cols,
    const float* __restrict__ hs,     // Nsrc x 128
    const float* __restrict__ es,
    const float* __restrict__ edv,
    const float* __restrict__ bias,   // 128
    float* __restrict__ out,          // Ndst x 32
    int Ndst)
{
    int n = blockIdx.x * 4 + (threadIdx.x >> 6);
    if (n >= Ndst) return;
    int lane = threadIdx.x & 63;
    int beg = rowptr[n], end = rowptr[n + 1];
    const float4 ed4 = *reinterpret_cast<const float4*>(&edv[(size_t)n * 4]);

    float m0 = -1e30f, m1 = -1e30f, m2 = -1e30f, m3 = -1e30f;
    for (int i = beg; i < end; ++i) {
        int sn = cols[i];
        float4 e4 = *reinterpret_cast<const float4*>(&es[(size_t)sn * 4]);
        float v0 = e4.x + ed4.x; v0 = v0 > 0.f ? v0 : 0.2f * v0;
        float v1 = e4.y + ed4.y; v1 = v1 > 0.f ? v1 : 0.2f * v1;
        float v2 = e4.z + ed4.z; v2 = v2 > 0.f ? v2 : 0.2f * v2;
        float v3 = e4.w + ed4.w; v3 = v3 > 0.f ? v3 : 0.2f * v3;
        m0 = fmaxf(m0, v0); m1 = fmaxf(m1, v1);
        m2 = fmaxf(m2, v2); m3 = fmaxf(m3, v3);
    }

    float den0 = 0.f, den1 = 0.f, den2 = 0.f, den3 = 0.f;
    float acc0 = 0.f, acc1 = 0.f;
    for (int i = beg; i < end; ++i) {
        int sn = cols[i];
        float4 e4 = *reinterpret_cast<const float4*>(&es[(size_t)sn * 4]);
        float v0 = e4.x + ed4.x; v0 = v0 > 0.f ? v0 : 0.2f * v0;
        float v1 = e4.y + ed4.y; v1 = v1 > 0.f ? v1 : 0.2f * v1;
        float v2 = e4.z + ed4.z; v2 = v2 > 0.f ? v2 : 0.2f * v2;
        float v3 = e4.w + ed4.w; v3 = v3 > 0.f ? v3 : 0.2f * v3;
        float w0 = expf(v0 - m0); den0 += w0;
        float w1 = expf(v1 - m1); den1 += w1;
        float w2 = expf(v2 - m2); den2 += w2;
        float w3 = expf(v3 - m3); den3 += w3;
        const float* hp = hs + (size_t)sn * 128;
        float wA = (lane < 32) ? w0 : w1;
        float wB = (lane < 32) ? w2 : w3;
        acc0 = fmaf(wA, hp[lane], acc0);
        acc1 = fmaf(wB, hp[64 + lane], acc1);
    }
    den0 += 1e-16f; den1 += 1e-16f; den2 += 1e-16f; den3 += 1e-16f;
    float d0 = lane < 32 ? den0 : den1;
    float d1 = lane < 32 ? den2 : den3;
    float v0 = fmaxf(acc0 / d0 + bias[lane], 0.f);
    float v1 = fmaxf(acc1 / d1 + bias[64 + lane], 0.f);
    float sum = v0 + __shfl_xor(v0, 32, 64) + v1 + __shfl_xor(v1, 32, 64);
    if (lane < 32) out[(size_t)n * 32 + lane] = 0.25f * sum;
}

// ---------------- per-node classifier tables (penalty folded in) ----------
__global__ __launch_bounds__(256) void fc1_halves_kernel(
    const float* __restrict__ xd, const float* __restrict__ xl,
    const float* __restrict__ fc1W,
    const float* __restrict__ penWd, const float* __restrict__ penbd,
    const float* __restrict__ penWl, const float* __restrict__ penbl,
    float* __restrict__ Ad, float* __restrict__ Bl, int N)
{
    int wid = (blockIdx.x * 256 + threadIdx.x) >> 6;
    if (wid >= 2 * N) return;
    int lane = threadIdx.x & 63;
    bool isl = wid >= N;
    int n = isl ? wid - N : wid;
    const float* x = (isl ? xl : xd) + (size_t)n * 32;
    const float* pW = isl ? penWl : penWd;
    float pb = isl ? penbl[0] : penbd[0];

    float pp = x[lane & 31] * pW[lane & 31];
    pp += __shfl_xor(pp, 1, 64);
    pp += __shfl_xor(pp, 2, 64);
    pp += __shfl_xor(pp, 4, 64);
    pp += __shfl_xor(pp, 8, 64);
    pp += __shfl_xor(pp, 16, 64);
    float s = expf(pp + pb);

    const float* W = fc1W + (isl ? 32 * 64 : 0);
    float acc = 0.f;
#pragma unroll
    for (int k = 0; k < 32; ++k)
        acc = fmaf(x[k], W[k * 64 + lane], acc);
    (isl ? Bl : Ad)[(size_t)n * 64 + lane] = s * acc;
}

// ---------------- link classifier: table gather + reduce ------------------
__global__ __launch_bounds__(256) void link_kernel(
    const float* __restrict__ Ad, const float* __restrict__ Bl,
    const int* __restrict__ eli,
    const float* __restrict__ fc1b, const float* __restrict__ fc2W,
    const float* __restrict__ fc2b,
    float* __restrict__ out, int EL)
{
    int wid = (blockIdx.x * 256 + threadIdx.x) >> 6;
    if (wid >= EL) return;
    int lane = threadIdx.x & 63;
    int e0 = eli[wid];
    int e1 = eli[EL + wid];
    float v = Ad[(size_t)e0 * 64 + lane] + Bl[(size_t)e1 * 64 + lane] + fc1b[lane];
    v = fmaxf(v, 0.f);
    float p = v * fc2W[lane];
#pragma unroll
    for (int off = 32; off >= 1; off >>= 1) p += __shfl_xor(p, off, 64);
    if (lane == 0) out[wid] = p + fc2b[0];
}

// ---------------------------------------------------------------------------
extern "C" void kernel_launch(void* const* d_in, const int* in_sizes, int n_in,
                              void* d_out, int out_size, void* d_ws, size_t ws_size,
                              hipStream_t stream)
{
    const int N  = in_sizes[6] / 128;
    const int Kd = in_sizes[2] / 128;   // 412
    const int Kl = in_sizes[4] / 128;   // 240
    const int KdP = (Kd + 31) & ~31;    // 416
    const int KlP = (Kl + 31) & ~31;    // 256
    const int E  = in_sizes[48] / 2;
    const int EL = in_sizes[49] / 2;

    const float* x_d    = (const float*)d_in[0];
    const float* x_l    = (const float*)d_in[1];
    const float* Wd_lin = (const float*)d_in[2];
    const float* bd_lin = (const float*)d_in[3];
    const float* Wl_lin = (const float*)d_in[4];
    const float* bl_lin = (const float*)d_in[5];
    const float* emb_d  = (const float*)d_in[6];
    const float* emb_l  = (const float*)d_in[7];

    const float *gWs[6], *gWd[6], *gas[6], *gad[6], *gb[6];
    for (int g = 0; g < 6; ++g) {
        gWs[g] = (const float*)d_in[8 + 5 * g + 0];
        gWd[g] = (const float*)d_in[8 + 5 * g + 1];
        gas[g] = (const float*)d_in[8 + 5 * g + 2];
        gad[g] = (const float*)d_in[8 + 5 * g + 3];
        gb[g]  = (const float*)d_in[8 + 5 * g + 4];
    }
    const float* pen_Wd = (const float*)d_in[38];
    const float* pen_bd = (const float*)d_in[39];
    const float* pen_Wl = (const float*)d_in[40];
    const float* pen_bl = (const float*)d_in[41];
    const float* fc1W   = (const float*)d_in[42];
    const float* fc1b   = (const float*)d_in[43];
    const float* fc2W   = (const float*)d_in[44];
    const float* fc2b   = (const float*)d_in[45];
    const int* node_id_d = (const int*)d_in[46];
    const int* node_id_l = (const int*)d_in[47];
    const int* ei  = (const int*)d_in[48];
    const int* eli = (const int*)d_in[49];
    const int* s_arr = ei;
    const int* t_arr = ei + E;

    // ---- workspace carve-up ----
    char* ws = (char*)d_ws;
    size_t off = 0;
    auto alloc = [&](size_t bytes) -> char* {
        char* p = ws + off;
        off = (off + bytes + 255) & ~(size_t)255;
        return p;
    };
    float* bufd0 = (float*)alloc((size_t)N * 128 * 4);
    float* bufd1 = (float*)alloc((size_t)N * 128 * 4);
    float* bufl0 = (float*)alloc((size_t)N * 128 * 4);
    float* bufl1 = (float*)alloc((size_t)N * 128 * 4);
    // region1 (N*2048 B): input-d planes | agg planes (2 x N*512 u16) | hs (N*128 f32)
    char* region1 = alloc((size_t)N * 512 * 4);
    u16* pxd_in = (u16*)region1;
    u16* aggp   = (u16*)region1;
    float* hs   = (float*)region1;
    // region2 (N*1024 B): input-l planes | layer-3 feature planes
    char* region2 = alloc((size_t)N * 1024);
    u16* pxl_in = (u16*)region2;
    u16* pxd = (u16*)region2;
    u16* pxl = (u16*)(region2 + (size_t)N * 512);
    // weight planes
    u16* btWd = (u16*)alloc((size_t)2 * 128 * KdP * 2);
    u16* btWl = (u16*)alloc((size_t)2 * 128 * KlP * 2);
    u16* btWs[6];
    for (int g = 0; g < 6; ++g) {
        int J = (g < 4) ? 512 : 128;
        btWs[g] = (u16*)alloc((size_t)2 * J * 128 * 2);
    }
    float* es1  = (float*)alloc((size_t)N * 4 * 4);
    float* ed1  = (float*)alloc((size_t)N * 4 * 4);
    float* es2  = (float*)alloc((size_t)N * 4 * 4);
    float* ed2  = (float*)alloc((size_t)N * 4 * 4);
    float* Uall = (float*)alloc((size_t)6 * 1024 * 4);
    int* rpt_t = (int*)alloc((size_t)(N + 1) * 4);
    int* rpt_s = (int*)alloc((size_t)(N + 1) * 4);
    int* deg_t = (int*)alloc((size_t)N * 4);
    int* deg_s = (int*)alloc((size_t)N * 4);
    int* cur_t = (int*)alloc((size_t)N * 4);
    int* cur_s = (int*)alloc((size_t)N * 4);
    int* col_t = (int*)alloc((size_t)E * 4);
    int* col_s = (int*)alloc((size_t)E * 4);
    int* bs_t  = (int*)alloc(256 * 4);
    int* bs_s  = (int*)alloc(256 * 4);
    int* bo_t  = (int*)alloc(257 * 4);
    int* bo_s  = (int*)alloc(257 * 4);
    float* Ad  = (float*)alloc((size_t)N * 64 * 4);
    float* Bl  = (float*)alloc((size_t)N * 64 * 4);
    (void)ws_size;

    hipMemsetAsync(deg_t, 0, (size_t)N * 4, stream);
    hipMemsetAsync(deg_s, 0, (size_t)N * 4, stream);
    hipMemsetAsync(cur_t, 0, (size_t)N * 4, stream);
    hipMemsetAsync(cur_s, 0, (size_t)N * 4, stream);

    dim3 blk(256);
    const int nMB = (N + 127) / 128;

    // ---- input splits (planes) ----
    splitX<<<dim3((N * (KdP >> 2) + 255) / 256), blk, 0, stream>>>(x_d, N, Kd, KdP, pxd_in);
    splitX<<<dim3((N * (KlP >> 2) + 255) / 256), blk, 0, stream>>>(x_l, N, Kl, KlP, pxl_in);
    splitBt<<<dim3((128 * KdP + 255) / 256), blk, 0, stream>>>(Wd_lin, Kd, KdP, 128, btWd);
    splitBt<<<dim3((128 * KlP + 255) / 256), blk, 0, stream>>>(Wl_lin, Kl, KlP, 128, btWl);
    for (int g = 0; g < 6; ++g) {
        int J = (g < 4) ? 512 : 128;
        splitBt<<<dim3((J * 128 + 255) / 256), blk, 0, stream>>>(gWs[g], 128, 128, J, btWs[g]);
    }

    {
        UParams up;
        for (int g = 0; g < 6; ++g) {
            up.Ws[g] = gWs[g]; up.Wd[g] = gWd[g];
            up.as_[g] = gas[g]; up.ad_[g] = gad[g];
            up.C[g] = (g < 4) ? 128 : 32;
        }
        compute_U<<<dim3(6), blk, 0, stream>>>(up, Uall);
    }

    // CSR for both directions
    {
        deg_kernel<<<dim3((E + 255) / 256), blk, 0, stream>>>(s_arr, t_arr, deg_t, deg_s, E);
        int nb = (N + 255) / 256;
        scan_partial<<<dim3(nb, 2), blk, 0, stream>>>(deg_t, deg_s, rpt_t, rpt_s, bs_t, bs_s, N);
        scan_bsums<<<dim3(1, 2), blk, 0, stream>>>(bs_t, bs_s, bo_t, bo_s, nb);
        scan_add<<<dim3(nb, 2), blk, 0, stream>>>(rpt_t, rpt_s, bo_t, bo_s, N, nb);
        fill_kernel<<<dim3((E + 255) / 256), blk, 0, stream>>>(s_arr, t_arr, rpt_t, rpt_s,
                                                               cur_t, cur_s, col_t, col_s, E);
    }

    // ---- input linears (+bias +embedding gather) ----
    gemm_mfma<true><<<dim3(nMB, 1), blk, 0, stream>>>(
        pxd_in, btWd, bd_lin, emb_d, node_id_d, bufd0, N, KdP, 128);
    gemm_mfma<true><<<dim3(nMB, 1), blk, 0, stream>>>(
        pxl_in, btWl, bl_lin, emb_l, node_id_l, bufl0, N, KlP, 128);

    float* xd_cur = bufd0; float* xl_cur = bufl0;
    float* xd_nxt = bufd1; float* xl_nxt = bufl1;

    // ---- layers 1-2: commuted path (aggregate x, then head-GEMM) ----
    for (int L = 0; L < 2; ++L) {
        const int gd = 2 * L, gl = 2 * L + 1;

        es_ed2_kernel<<<dim3((N * 16 + 255) / 256), blk, 0, stream>>>(
            xd_cur, xl_cur, Uall + gd * 1024, Uall + gl * 1024,
            es1, ed1, es2, ed2, N);

        // d2l: src = xd side, dst = xl side
        agg_x<<<dim3((N + 3) / 4), blk, 0, stream>>>(
            rpt_t, col_t, xd_cur, es1, ed1, aggp, N);
        gemm_heads<<<dim3(nMB), blk, 0, stream>>>(
            aggp, btWs[gd], gb[gd], xl_nxt, N);

        // l2d: src = xl side, dst = xd side
        agg_x<<<dim3((N + 3) / 4), blk, 0, stream>>>(
            rpt_s, col_s, xl_cur, es2, ed2, aggp, N);
        gemm_heads<<<dim3(nMB), blk, 0, stream>>>(
            aggp, btWs[gl], gb[gl], xd_nxt, N);

        float* tmp;
        tmp = xd_cur; xd_cur = xd_nxt; xd_nxt = tmp;
        tmp = xl_cur; xl_cur = xl_nxt; xl_nxt = tmp;
    }

    // ---- layer 3: direct path (hs is only N x 128) ----
    {
        const int gd = 4, gl = 5;
        splitX<<<dim3((N * 32 + 255) / 256), blk, 0, stream>>>(xd_cur, N, 128, 128, pxd);
        splitX<<<dim3((N * 32 + 255) / 256), blk, 0, stream>>>(xl_cur, N, 128, 128, pxl);

        es_ed2_kernel<<<dim3((N * 16 + 255) / 256), blk, 0, stream>>>(
            xd_cur, xl_cur, Uall + gd * 1024, Uall + gl * 1024,
            es1, ed1, es2, ed2, N);

        gemm_mfma<false><<<dim3(nMB, 1), blk, 0, stream>>>(
            pxd, btWs[gd], nullptr, nullptr, nullptr, hs, N, 128, 128);
        gat_agg128<<<dim3((N + 3) / 4), blk, 0, stream>>>(
            rpt_t, col_t, hs, es1, ed1, gb[gd], xl_nxt, N);

        gemm_mfma<false><<<dim3(nMB, 1), blk, 0, stream>>>(
            pxl, btWs[gl], nullptr, nullptr, nullptr, hs, N, 128, 128);
        gat_agg128<<<dim3((N + 3) / 4), blk, 0, stream>>>(
            rpt_s, col_s, hs, es2, ed2, gb[gl], xd_nxt, N);

        float* tmp;
        tmp = xd_cur; xd_cur = xd_nxt; xd_nxt = tmp;
        tmp = xl_cur; xl_cur = xl_nxt; xl_nxt = tmp;
    }

    // classifier: per-node tables (penalty folded), then per-edge gather
    fc1_halves_kernel<<<dim3((2 * N * 64 + 255) / 256), blk, 0, stream>>>(
        xd_cur, xl_cur, fc1W, pen_Wd, pen_bd, pen_Wl, pen_bl, Ad, Bl, N);
    link_kernel<<<dim3((EL + 3) / 4), blk, 0, stream>>>(
        Ad, Bl, eli, fc1b, fc2W, fc2b, (float*)d_out, EL);
}

// Round 5
// 1189.696 us; speedup vs baseline: 2.2547x; 1.0761x over previous
//
#include <hip/hip_runtime.h>
#include <hip/hip_bf16.h>
#include <math.h>

typedef unsigned short u16;
typedef __bf16 bf16x8 __attribute__((ext_vector_type(8)));
typedef float f32x4 __attribute__((ext_vector_type(4)));

// ---------------------------------------------------------------------------
// Hetero-GAT forward, bf16 hi/lo split MFMA.
// Key algebra: alpha depends only on es/ed (linear in x), so for layers 1-2
//   out[dst] = (sum_e alpha_e x[src_e]) @ Ws      (commute agg <-> GEMM)
// -> aggregate 128-dim x per head (512B/edge gather, 25.6MB table), then a
//    head-blocked GEMM with fused +bias/relu/head-mean epilogue.
// hs (N x 512) is never materialized for layers 1-2.
// ---------------------------------------------------------------------------

__device__ inline float bfbits2f(u16 u) {
    unsigned int v = ((unsigned int)u) << 16;
    float f;
    __builtin_memcpy(&f, &v, 4);
    return f;
}
__device__ inline u16 f2bf(float x) {
    __hip_bfloat16 h = __float2bfloat16(x);
    u16 u;
    __builtin_memcpy(&u, &h, 2);
    return u;
}

#define GLD16(gp, lp) __builtin_amdgcn_global_load_lds( \
    (__attribute__((address_space(1))) void*)(gp),      \
    (__attribute__((address_space(3))) void*)(lp), 16, 0, 0)

// ---------------- split fp32 -> bf16 hi/lo planes (K padded to Kp) ---------
__global__ void splitX(const float* __restrict__ x, int N, int K, int Kp,
                       u16* __restrict__ hi)
{
    u16* lo = hi + (size_t)N * Kp;
    int nk4 = Kp >> 2;
    int t = blockIdx.x * 256 + threadIdx.x;
    if (t >= N * nk4) return;
    int n = t / nk4;
    int k4 = (t - n * nk4) << 2;
    u16 h[4], l[4];
#pragma unroll
    for (int j = 0; j < 4; ++j) {
        int k = k4 + j;
        float xv = (k < K) ? x[(size_t)n * K + k] : 0.f;
        u16 hb = f2bf(xv);
        h[j] = hb;
        l[j] = f2bf(xv - bfbits2f(hb));
    }
    uint2 hp, lp;
    hp.x = (unsigned)h[0] | ((unsigned)h[1] << 16);
    hp.y = (unsigned)h[2] | ((unsigned)h[3] << 16);
    lp.x = (unsigned)l[0] | ((unsigned)l[1] << 16);
    lp.y = (unsigned)l[2] | ((unsigned)l[3] << 16);
    *reinterpret_cast<uint2*>(&hi[(size_t)n * Kp + k4]) = hp;
    *reinterpret_cast<uint2*>(&lo[(size_t)n * Kp + k4]) = lp;
}

// ---------------- weight: (K x J) fp32 -> transposed bf16 planes (J x Kp) --
__global__ void splitBt(const float* __restrict__ B, int K, int Kp, int J,
                        u16* __restrict__ hi)
{
    int t = blockIdx.x * 256 + threadIdx.x;
    if (t >= J * Kp) return;
    int col = t / Kp, k = t - col * Kp;
    float v = (k < K) ? B[(size_t)k * J + col] : 0.f;
    u16 hb = f2bf(v);
    hi[t] = hb;
    hi[(size_t)J * Kp + t] = f2bf(v - bfbits2f(hb));
}

// ---------------- MFMA GEMM: C(NxJ) = A(NxKp) @ Bt(JxKp)^T, 3-term split ---
template<bool BIAS_EMB>
__global__ __launch_bounds__(256) void gemm_mfma(
    const u16* __restrict__ Ahi,
    const u16* __restrict__ Bhi,
    const float* __restrict__ bias,
    const float* __restrict__ emb,
    const int* __restrict__ ids,
    float* __restrict__ C,
    int N, int Kp, int J)
{
    __shared__ __align__(16) u16 sA[4096];
    __shared__ __align__(16) u16 sB[4096];
    const int tid = threadIdx.x;
    const int lane = tid & 63;
    const int wid = tid >> 6;
    const int wr = wid >> 1, wc = wid & 1;
    const int rowbase = blockIdx.x * 128;
    const int colbase = blockIdx.y * 128;

    const size_t planeA = (size_t)N * Kp;
    const size_t planeB = (size_t)J * Kp;
    const int nk = Kp / 32;

    const int akc = tid & 3;
    const int arow0 = tid >> 2;
    const int arow1 = 64 + (tid >> 2);
    const int swz = (arow0 >> 1) & 3;
    int gr0 = rowbase + arow0; if (gr0 >= N) gr0 = N - 1;
    int gr1 = rowbase + arow1; if (gr1 >= N) gr1 = N - 1;
    const size_t aoff0 = (size_t)gr0 * Kp + (size_t)((akc ^ swz) * 8);
    const size_t aoff1 = (size_t)gr1 * Kp + (size_t)((akc ^ swz) * 8);
    const size_t boff0 = (size_t)(colbase + arow0) * Kp + (size_t)((akc ^ swz) * 8);
    const size_t boff1 = (size_t)(colbase + arow1) * Kp + (size_t)((akc ^ swz) * 8);

    const int kgs = ((lane >> 4) ^ ((lane >> 1) & 3)) * 8;
    const int arow_rd = wr * 64 + (lane & 15);
    const int brow_rd = wc * 64 + (lane & 15);

    f32x4 acc[4][4] = {};

    for (int term = 0; term < 3; ++term) {
        const u16* Ap = (term < 2) ? Ahi : (Ahi + planeA);
        const u16* Bp = (term == 1) ? (Bhi + planeB) : Bhi;
        for (int ks = 0; ks < nk; ++ks) {
            const int k0 = ks * 32;
            GLD16(Ap + aoff0 + k0, &sA[(size_t)tid * 8]);
            GLD16(Ap + aoff1 + k0, &sA[(size_t)(tid + 256) * 8]);
            GLD16(Bp + boff0 + k0, &sB[(size_t)tid * 8]);
            GLD16(Bp + boff1 + k0, &sB[(size_t)(tid + 256) * 8]);
            __syncthreads();
            bf16x8 af[4], bfq[4];
#pragma unroll
            for (int m = 0; m < 4; ++m)
                af[m] = *reinterpret_cast<const bf16x8*>(&sA[(arow_rd + m * 16) * 32 + kgs]);
#pragma unroll
            for (int n = 0; n < 4; ++n)
                bfq[n] = *reinterpret_cast<const bf16x8*>(&sB[(brow_rd + n * 16) * 32 + kgs]);
#pragma unroll
            for (int m = 0; m < 4; ++m)
#pragma unroll
                for (int n = 0; n < 4; ++n)
                    acc[m][n] = __builtin_amdgcn_mfma_f32_16x16x32_bf16(
                        af[m], bfq[n], acc[m][n], 0, 0, 0);
            __syncthreads();
        }
    }

#pragma unroll
    for (int m = 0; m < 4; ++m) {
        int rb = rowbase + wr * 64 + m * 16 + ((lane >> 4) << 2);
#pragma unroll
        for (int i = 0; i < 4; ++i) {
            int r = rb + i;
            if (r >= N) continue;
            const float* ep = nullptr;
            if (BIAS_EMB) ep = emb + (size_t)ids[r] * 128;
#pragma unroll
            for (int n = 0; n < 4; ++n) {
                int col = colbase + wc * 64 + n * 16 + (lane & 15);
                float v = acc[m][n][i];
                if (BIAS_EMB) v += bias[col] + ep[col];
                C[(size_t)r * J + col] = v;
            }
        }
    }
}

// ---------------- head-blocked GEMM with fused relu/head-mean epilogue -----
__global__ __launch_bounds__(256) void gemm_heads(
    const u16* __restrict__ Ahi,
    const u16* __restrict__ Bhi,
    const float* __restrict__ bias,
    float* __restrict__ C,
    int N)
{
    __shared__ __align__(16) u16 sAh[4096];
    __shared__ __align__(16) u16 sAl[4096];
    __shared__ __align__(16) u16 sBh[4096];
    __shared__ __align__(16) u16 sBl[4096];
    const int tid = threadIdx.x;
    const int lane = tid & 63;
    const int wid = tid >> 6;
    const int wr = wid >> 1, wc = wid & 1;
    const int rowbase = blockIdx.x * 128;

    const u16* Alo = Ahi + (size_t)N * 512;
    const u16* Blo = Bhi + (size_t)512 * 128;

    const int akc = tid & 3;
    const int arow0 = tid >> 2;
    const int arow1 = 64 + arow0;
    const int swz = (arow0 >> 1) & 3;
    int gr0 = rowbase + arow0; if (gr0 >= N) gr0 = N - 1;
    int gr1 = rowbase + arow1; if (gr1 >= N) gr1 = N - 1;
    const size_t aoff0 = (size_t)gr0 * 512 + (size_t)((akc ^ swz) * 8);
    const size_t aoff1 = (size_t)gr1 * 512 + (size_t)((akc ^ swz) * 8);
    const size_t boff0 = (size_t)arow0 * 128 + (size_t)((akc ^ swz) * 8);
    const size_t boff1 = (size_t)arow1 * 128 + (size_t)((akc ^ swz) * 8);

    const int kgs = ((lane >> 4) ^ ((lane >> 1) & 3)) * 8;
    const int arow_rd = wr * 64 + (lane & 15);
    const int brow_rd = wc * 64 + (lane & 15);

    f32x4 acc[4][4] = {};
    f32x4 runsum[4][4] = {};

    for (int h = 0; h < 4; ++h) {
        const size_t ha = (size_t)h * 128;
        const size_t hb = (size_t)h * 128 * 128;
#pragma unroll
        for (int ks = 0; ks < 4; ++ks) {
            const int k0 = ks * 32;
            GLD16(Ahi + aoff0 + ha + k0, &sAh[(size_t)tid * 8]);
            GLD16(Ahi + aoff1 + ha + k0, &sAh[(size_t)(tid + 256) * 8]);
            GLD16(Alo + aoff0 + ha + k0, &sAl[(size_t)tid * 8]);
            GLD16(Alo + aoff1 + ha + k0, &sAl[(size_t)(tid + 256) * 8]);
            GLD16(Bhi + boff0 + hb + k0, &sBh[(size_t)tid * 8]);
            GLD16(Bhi + boff1 + hb + k0, &sBh[(size_t)(tid + 256) * 8]);
            GLD16(Blo + boff0 + hb + k0, &sBl[(size_t)tid * 8]);
            GLD16(Blo + boff1 + hb + k0, &sBl[(size_t)(tid + 256) * 8]);
            __syncthreads();
            bf16x8 bh[4], bl[4];
#pragma unroll
            for (int n = 0; n < 4; ++n) {
                bh[n] = *reinterpret_cast<const bf16x8*>(&sBh[(brow_rd + n * 16) * 32 + kgs]);
                bl[n] = *reinterpret_cast<const bf16x8*>(&sBl[(brow_rd + n * 16) * 32 + kgs]);
            }
#pragma unroll
            for (int m = 0; m < 4; ++m) {
                bf16x8 ah = *reinterpret_cast<const bf16x8*>(&sAh[(arow_rd + m * 16) * 32 + kgs]);
                bf16x8 al = *reinterpret_cast<const bf16x8*>(&sAl[(arow_rd + m * 16) * 32 + kgs]);
#pragma unroll
                for (int n = 0; n < 4; ++n) {
                    acc[m][n] = __builtin_amdgcn_mfma_f32_16x16x32_bf16(ah, bh[n], acc[m][n], 0, 0, 0);
                    acc[m][n] = __builtin_amdgcn_mfma_f32_16x16x32_bf16(ah, bl[n], acc[m][n], 0, 0, 0);
                    acc[m][n] = __builtin_amdgcn_mfma_f32_16x16x32_bf16(al, bh[n], acc[m][n], 0, 0, 0);
                }
            }
            __syncthreads();
        }
#pragma unroll
        for (int m = 0; m < 4; ++m)
#pragma unroll
            for (int n = 0; n < 4; ++n) {
                int col = wc * 64 + n * 16 + (lane & 15);
                float b = bias[h * 128 + col];
#pragma unroll
                for (int i = 0; i < 4; ++i) {
                    runsum[m][n][i] += fmaxf(acc[m][n][i] + b, 0.f);
                    acc[m][n][i] = 0.f;
                }
            }
    }

#pragma unroll
    for (int m = 0; m < 4; ++m) {
        int rb = rowbase + wr * 64 + m * 16 + ((lane >> 4) << 2);
#pragma unroll
        for (int i = 0; i < 4; ++i) {
            int r = rb + i;
            if (r >= N) continue;
#pragma unroll
            for (int n = 0; n < 4; ++n) {
                int col = wc * 64 + n * 16 + (lane & 15);
                C[(size_t)r * 128 + col] = 0.25f * runsum[m][n][i];
            }
        }
    }
}

// ---------------- U = [Ws @ a_s | Wd @ a_d] per head: (128 x 8) per GAT ----
// One wave per output element (6*1024 outputs); lanes stride the C dim.
struct UParams {
    const float* Ws[6];
    const float* Wd[6];
    const float* as_[6];
    const float* ad_[6];
    int C[6];
};

__global__ __launch_bounds__(256) void compute_U(UParams P, float* __restrict__ U)
{
    int w = (blockIdx.x * 256 + threadIdx.x) >> 6;    // 0..6143
    if (w >= 6144) return;
    int lane = threadIdx.x & 63;
    int g = w >> 10;
    int o = w & 1023;
    int k = o >> 3, j = o & 7, h = j & 3;
    int C = P.C[g];
    int HC = 4 * C;
    const float* W = (j < 4) ? P.Ws[g] : P.Wd[g];
    const float* a = (j < 4) ? P.as_[g] : P.ad_[g];
    float s = 0.f;
    for (int c = lane; c < C; c += 64)
        s = fmaf(W[k * HC + h * C + c], a[h * C + c], s);
#pragma unroll
    for (int off = 32; off >= 1; off >>= 1) s += __shfl_xor(s, off, 64);
    if (lane == 0) U[g * 1024 + o] = s;
}

// ---------------- fused es/ed for BOTH directions of one layer ------------
__global__ void es_ed2_kernel(const float* __restrict__ xd, const float* __restrict__ xl,
                              const float* __restrict__ U1, const float* __restrict__ U2,
                              float* __restrict__ es1, float* __restrict__ ed1,
                              float* __restrict__ es2, float* __restrict__ ed2, int N)
{
    int t = blockIdx.x * blockDim.x + threadIdx.x;
    if (t >= N * 16) return;
    int n = t >> 4, j = t & 15;
    const float4* X4 = reinterpret_cast<const float4*>(((j < 8) ? xd : xl) + (size_t)n * 128);
    const float* U;
    float* dst;
    int col;
    if (j < 4)       { U = U1; col = j;      dst = &es1[n * 4 + j]; }
    else if (j < 8)  { U = U2; col = j;      dst = &ed2[n * 4 + (j - 4)]; }
    else if (j < 12) { U = U1; col = j - 4;  dst = &ed1[n * 4 + (j - 8)]; }
    else             { U = U2; col = j - 12; dst = &es2[n * 4 + (j - 12)]; }
    float s = 0.f;
#pragma unroll 8
    for (int k4 = 0; k4 < 32; ++k4) {
        float4 x = X4[k4];
        s = fmaf(x.x, U[(k4 * 4 + 0) * 8 + col], s);
        s = fmaf(x.y, U[(k4 * 4 + 1) * 8 + col], s);
        s = fmaf(x.z, U[(k4 * 4 + 2) * 8 + col], s);
        s = fmaf(x.w, U[(k4 * 4 + 3) * 8 + col], s);
    }
    *dst = s;
}

// ---------------- CSR build (stores src-node column indices directly) -----
__global__ void deg_kernel(const int* __restrict__ s, const int* __restrict__ t,
                           int* __restrict__ deg_t, int* __restrict__ deg_s, int E)
{
    int i = blockIdx.x * blockDim.x + threadIdx.x;
    if (i >= E) return;
    atomicAdd(&deg_t[t[i]], 1);
    atomicAdd(&deg_s[s[i]], 1);
}

__global__ void scan_partial(const int* dA, const int* dB, int* eA, int* eB,
                             int* bsA, int* bsB, int N)
{
    __shared__ int lds[256];
    const int* deg = blockIdx.y ? dB : dA;
    int* ex = blockIdx.y ? eB : eA;
    int* bs = blockIdx.y ? bsB : bsA;
    int i = blockIdx.x * 256 + threadIdx.x;
    int v = (i < N) ? deg[i] : 0;
    int x = v;
    lds[threadIdx.x] = x;
    __syncthreads();
    for (int off = 1; off < 256; off <<= 1) {
        int tv = (threadIdx.x >= off) ? lds[threadIdx.x - off] : 0;
        __syncthreads();
        x += tv;
        lds[threadIdx.x] = x;
        __syncthreads();
    }
    if (i < N) ex[i] = x - v;
    if (threadIdx.x == 255) bs[blockIdx.x] = x;
}

__global__ void scan_bsums(int* bsA, int* bsB, int* boA, int* boB, int nb)
{
    __shared__ int lds[256];
    int* bs = blockIdx.y ? bsB : bsA;
    int* bo = blockIdx.y ? boB : boA;
    int v = (threadIdx.x < nb) ? bs[threadIdx.x] : 0;
    int x = v;
    lds[threadIdx.x] = x;
    __syncthreads();
    for (int off = 1; off < 256; off <<= 1) {
        int tv = (threadIdx.x >= off) ? lds[threadIdx.x - off] : 0;
        __syncthreads();
        x += tv;
        lds[threadIdx.x] = x;
        __syncthreads();
    }
    if (threadIdx.x < nb) bo[threadIdx.x] = x - v;
    if (threadIdx.x == 255) bo[nb] = x;
}

__global__ void scan_add(int* eA, int* eB, const int* boA, const int* boB, int N, int nb)
{
    int* ex = blockIdx.y ? eB : eA;
    const int* bo = blockIdx.y ? boB : boA;
    int i = blockIdx.x * 256 + threadIdx.x;
    if (i < N) ex[i] += bo[i >> 8];
    if (i == 0) ex[N] = bo[nb];
}

__global__ void fill_kernel(const int* __restrict__ s, const int* __restrict__ t,
                            const int* __restrict__ rpt_t, const int* __restrict__ rpt_s,
                            int* __restrict__ cur_t, int* __restrict__ cur_s,
                            int* __restrict__ col_t, int* __restrict__ col_s, int E)
{
    int i = blockIdx.x * blockDim.x + threadIdx.x;
    if (i >= E) return;
    int sv = s[i], tv = t[i];
    int p = atomicAdd(&cur_t[tv], 1);
    col_t[rpt_t[tv] + p] = sv;
    p = atomicAdd(&cur_s[sv], 1);
    col_s[rpt_s[sv] + p] = tv;
}

// ---------------- per-head x-aggregation (layers 1-2) ---------------------
__global__ __launch_bounds__(256) void agg_x(
    const int* __restrict__ rowptr, const int* __restrict__ cols,
    const float* __restrict__ xsrc,   // Nsrc x 128 fp32
    const float* __restrict__ es,     // Nsrc x 4
    const float* __restrict__ edv,    // Ndst x 4
    u16* __restrict__ aggp,           // hi plane; lo at +Ndst*512
    int Ndst)
{
    int n = blockIdx.x * 4 + (threadIdx.x >> 6);
    if (n >= Ndst) return;
    int lane = threadIdx.x & 63;
    int beg = rowptr[n], end = rowptr[n + 1];
    const float4 ed4 = *reinterpret_cast<const float4*>(&edv[(size_t)n * 4]);

    float m0 = -1e30f, m1 = -1e30f, m2 = -1e30f, m3 = -1e30f;
    for (int i = beg; i < end; ++i) {
        int sn = cols[i];
        float4 e4 = *reinterpret_cast<const float4*>(&es[(size_t)sn * 4]);
        float v0 = e4.x + ed4.x; v0 = v0 > 0.f ? v0 : 0.2f * v0;
        float v1 = e4.y + ed4.y; v1 = v1 > 0.f ? v1 : 0.2f * v1;
        float v2 = e4.z + ed4.z; v2 = v2 > 0.f ? v2 : 0.2f * v2;
        float v3 = e4.w + ed4.w; v3 = v3 > 0.f ? v3 : 0.2f * v3;
        m0 = fmaxf(m0, v0); m1 = fmaxf(m1, v1);
        m2 = fmaxf(m2, v2); m3 = fmaxf(m3, v3);
    }

    float den0 = 0.f, den1 = 0.f, den2 = 0.f, den3 = 0.f;
    float a00 = 0.f, a01 = 0.f, a02 = 0.f, a03 = 0.f;
    float a10 = 0.f, a11 = 0.f, a12 = 0.f, a13 = 0.f;

    for (int i = beg; i < end; ++i) {
        int sn = cols[i];
        float4 e4 = *reinterpret_cast<const float4*>(&es[(size_t)sn * 4]);
        float v0 = e4.x + ed4.x; v0 = v0 > 0.f ? v0 : 0.2f * v0;
        float v1 = e4.y + ed4.y; v1 = v1 > 0.f ? v1 : 0.2f * v1;
        float v2 = e4.z + ed4.z; v2 = v2 > 0.f ? v2 : 0.2f * v2;
        float v3 = e4.w + ed4.w; v3 = v3 > 0.f ? v3 : 0.2f * v3;
        float w0 = expf(v0 - m0); den0 += w0;
        float w1 = expf(v1 - m1); den1 += w1;
        float w2 = expf(v2 - m2); den2 += w2;
        float w3 = expf(v3 - m3); den3 += w3;
        const float* xp = xsrc + (size_t)sn * 128;
        float x0 = xp[lane];
        float x1 = xp[64 + lane];
        a00 = fmaf(w0, x0, a00); a10 = fmaf(w0, x1, a10);
        a01 = fmaf(w1, x0, a01); a11 = fmaf(w1, x1, a11);
        a02 = fmaf(w2, x0, a02); a12 = fmaf(w2, x1, a12);
        a03 = fmaf(w3, x0, a03); a13 = fmaf(w3, x1, a13);
    }

    float i0 = 1.f / (den0 + 1e-16f);
    float i1 = 1.f / (den1 + 1e-16f);
    float i2 = 1.f / (den2 + 1e-16f);
    float i3 = 1.f / (den3 + 1e-16f);
    u16* lo = aggp + (size_t)Ndst * 512;
    size_t base = (size_t)n * 512 + lane;
    float va[8] = {a00 * i0, a01 * i1, a02 * i2, a03 * i3,
                   a10 * i0, a11 * i1, a12 * i2, a13 * i3};
#pragma unroll
    for (int h = 0; h < 4; ++h) {
        float v = va[h];
        u16 hb = f2bf(v);
        aggp[base + h * 128] = hb;
        lo[base + h * 128] = f2bf(v - bfbits2f(hb));
        float v1 = va[4 + h];
        u16 hb1 = f2bf(v1);
        aggp[base + h * 128 + 64] = hb1;
        lo[base + h * 128 + 64] = f2bf(v1 - bfbits2f(hb1));
    }
}

// ---------------- GAT aggregation for layer 3 (direct hs, HC=128) ---------
__global__ __launch_bounds__(256) void gat_agg128(
    const int* __restrict__ rowptr, const int* __restrict__ cols,
    const float* __restrict__ hs,     // Nsrc x 128
    const float* __restrict__ es,
    const float* __restrict__ edv,
    const float* __restrict__ bias,   // 128
    float* __restrict__ out,          // Ndst x 32
    int Ndst)
{
    int n = blockIdx.x * 4 + (threadIdx.x >> 6);
    if (n >= Ndst) return;
    int lane = threadIdx.x & 63;
    int beg = rowptr[n], end = rowptr[n + 1];
    const float4 ed4 = *reinterpret_cast<const float4*>(&edv[(size_t)n * 4]);

    float m0 = -1e30f, m1 = -1e30f, m2 = -1e30f, m3 = -1e30f;
    for (int i = beg; i < end; ++i) {
        int sn = cols[i];
        float4 e4 = *reinterpret_cast<const float4*>(&es[(size_t)sn * 4]);
        float v0 = e4.x + ed4.x; v0 = v0 > 0.f ? v0 : 0.2f * v0;
        float v1 = e4.y + ed4.y; v1 = v1 > 0.f ? v1 : 0.2f * v1;
        float v2 = e4.z + ed4.z; v2 = v2 > 0.f ? v2 : 0.2f * v2;
        float v3 = e4.w + ed4.w; v3 = v3 > 0.f ? v3 : 0.2f * v3;
        m0 = fmaxf(m0, v0); m1 = fmaxf(m1, v1);
        m2 = fmaxf(m2, v2); m3 = fmaxf(m3, v3);
    }

    float den0 = 0.f, den1 = 0.f, den2 = 0.f, den3 = 0.f;
    float acc0 = 0.f, acc1 = 0.f;
    for (int i = beg; i < end; ++i) {
        int sn = cols[i];
        float4 e4 = *reinterpret_cast<const float4*>(&es[(size_t)sn * 4]);
        float v0 = e4.x + ed4.x; v0 = v0 > 0.f ? v0 : 0.2f * v0;
        float v1 = e4.y + ed4.y; v1 = v1 > 0.f ? v1 : 0.2f * v1;
        float v2 = e4.z + ed4.z; v2 = v2 > 0.f ? v2 : 0.2f * v2;
        float v3 = e4.w + ed4.w; v3 = v3 > 0.f ? v3 : 0.2f * v3;
        float w0 = expf(v0 - m0); den0 += w0;
        float w1 = expf(v1 - m1); den1 += w1;
        float w2 = expf(v2 - m2); den2 += w2;
        float w3 = expf(v3 - m3); den3 += w3;
        const float* hp = hs + (size_t)sn * 128;
        float wA = (lane < 32) ? w0 : w1;
        float wB = (lane < 32) ? w2 : w3;
        acc0 = fmaf(wA, hp[lane], acc0);
        acc1 = fmaf(wB, hp[64 + lane], acc1);
    }
    den0 += 1e-16f; den1 += 1e-16f; den2 += 1e-16f; den3 += 1e-16f;
    float d0 = lane < 32 ? den0 : den1;
    float d1 = lane < 32 ? den2 : den3;
    float v0 = fmaxf(acc0 / d0 + bias[lane], 0.f);
    float v1 = fmaxf(acc1 / d1 + bias[64 + lane], 0.f);
    float sum = v0 + __shfl_xor(v0, 32, 64) + v1 + __shfl_xor(v1, 32, 64);
    if (lane < 32) out[(size_t)n * 32 + lane] = 0.25f * sum;
}

// ---------------- per-node classifier tables (penalty folded in) ----------
__global__ __launch_bounds__(256) void fc1_halves_kernel(
    const float* __restrict__ xd, const float* __restrict__ xl,
    const float* __restrict__ fc1W,
    const float* __restrict__ penWd, const float* __restrict__ penbd,
    const float* __restrict__ penWl, const float* __restrict__ penbl,
    float* __restrict__ Ad, float* __restrict__ Bl, int N)
{
    int wid = (blockIdx.x * 256 + threadIdx.x) >> 6;
    if (wid >= 2 * N) return;
    int lane = threadIdx.x & 63;
    bool isl = wid >= N;
    int n = isl ? wid - N : wid;
    const float* x = (isl ? xl : xd) + (size_t)n * 32;
    const float* pW = isl ? penWl : penWd;
    float pb = isl ? penbl[0] : penbd[0];

    float pp = x[lane & 31] * pW[lane & 31];
    pp += __shfl_xor(pp, 1, 64);
    pp += __shfl_xor(pp, 2, 64);
    pp += __shfl_xor(pp, 4, 64);
    pp += __shfl_xor(pp, 8, 64);
    pp += __shfl_xor(pp, 16, 64);
    float s = expf(pp + pb);

    const float* W = fc1W + (isl ? 32 * 64 : 0);
    float acc = 0.f;
#pragma unroll
    for (int k = 0; k < 32; ++k)
        acc = fmaf(x[k], W[k * 64 + lane], acc);
    (isl ? Bl : Ad)[(size_t)n * 64 + lane] = s * acc;
}

// ---------------- link classifier: table gather + reduce ------------------
__global__ __launch_bounds__(256) void link_kernel(
    const float* __restrict__ Ad, const float* __restrict__ Bl,
    const int* __restrict__ eli,
    const float* __restrict__ fc1b, const float* __restrict__ fc2W,
    const float* __restrict__ fc2b,
    float* __restrict__ out, int EL)
{
    int wid = (blockIdx.x * 256 + threadIdx.x) >> 6;
    if (wid >= EL) return;
    int lane = threadIdx.x & 63;
    int e0 = eli[wid];
    int e1 = eli[EL + wid];
    float v = Ad[(size_t)e0 * 64 + lane] + Bl[(size_t)e1 * 64 + lane] + fc1b[lane];
    v = fmaxf(v, 0.f);
    float p = v * fc2W[lane];
#pragma unroll
    for (int off = 32; off >= 1; off >>= 1) p += __shfl_xor(p, off, 64);
    if (lane == 0) out[wid] = p + fc2b[0];
}

// ---------------------------------------------------------------------------
extern "C" void kernel_launch(void* const* d_in, const int* in_sizes, int n_in,
                              void* d_out, int out_size, void* d_ws, size_t ws_size,
                              hipStream_t stream)
{
    const int N  = in_sizes[6] / 128;
    const int Kd = in_sizes[2] / 128;   // 412
    const int Kl = in_sizes[4] / 128;   // 240
    const int KdP = (Kd + 31) & ~31;    // 416
    const int KlP = (Kl + 31) & ~31;    // 256
    const int E  = in_sizes[48] / 2;
    const int EL = in_sizes[49] / 2;

    const float* x_d    = (const float*)d_in[0];
    const float* x_l    = (const float*)d_in[1];
    const float* Wd_lin = (const float*)d_in[2];
    const float* bd_lin = (const float*)d_in[3];
    const float* Wl_lin = (const float*)d_in[4];
    const float* bl_lin = (const float*)d_in[5];
    const float* emb_d  = (const float*)d_in[6];
    const float* emb_l  = (const float*)d_in[7];

    const float *gWs[6], *gWd[6], *gas[6], *gad[6], *gb[6];
    for (int g = 0; g < 6; ++g) {
        gWs[g] = (const float*)d_in[8 + 5 * g + 0];
        gWd[g] = (const float*)d_in[8 + 5 * g + 1];
        gas[g] = (const float*)d_in[8 + 5 * g + 2];
        gad[g] = (const float*)d_in[8 + 5 * g + 3];
        gb[g]  = (const float*)d_in[8 + 5 * g + 4];
    }
    const float* pen_Wd = (const float*)d_in[38];
    const float* pen_bd = (const float*)d_in[39];
    const float* pen_Wl = (const float*)d_in[40];
    const float* pen_bl = (const float*)d_in[41];
    const float* fc1W   = (const float*)d_in[42];
    const float* fc1b   = (const float*)d_in[43];
    const float* fc2W   = (const float*)d_in[44];
    const float* fc2b   = (const float*)d_in[45];
    const int* node_id_d = (const int*)d_in[46];
    const int* node_id_l = (const int*)d_in[47];
    const int* ei  = (const int*)d_in[48];
    const int* eli = (const int*)d_in[49];
    const int* s_arr = ei;
    const int* t_arr = ei + E;

    // ---- workspace carve-up ----
    char* ws = (char*)d_ws;
    size_t off = 0;
    auto alloc = [&](size_t bytes) -> char* {
        char* p = ws + off;
        off = (off + bytes + 255) & ~(size_t)255;
        return p;
    };
    float* bufd0 = (float*)alloc((size_t)N * 128 * 4);
    float* bufd1 = (float*)alloc((size_t)N * 128 * 4);
    float* bufl0 = (float*)alloc((size_t)N * 128 * 4);
    float* bufl1 = (float*)alloc((size_t)N * 128 * 4);
    // region1 (N*2048 B): input-d planes | agg planes (2 x N*512 u16) | hs (N*128 f32)
    char* region1 = alloc((size_t)N * 512 * 4);
    u16* pxd_in = (u16*)region1;
    u16* aggp   = (u16*)region1;
    float* hs   = (float*)region1;
    // region2 (N*1024 B): input-l planes | layer-3 feature planes
    char* region2 = alloc((size_t)N * 1024);
    u16* pxl_in = (u16*)region2;
    u16* pxd = (u16*)region2;
    u16* pxl = (u16*)(region2 + (size_t)N * 512);
    // weight planes
    u16* btWd = (u16*)alloc((size_t)2 * 128 * KdP * 2);
    u16* btWl = (u16*)alloc((size_t)2 * 128 * KlP * 2);
    u16* btWs[6];
    for (int g = 0; g < 6; ++g) {
        int J = (g < 4) ? 512 : 128;
        btWs[g] = (u16*)alloc((size_t)2 * J * 128 * 2);
    }
    float* es1  = (float*)alloc((size_t)N * 4 * 4);
    float* ed1  = (float*)alloc((size_t)N * 4 * 4);
    float* es2  = (float*)alloc((size_t)N * 4 * 4);
    float* ed2  = (float*)alloc((size_t)N * 4 * 4);
    float* Uall = (float*)alloc((size_t)6 * 1024 * 4);
    int* rpt_t = (int*)alloc((size_t)(N + 1) * 4);
    int* rpt_s = (int*)alloc((size_t)(N + 1) * 4);
    int* deg_t = (int*)alloc((size_t)N * 4);
    int* deg_s = (int*)alloc((size_t)N * 4);
    int* cur_t = (int*)alloc((size_t)N * 4);
    int* cur_s = (int*)alloc((size_t)N * 4);
    int* col_t = (int*)alloc((size_t)E * 4);
    int* col_s = (int*)alloc((size_t)E * 4);
    int* bs_t  = (int*)alloc(256 * 4);
    int* bs_s  = (int*)alloc(256 * 4);
    int* bo_t  = (int*)alloc(257 * 4);
    int* bo_s  = (int*)alloc(257 * 4);
    float* Ad  = (float*)alloc((size_t)N * 64 * 4);
    float* Bl  = (float*)alloc((size_t)N * 64 * 4);
    (void)ws_size;

    hipMemsetAsync(deg_t, 0, (size_t)N * 4, stream);
    hipMemsetAsync(deg_s, 0, (size_t)N * 4, stream);
    hipMemsetAsync(cur_t, 0, (size_t)N * 4, stream);
    hipMemsetAsync(cur_s, 0, (size_t)N * 4, stream);

    dim3 blk(256);
    const int nMB = (N + 127) / 128;

    // ---- input splits (planes) ----
    splitX<<<dim3((N * (KdP >> 2) + 255) / 256), blk, 0, stream>>>(x_d, N, Kd, KdP, pxd_in);
    splitX<<<dim3((N * (KlP >> 2) + 255) / 256), blk, 0, stream>>>(x_l, N, Kl, KlP, pxl_in);
    splitBt<<<dim3((128 * KdP + 255) / 256), blk, 0, stream>>>(Wd_lin, Kd, KdP, 128, btWd);
    splitBt<<<dim3((128 * KlP + 255) / 256), blk, 0, stream>>>(Wl_lin, Kl, KlP, 128, btWl);
    for (int g = 0; g < 6; ++g) {
        int J = (g < 4) ? 512 : 128;
        splitBt<<<dim3((J * 128 + 255) / 256), blk, 0, stream>>>(gWs[g], 128, 128, J, btWs[g]);
    }

    {
        UParams up;
        for (int g = 0; g < 6; ++g) {
            up.Ws[g] = gWs[g]; up.Wd[g] = gWd[g];
            up.as_[g] = gas[g]; up.ad_[g] = gad[g];
            up.C[g] = (g < 4) ? 128 : 32;
        }
        compute_U<<<dim3(1536), blk, 0, stream>>>(up, Uall);
    }

    // CSR for both directions
    {
        deg_kernel<<<dim3((E + 255) / 256), blk, 0, stream>>>(s_arr, t_arr, deg_t, deg_s, E);
        int nb = (N + 255) / 256;
        scan_partial<<<dim3(nb, 2), blk, 0, stream>>>(deg_t, deg_s, rpt_t, rpt_s, bs_t, bs_s, N);
        scan_bsums<<<dim3(1, 2), blk, 0, stream>>>(bs_t, bs_s, bo_t, bo_s, nb);
        scan_add<<<dim3(nb, 2), blk, 0, stream>>>(rpt_t, rpt_s, bo_t, bo_s, N, nb);
        fill_kernel<<<dim3((E + 255) / 256), blk, 0, stream>>>(s_arr, t_arr, rpt_t, rpt_s,
                                                               cur_t, cur_s, col_t, col_s, E);
    }

    // ---- input linears (+bias +embedding gather) ----
    gemm_mfma<true><<<dim3(nMB, 1), blk, 0, stream>>>(
        pxd_in, btWd, bd_lin, emb_d, node_id_d, bufd0, N, KdP, 128);
    gemm_mfma<true><<<dim3(nMB, 1), blk, 0, stream>>>(
        pxl_in, btWl, bl_lin, emb_l, node_id_l, bufl0, N, KlP, 128);

    float* xd_cur = bufd0; float* xl_cur = bufl0;
    float* xd_nxt = bufd1; float* xl_nxt = bufl1;

    // ---- layers 1-2: commuted path (aggregate x, then head-GEMM) ----
    for (int L = 0; L < 2; ++L) {
        const int gd = 2 * L, gl = 2 * L + 1;

        es_ed2_kernel<<<dim3((N * 16 + 255) / 256), blk, 0, stream>>>(
            xd_cur, xl_cur, Uall + gd * 1024, Uall + gl * 1024,
            es1, ed1, es2, ed2, N);

        agg_x<<<dim3((N + 3) / 4), blk, 0, stream>>>(
            rpt_t, col_t, xd_cur, es1, ed1, aggp, N);
        gemm_heads<<<dim3(nMB), blk, 0, stream>>>(
            aggp, btWs[gd], gb[gd], xl_nxt, N);

        agg_x<<<dim3((N + 3) / 4), blk, 0, stream>>>(
            rpt_s, col_s, xl_cur, es2, ed2, aggp, N);
        gemm_heads<<<dim3(nMB), blk, 0, stream>>>(
            aggp, btWs[gl], gb[gl], xd_nxt, N);

        float* tmp;
        tmp = xd_cur; xd_cur = xd_nxt; xd_nxt = tmp;
        tmp = xl_cur; xl_cur = xl_nxt; xl_nxt = tmp;
    }

    // ---- layer 3: direct path (hs is only N x 128) ----
    {
        const int gd = 4, gl = 5;
        splitX<<<dim3((N * 32 + 255) / 256), blk, 0, stream>>>(xd_cur, N, 128, 128, pxd);
        splitX<<<dim3((N * 32 + 255) / 256), blk, 0, stream>>>(xl_cur, N, 128, 128, pxl);

        es_ed2_kernel<<<dim3((N * 16 + 255) / 256), blk, 0, stream>>>(
            xd_cur, xl_cur, Uall + gd * 1024, Uall + gl * 1024,
            es1, ed1, es2, ed2, N);

        gemm_mfma<false><<<dim3(nMB, 1), blk, 0, stream>>>(
            pxd, btWs[gd], nullptr, nullptr, nullptr, hs, N, 128, 128);
        gat_agg128<<<dim3((N + 3) / 4), blk, 0, stream>>>(
            rpt_t, col_t, hs, es1, ed1, gb[gd], xl_nxt, N);

        gemm_mfma<false><<<dim3(nMB, 1), blk, 0, stream>>>(
            pxl, btWs[gl], nullptr, nullptr, nullptr, hs, N, 128, 128);
        gat_agg128<<<dim3((N + 3) / 4), blk, 0, stream>>>(
            rpt_s, col_s, hs, es2, ed2, gb[gl], xd_nxt, N);

        float* tmp;
        tmp = xd_cur; xd_cur = xd_nxt; xd_nxt = tmp;
        tmp = xl_cur; xl_cur = xl_nxt; xl_nxt = tmp;
    }

    // classifier: per-node tables (penalty folded), then per-edge gather
    fc1_halves_kernel<<<dim3((2 * N * 64 + 255) / 256), blk, 0, stream>>>(
        xd_cur, xl_cur, fc1W, pen_Wd, pen_bd, pen_Wl, pen_bl, Ad, Bl, N);
    link_kernel<<<dim3((EL + 3) / 4), blk, 0, stream>>>(
        Ad, Bl, eli, fc1b, fc2W, fc2b, (float*)d_out, EL);
}

// Round 6
// 996.763 us; speedup vs baseline: 2.6911x; 1.1936x over previous
//
#include <hip/hip_runtime.h>
#include <hip/hip_bf16.h>
#include <math.h>

typedef unsigned short u16;
typedef __bf16 bf16x8 __attribute__((ext_vector_type(8)));
typedef float f32x4 __attribute__((ext_vector_type(4)));

// ---------------------------------------------------------------------------
// Hetero-GAT forward, bf16 hi/lo split MFMA.
//  - agg<->GEMM commute for layers 1-2 (aggregate 128-dim x, then head-GEMM).
//  - per-edge softmax weights precomputed in a flat E-thread kernel (no-max
//    softmax: shift-invariant, e is O(1) here); per-node wave loop is then
//    pure gather+fma.
// ---------------------------------------------------------------------------

__device__ inline float bfbits2f(u16 u) {
    unsigned int v = ((unsigned int)u) << 16;
    float f;
    __builtin_memcpy(&f, &v, 4);
    return f;
}
__device__ inline u16 f2bf(float x) {
    __hip_bfloat16 h = __float2bfloat16(x);
    u16 u;
    __builtin_memcpy(&u, &h, 2);
    return u;
}

#define GLD16(gp, lp) __builtin_amdgcn_global_load_lds( \
    (__attribute__((address_space(1))) void*)(gp),      \
    (__attribute__((address_space(3))) void*)(lp), 16, 0, 0)

// ---------------- split fp32 -> bf16 hi/lo planes (K padded to Kp) ---------
__global__ void splitX(const float* __restrict__ x, int N, int K, int Kp,
                       u16* __restrict__ hi)
{
    u16* lo = hi + (size_t)N * Kp;
    int nk4 = Kp >> 2;
    int t = blockIdx.x * 256 + threadIdx.x;
    if (t >= N * nk4) return;
    int n = t / nk4;
    int k4 = (t - n * nk4) << 2;
    u16 h[4], l[4];
#pragma unroll
    for (int j = 0; j < 4; ++j) {
        int k = k4 + j;
        float xv = (k < K) ? x[(size_t)n * K + k] : 0.f;
        u16 hb = f2bf(xv);
        h[j] = hb;
        l[j] = f2bf(xv - bfbits2f(hb));
    }
    uint2 hp, lp;
    hp.x = (unsigned)h[0] | ((unsigned)h[1] << 16);
    hp.y = (unsigned)h[2] | ((unsigned)h[3] << 16);
    lp.x = (unsigned)l[0] | ((unsigned)l[1] << 16);
    lp.y = (unsigned)l[2] | ((unsigned)l[3] << 16);
    *reinterpret_cast<uint2*>(&hi[(size_t)n * Kp + k4]) = hp;
    *reinterpret_cast<uint2*>(&lo[(size_t)n * Kp + k4]) = lp;
}

// ---------------- weight: (K x J) fp32 -> transposed bf16 planes (J x Kp) --
__global__ void splitBt(const float* __restrict__ B, int K, int Kp, int J,
                        u16* __restrict__ hi)
{
    int t = blockIdx.x * 256 + threadIdx.x;
    if (t >= J * Kp) return;
    int col = t / Kp, k = t - col * Kp;
    float v = (k < K) ? B[(size_t)k * J + col] : 0.f;
    u16 hb = f2bf(v);
    hi[t] = hb;
    hi[(size_t)J * Kp + t] = f2bf(v - bfbits2f(hb));
}

// ---------------- MFMA GEMM: C(NxJ) = A(NxKp) @ Bt(JxKp)^T, 3-term split ---
template<bool BIAS_EMB>
__global__ __launch_bounds__(256) void gemm_mfma(
    const u16* __restrict__ Ahi,
    const u16* __restrict__ Bhi,
    const float* __restrict__ bias,
    const float* __restrict__ emb,
    const int* __restrict__ ids,
    float* __restrict__ C,
    int N, int Kp, int J)
{
    __shared__ __align__(16) u16 sA[4096];
    __shared__ __align__(16) u16 sB[4096];
    const int tid = threadIdx.x;
    const int lane = tid & 63;
    const int wid = tid >> 6;
    const int wr = wid >> 1, wc = wid & 1;
    const int rowbase = blockIdx.x * 128;
    const int colbase = blockIdx.y * 128;

    const size_t planeA = (size_t)N * Kp;
    const size_t planeB = (size_t)J * Kp;
    const int nk = Kp / 32;

    const int akc = tid & 3;
    const int arow0 = tid >> 2;
    const int arow1 = 64 + (tid >> 2);
    const int swz = (arow0 >> 1) & 3;
    int gr0 = rowbase + arow0; if (gr0 >= N) gr0 = N - 1;
    int gr1 = rowbase + arow1; if (gr1 >= N) gr1 = N - 1;
    const size_t aoff0 = (size_t)gr0 * Kp + (size_t)((akc ^ swz) * 8);
    const size_t aoff1 = (size_t)gr1 * Kp + (size_t)((akc ^ swz) * 8);
    const size_t boff0 = (size_t)(colbase + arow0) * Kp + (size_t)((akc ^ swz) * 8);
    const size_t boff1 = (size_t)(colbase + arow1) * Kp + (size_t)((akc ^ swz) * 8);

    const int kgs = ((lane >> 4) ^ ((lane >> 1) & 3)) * 8;
    const int arow_rd = wr * 64 + (lane & 15);
    const int brow_rd = wc * 64 + (lane & 15);

    f32x4 acc[4][4] = {};

    for (int term = 0; term < 3; ++term) {
        const u16* Ap = (term < 2) ? Ahi : (Ahi + planeA);
        const u16* Bp = (term == 1) ? (Bhi + planeB) : Bhi;
        for (int ks = 0; ks < nk; ++ks) {
            const int k0 = ks * 32;
            GLD16(Ap + aoff0 + k0, &sA[(size_t)tid * 8]);
            GLD16(Ap + aoff1 + k0, &sA[(size_t)(tid + 256) * 8]);
            GLD16(Bp + boff0 + k0, &sB[(size_t)tid * 8]);
            GLD16(Bp + boff1 + k0, &sB[(size_t)(tid + 256) * 8]);
            __syncthreads();
            bf16x8 af[4], bfq[4];
#pragma unroll
            for (int m = 0; m < 4; ++m)
                af[m] = *reinterpret_cast<const bf16x8*>(&sA[(arow_rd + m * 16) * 32 + kgs]);
#pragma unroll
            for (int n = 0; n < 4; ++n)
                bfq[n] = *reinterpret_cast<const bf16x8*>(&sB[(brow_rd + n * 16) * 32 + kgs]);
#pragma unroll
            for (int m = 0; m < 4; ++m)
#pragma unroll
                for (int n = 0; n < 4; ++n)
                    acc[m][n] = __builtin_amdgcn_mfma_f32_16x16x32_bf16(
                        af[m], bfq[n], acc[m][n], 0, 0, 0);
            __syncthreads();
        }
    }

#pragma unroll
    for (int m = 0; m < 4; ++m) {
        int rb = rowbase + wr * 64 + m * 16 + ((lane >> 4) << 2);
#pragma unroll
        for (int i = 0; i < 4; ++i) {
            int r = rb + i;
            if (r >= N) continue;
            const float* ep = nullptr;
            if (BIAS_EMB) ep = emb + (size_t)ids[r] * 128;
#pragma unroll
            for (int n = 0; n < 4; ++n) {
                int col = colbase + wc * 64 + n * 16 + (lane & 15);
                float v = acc[m][n][i];
                if (BIAS_EMB) v += bias[col] + ep[col];
                C[(size_t)r * J + col] = v;
            }
        }
    }
}

// ---------------- head-blocked GEMM with fused relu/head-mean epilogue -----
__global__ __launch_bounds__(256) void gemm_heads(
    const u16* __restrict__ Ahi,
    const u16* __restrict__ Bhi,
    const float* __restrict__ bias,
    float* __restrict__ C,
    int N)
{
    __shared__ __align__(16) u16 sAh[4096];
    __shared__ __align__(16) u16 sAl[4096];
    __shared__ __align__(16) u16 sBh[4096];
    __shared__ __align__(16) u16 sBl[4096];
    const int tid = threadIdx.x;
    const int lane = tid & 63;
    const int wid = tid >> 6;
    const int wr = wid >> 1, wc = wid & 1;
    const int rowbase = blockIdx.x * 128;

    const u16* Alo = Ahi + (size_t)N * 512;
    const u16* Blo = Bhi + (size_t)512 * 128;

    const int akc = tid & 3;
    const int arow0 = tid >> 2;
    const int arow1 = 64 + arow0;
    const int swz = (arow0 >> 1) & 3;
    int gr0 = rowbase + arow0; if (gr0 >= N) gr0 = N - 1;
    int gr1 = rowbase + arow1; if (gr1 >= N) gr1 = N - 1;
    const size_t aoff0 = (size_t)gr0 * 512 + (size_t)((akc ^ swz) * 8);
    const size_t aoff1 = (size_t)gr1 * 512 + (size_t)((akc ^ swz) * 8);
    const size_t boff0 = (size_t)arow0 * 128 + (size_t)((akc ^ swz) * 8);
    const size_t boff1 = (size_t)arow1 * 128 + (size_t)((akc ^ swz) * 8);

    const int kgs = ((lane >> 4) ^ ((lane >> 1) & 3)) * 8;
    const int arow_rd = wr * 64 + (lane & 15);
    const int brow_rd = wc * 64 + (lane & 15);

    f32x4 acc[4][4] = {};
    f32x4 runsum[4][4] = {};

    for (int h = 0; h < 4; ++h) {
        const size_t ha = (size_t)h * 128;
        const size_t hb = (size_t)h * 128 * 128;
#pragma unroll
        for (int ks = 0; ks < 4; ++ks) {
            const int k0 = ks * 32;
            GLD16(Ahi + aoff0 + ha + k0, &sAh[(size_t)tid * 8]);
            GLD16(Ahi + aoff1 + ha + k0, &sAh[(size_t)(tid + 256) * 8]);
            GLD16(Alo + aoff0 + ha + k0, &sAl[(size_t)tid * 8]);
            GLD16(Alo + aoff1 + ha + k0, &sAl[(size_t)(tid + 256) * 8]);
            GLD16(Bhi + boff0 + hb + k0, &sBh[(size_t)tid * 8]);
            GLD16(Bhi + boff1 + hb + k0, &sBh[(size_t)(tid + 256) * 8]);
            GLD16(Blo + boff0 + hb + k0, &sBl[(size_t)tid * 8]);
            GLD16(Blo + boff1 + hb + k0, &sBl[(size_t)(tid + 256) * 8]);
            __syncthreads();
            bf16x8 bh[4], bl[4];
#pragma unroll
            for (int n = 0; n < 4; ++n) {
                bh[n] = *reinterpret_cast<const bf16x8*>(&sBh[(brow_rd + n * 16) * 32 + kgs]);
                bl[n] = *reinterpret_cast<const bf16x8*>(&sBl[(brow_rd + n * 16) * 32 + kgs]);
            }
#pragma unroll
            for (int m = 0; m < 4; ++m) {
                bf16x8 ah = *reinterpret_cast<const bf16x8*>(&sAh[(arow_rd + m * 16) * 32 + kgs]);
                bf16x8 al = *reinterpret_cast<const bf16x8*>(&sAl[(arow_rd + m * 16) * 32 + kgs]);
#pragma unroll
                for (int n = 0; n < 4; ++n) {
                    acc[m][n] = __builtin_amdgcn_mfma_f32_16x16x32_bf16(ah, bh[n], acc[m][n], 0, 0, 0);
                    acc[m][n] = __builtin_amdgcn_mfma_f32_16x16x32_bf16(ah, bl[n], acc[m][n], 0, 0, 0);
                    acc[m][n] = __builtin_amdgcn_mfma_f32_16x16x32_bf16(al, bh[n], acc[m][n], 0, 0, 0);
                }
            }
            __syncthreads();
        }
#pragma unroll
        for (int m = 0; m < 4; ++m)
#pragma unroll
            for (int n = 0; n < 4; ++n) {
                int col = wc * 64 + n * 16 + (lane & 15);
                float b = bias[h * 128 + col];
#pragma unroll
                for (int i = 0; i < 4; ++i) {
                    runsum[m][n][i] += fmaxf(acc[m][n][i] + b, 0.f);
                    acc[m][n][i] = 0.f;
                }
            }
    }

#pragma unroll
    for (int m = 0; m < 4; ++m) {
        int rb = rowbase + wr * 64 + m * 16 + ((lane >> 4) << 2);
#pragma unroll
        for (int i = 0; i < 4; ++i) {
            int r = rb + i;
            if (r >= N) continue;
#pragma unroll
            for (int n = 0; n < 4; ++n) {
                int col = wc * 64 + n * 16 + (lane & 15);
                C[(size_t)r * 128 + col] = 0.25f * runsum[m][n][i];
            }
        }
    }
}

// ---------------- U = [Ws @ a_s | Wd @ a_d] per head: one wave/output -----
struct UParams {
    const float* Ws[6];
    const float* Wd[6];
    const float* as_[6];
    const float* ad_[6];
    int C[6];
};

__global__ __launch_bounds__(256) void compute_U(UParams P, float* __restrict__ U)
{
    int w = (blockIdx.x * 256 + threadIdx.x) >> 6;    // 0..6143
    if (w >= 6144) return;
    int lane = threadIdx.x & 63;
    int g = w >> 10;
    int o = w & 1023;
    int k = o >> 3, j = o & 7, h = j & 3;
    int C = P.C[g];
    int HC = 4 * C;
    const float* W = (j < 4) ? P.Ws[g] : P.Wd[g];
    const float* a = (j < 4) ? P.as_[g] : P.ad_[g];
    float s = 0.f;
    for (int c = lane; c < C; c += 64)
        s = fmaf(W[k * HC + h * C + c], a[h * C + c], s);
#pragma unroll
    for (int off = 32; off >= 1; off >>= 1) s += __shfl_xor(s, off, 64);
    if (lane == 0) U[g * 1024 + o] = s;
}

// ---------------- fused es/ed for BOTH directions of one layer ------------
__global__ void es_ed2_kernel(const float* __restrict__ xd, const float* __restrict__ xl,
                              const float* __restrict__ U1, const float* __restrict__ U2,
                              float* __restrict__ es1, float* __restrict__ ed1,
                              float* __restrict__ es2, float* __restrict__ ed2, int N)
{
    int t = blockIdx.x * blockDim.x + threadIdx.x;
    if (t >= N * 16) return;
    int n = t >> 4, j = t & 15;
    const float4* X4 = reinterpret_cast<const float4*>(((j < 8) ? xd : xl) + (size_t)n * 128);
    const float* U;
    float* dst;
    int col;
    if (j < 4)       { U = U1; col = j;      dst = &es1[n * 4 + j]; }
    else if (j < 8)  { U = U2; col = j;      dst = &ed2[n * 4 + (j - 4)]; }
    else if (j < 12) { U = U1; col = j - 4;  dst = &ed1[n * 4 + (j - 8)]; }
    else             { U = U2; col = j - 12; dst = &es2[n * 4 + (j - 12)]; }
    float s = 0.f;
#pragma unroll 8
    for (int k4 = 0; k4 < 32; ++k4) {
        float4 x = X4[k4];
        s = fmaf(x.x, U[(k4 * 4 + 0) * 8 + col], s);
        s = fmaf(x.y, U[(k4 * 4 + 1) * 8 + col], s);
        s = fmaf(x.z, U[(k4 * 4 + 2) * 8 + col], s);
        s = fmaf(x.w, U[(k4 * 4 + 3) * 8 + col], s);
    }
    *dst = s;
}

// ---------------- CSR build (stores src + dst node per slot) --------------
__global__ void deg_kernel(const int* __restrict__ s, const int* __restrict__ t,
                           int* __restrict__ deg_t, int* __restrict__ deg_s, int E)
{
    int i = blockIdx.x * blockDim.x + threadIdx.x;
    if (i >= E) return;
    atomicAdd(&deg_t[t[i]], 1);
    atomicAdd(&deg_s[s[i]], 1);
}

__global__ void scan_partial(const int* dA, const int* dB, int* eA, int* eB,
                             int* bsA, int* bsB, int N)
{
    __shared__ int lds[256];
    const int* deg = blockIdx.y ? dB : dA;
    int* ex = blockIdx.y ? eB : eA;
    int* bs = blockIdx.y ? bsB : bsA;
    int i = blockIdx.x * 256 + threadIdx.x;
    int v = (i < N) ? deg[i] : 0;
    int x = v;
    lds[threadIdx.x] = x;
    __syncthreads();
    for (int off = 1; off < 256; off <<= 1) {
        int tv = (threadIdx.x >= off) ? lds[threadIdx.x - off] : 0;
        __syncthreads();
        x += tv;
        lds[threadIdx.x] = x;
        __syncthreads();
    }
    if (i < N) ex[i] = x - v;
    if (threadIdx.x == 255) bs[blockIdx.x] = x;
}

__global__ void scan_bsums(int* bsA, int* bsB, int* boA, int* boB, int nb)
{
    __shared__ int lds[256];
    int* bs = blockIdx.y ? bsB : bsA;
    int* bo = blockIdx.y ? boB : boA;
    int v = (threadIdx.x < nb) ? bs[threadIdx.x] : 0;
    int x = v;
    lds[threadIdx.x] = x;
    __syncthreads();
    for (int off = 1; off < 256; off <<= 1) {
        int tv = (threadIdx.x >= off) ? lds[threadIdx.x - off] : 0;
        __syncthreads();
        x += tv;
        lds[threadIdx.x] = x;
        __syncthreads();
    }
    if (threadIdx.x < nb) bo[threadIdx.x] = x - v;
    if (threadIdx.x == 255) bo[nb] = x;
}

__global__ void scan_add(int* eA, int* eB, const int* boA, const int* boB, int N, int nb)
{
    int* ex = blockIdx.y ? eB : eA;
    const int* bo = blockIdx.y ? boB : boA;
    int i = blockIdx.x * 256 + threadIdx.x;
    if (i < N) ex[i] += bo[i >> 8];
    if (i == 0) ex[N] = bo[nb];
}

__global__ void fill_kernel(const int* __restrict__ s, const int* __restrict__ t,
                            const int* __restrict__ rpt_t, const int* __restrict__ rpt_s,
                            int* __restrict__ cur_t, int* __restrict__ cur_s,
                            int* __restrict__ col_t, int* __restrict__ col_s,
                            int* __restrict__ row_t, int* __restrict__ row_s, int E)
{
    int i = blockIdx.x * blockDim.x + threadIdx.x;
    if (i >= E) return;
    int sv = s[i], tv = t[i];
    int p = atomicAdd(&cur_t[tv], 1);
    int pos = rpt_t[tv] + p;
    col_t[pos] = sv; row_t[pos] = tv;
    p = atomicAdd(&cur_s[sv], 1);
    pos = rpt_s[sv] + p;
    col_s[pos] = tv; row_s[pos] = sv;
}

// ---------------- per-edge softmax weights (no-max, CSR order) ------------
// w4[i] = exp(leaky(es[col[i]] + ed[row[i]])) for direction blockIdx.y.
__global__ __launch_bounds__(256) void edge_w_kernel(
    const int* __restrict__ col_t, const int* __restrict__ row_t,
    const int* __restrict__ col_s, const int* __restrict__ row_s,
    const float* __restrict__ es1, const float* __restrict__ ed1,
    const float* __restrict__ es2, const float* __restrict__ ed2,
    float* __restrict__ w_t, float* __restrict__ w_s, int E)
{
    int i = blockIdx.x * 256 + threadIdx.x;
    if (i >= E) return;
    const int* col; const int* row; const float* es; const float* ed; float* w;
    if (blockIdx.y == 0) { col = col_t; row = row_t; es = es1; ed = ed1; w = w_t; }
    else                 { col = col_s; row = row_s; es = es2; ed = ed2; w = w_s; }
    int sn = col[i], rn = row[i];
    float4 a = *reinterpret_cast<const float4*>(&es[(size_t)sn * 4]);
    float4 b = *reinterpret_cast<const float4*>(&ed[(size_t)rn * 4]);
    float v0 = a.x + b.x; v0 = v0 > 0.f ? v0 : 0.2f * v0;
    float v1 = a.y + b.y; v1 = v1 > 0.f ? v1 : 0.2f * v1;
    float v2 = a.z + b.z; v2 = v2 > 0.f ? v2 : 0.2f * v2;
    float v3 = a.w + b.w; v3 = v3 > 0.f ? v3 : 0.2f * v3;
    float4 o;
    o.x = __expf(v0); o.y = __expf(v1); o.z = __expf(v2); o.w = __expf(v3);
    *reinterpret_cast<float4*>(&w[(size_t)i * 4]) = o;
}

// ---------------- per-head x-aggregation (layers 1-2), w precomputed ------
// agg[n, h, c] = (sum_e w_e^h x[src_e, c]) / den_h, written as bf16 hi/lo.
// Lane owns channels (2*lane, 2*lane+1): float2 gathers, packed u32 stores.
__global__ __launch_bounds__(256) void agg_x(
    const int* __restrict__ rowptr, const int* __restrict__ cols,
    const float* __restrict__ wbuf,   // E x 4 (CSR order)
    const float* __restrict__ xsrc,   // Nsrc x 128 fp32
    u16* __restrict__ aggp,           // hi plane; lo at +Ndst*512
    int Ndst)
{
    int n = blockIdx.x * 4 + (threadIdx.x >> 6);
    if (n >= Ndst) return;
    int lane = threadIdx.x & 63;
    int beg = rowptr[n], end = rowptr[n + 1];

    float den0 = 0.f, den1 = 0.f, den2 = 0.f, den3 = 0.f;
    float2 acc[4] = {};

    for (int i = beg; i < end; ++i) {
        float4 w4 = *reinterpret_cast<const float4*>(&wbuf[(size_t)i * 4]);
        den0 += w4.x; den1 += w4.y; den2 += w4.z; den3 += w4.w;
        int sn = cols[i];
        float2 xv = *reinterpret_cast<const float2*>(&xsrc[(size_t)sn * 128 + 2 * lane]);
        acc[0].x = fmaf(w4.x, xv.x, acc[0].x); acc[0].y = fmaf(w4.x, xv.y, acc[0].y);
        acc[1].x = fmaf(w4.y, xv.x, acc[1].x); acc[1].y = fmaf(w4.y, xv.y, acc[1].y);
        acc[2].x = fmaf(w4.z, xv.x, acc[2].x); acc[2].y = fmaf(w4.z, xv.y, acc[2].y);
        acc[3].x = fmaf(w4.w, xv.x, acc[3].x); acc[3].y = fmaf(w4.w, xv.y, acc[3].y);
    }

    float inv[4] = {1.f / (den0 + 1e-16f), 1.f / (den1 + 1e-16f),
                    1.f / (den2 + 1e-16f), 1.f / (den3 + 1e-16f)};
    u16* lo = aggp + (size_t)Ndst * 512;
    size_t base = (size_t)n * 512 + 2 * lane;
#pragma unroll
    for (int h = 0; h < 4; ++h) {
        float v0 = acc[h].x * inv[h];
        float v1 = acc[h].y * inv[h];
        u16 h0 = f2bf(v0), h1 = f2bf(v1);
        *reinterpret_cast<unsigned*>(&aggp[base + h * 128]) =
            (unsigned)h0 | ((unsigned)h1 << 16);
        u16 l0 = f2bf(v0 - bfbits2f(h0)), l1 = f2bf(v1 - bfbits2f(h1));
        *reinterpret_cast<unsigned*>(&lo[base + h * 128]) =
            (unsigned)l0 | ((unsigned)l1 << 16);
    }
}

// ---------------- GAT aggregation for layer 3 (w precomputed) -------------
__global__ __launch_bounds__(256) void gat_agg128(
    const int* __restrict__ rowptr, const int* __restrict__ cols,
    const float* __restrict__ wbuf,
    const float* __restrict__ hs,     // Nsrc x 128
    const float* __restrict__ bias,   // 128
    float* __restrict__ out,          // Ndst x 32
    int Ndst)
{
    int n = blockIdx.x * 4 + (threadIdx.x >> 6);
    if (n >= Ndst) return;
    int lane = threadIdx.x & 63;
    int beg = rowptr[n], end = rowptr[n + 1];

    float den0 = 0.f, den1 = 0.f, den2 = 0.f, den3 = 0.f;
    float acc0 = 0.f, acc1 = 0.f;
    for (int i = beg; i < end; ++i) {
        float4 w4 = *reinterpret_cast<const float4*>(&wbuf[(size_t)i * 4]);
        den0 += w4.x; den1 += w4.y; den2 += w4.z; den3 += w4.w;
        int sn = cols[i];
        const float* hp = hs + (size_t)sn * 128;
        float wA = (lane < 32) ? w4.x : w4.y;
        float wB = (lane < 32) ? w4.z : w4.w;
        acc0 = fmaf(wA, hp[lane], acc0);
        acc1 = fmaf(wB, hp[64 + lane], acc1);
    }
    den0 += 1e-16f; den1 += 1e-16f; den2 += 1e-16f; den3 += 1e-16f;
    float d0 = lane < 32 ? den0 : den1;
    float d1 = lane < 32 ? den2 : den3;
    float v0 = fmaxf(acc0 / d0 + bias[lane], 0.f);
    float v1 = fmaxf(acc1 / d1 + bias[64 + lane], 0.f);
    float sum = v0 + __shfl_xor(v0, 32, 64) + v1 + __shfl_xor(v1, 32, 64);
    if (lane < 32) out[(size_t)n * 32 + lane] = 0.25f * sum;
}

// ---------------- per-node classifier tables (penalty folded in) ----------
__global__ __launch_bounds__(256) void fc1_halves_kernel(
    const float* __restrict__ xd, const float* __restrict__ xl,
    const float* __restrict__ fc1W,
    const float* __restrict__ penWd, const float* __restrict__ penbd,
    const float* __restrict__ penWl, const float* __restrict__ penbl,
    float* __restrict__ Ad, float* __restrict__ Bl, int N)
{
    int wid = (blockIdx.x * 256 + threadIdx.x) >> 6;
    if (wid >= 2 * N) return;
    int lane = threadIdx.x & 63;
    bool isl = wid >= N;
    int n = isl ? wid - N : wid;
    const float* x = (isl ? xl : xd) + (size_t)n * 32;
    const float* pW = isl ? penWl : penWd;
    float pb = isl ? penbl[0] : penbd[0];

    float pp = x[lane & 31] * pW[lane & 31];
    pp += __shfl_xor(pp, 1, 64);
    pp += __shfl_xor(pp, 2, 64);
    pp += __shfl_xor(pp, 4, 64);
    pp += __shfl_xor(pp, 8, 64);
    pp += __shfl_xor(pp, 16, 64);
    float s = expf(pp + pb);

    const float* W = fc1W + (isl ? 32 * 64 : 0);
    float acc = 0.f;
#pragma unroll
    for (int k = 0; k < 32; ++k)
        acc = fmaf(x[k], W[k * 64 + lane], acc);
    (isl ? Bl : Ad)[(size_t)n * 64 + lane] = s * acc;
}

// ---------------- link classifier: table gather + reduce ------------------
__global__ __launch_bounds__(256) void link_kernel(
    const float* __restrict__ Ad, const float* __restrict__ Bl,
    const int* __restrict__ eli,
    const float* __restrict__ fc1b, const float* __restrict__ fc2W,
    const float* __restrict__ fc2b,
    float* __restrict__ out, int EL)
{
    int wid = (blockIdx.x * 256 + threadIdx.x) >> 6;
    if (wid >= EL) return;
    int lane = threadIdx.x & 63;
    int e0 = eli[wid];
    int e1 = eli[EL + wid];
    float v = Ad[(size_t)e0 * 64 + lane] + Bl[(size_t)e1 * 64 + lane] + fc1b[lane];
    v = fmaxf(v, 0.f);
    float p = v * fc2W[lane];
#pragma unroll
    for (int off = 32; off >= 1; off >>= 1) p += __shfl_xor(p, off, 64);
    if (lane == 0) out[wid] = p + fc2b[0];
}

// ---------------------------------------------------------------------------
extern "C" void kernel_launch(void* const* d_in, const int* in_sizes, int n_in,
                              void* d_out, int out_size, void* d_ws, size_t ws_size,
                              hipStream_t stream)
{
    const int N  = in_sizes[6] / 128;
    const int Kd = in_sizes[2] / 128;   // 412
    const int Kl = in_sizes[4] / 128;   // 240
    const int KdP = (Kd + 31) & ~31;    // 416
    const int KlP = (Kl + 31) & ~31;    // 256
    const int E  = in_sizes[48] / 2;
    const int EL = in_sizes[49] / 2;

    const float* x_d    = (const float*)d_in[0];
    const float* x_l    = (const float*)d_in[1];
    const float* Wd_lin = (const float*)d_in[2];
    const float* bd_lin = (const float*)d_in[3];
    const float* Wl_lin = (const float*)d_in[4];
    const float* bl_lin = (const float*)d_in[5];
    const float* emb_d  = (const float*)d_in[6];
    const float* emb_l  = (const float*)d_in[7];

    const float *gWs[6], *gWd[6], *gas[6], *gad[6], *gb[6];
    for (int g = 0; g < 6; ++g) {
        gWs[g] = (const float*)d_in[8 + 5 * g + 0];
        gWd[g] = (const float*)d_in[8 + 5 * g + 1];
        gas[g] = (const float*)d_in[8 + 5 * g + 2];
        gad[g] = (const float*)d_in[8 + 5 * g + 3];
        gb[g]  = (const float*)d_in[8 + 5 * g + 4];
    }
    const float* pen_Wd = (const float*)d_in[38];
    const float* pen_bd = (const float*)d_in[39];
    const float* pen_Wl = (const float*)d_in[40];
    const float* pen_bl = (const float*)d_in[41];
    const float* fc1W   = (const float*)d_in[42];
    const float* fc1b   = (const float*)d_in[43];
    const float* fc2W   = (const float*)d_in[44];
    const float* fc2b   = (const float*)d_in[45];
    const int* node_id_d = (const int*)d_in[46];
    const int* node_id_l = (const int*)d_in[47];
    const int* ei  = (const int*)d_in[48];
    const int* eli = (const int*)d_in[49];
    const int* s_arr = ei;
    const int* t_arr = ei + E;

    // ---- workspace carve-up ----
    char* ws = (char*)d_ws;
    size_t off = 0;
    auto alloc = [&](size_t bytes) -> char* {
        char* p = ws + off;
        off = (off + bytes + 255) & ~(size_t)255;
        return p;
    };
    float* bufd0 = (float*)alloc((size_t)N * 128 * 4);
    float* bufd1 = (float*)alloc((size_t)N * 128 * 4);
    float* bufl0 = (float*)alloc((size_t)N * 128 * 4);
    float* bufl1 = (float*)alloc((size_t)N * 128 * 4);
    // region1 (N*2048 B): input-d planes | agg planes (2 x N*512 u16) | hs (N*128 f32)
    char* region1 = alloc((size_t)N * 512 * 4);
    u16* pxd_in = (u16*)region1;
    u16* aggp   = (u16*)region1;
    float* hs   = (float*)region1;
    // region2 (N*1024 B): input-l planes | layer-3 feature planes
    char* region2 = alloc((size_t)N * 1024);
    u16* pxl_in = (u16*)region2;
    u16* pxd = (u16*)region2;
    u16* pxl = (u16*)(region2 + (size_t)N * 512);
    // weight planes
    u16* btWd = (u16*)alloc((size_t)2 * 128 * KdP * 2);
    u16* btWl = (u16*)alloc((size_t)2 * 128 * KlP * 2);
    u16* btWs[6];
    for (int g = 0; g < 6; ++g) {
        int J = (g < 4) ? 512 : 128;
        btWs[g] = (u16*)alloc((size_t)2 * J * 128 * 2);
    }
    float* es1  = (float*)alloc((size_t)N * 4 * 4);
    float* ed1  = (float*)alloc((size_t)N * 4 * 4);
    float* es2  = (float*)alloc((size_t)N * 4 * 4);
    float* ed2  = (float*)alloc((size_t)N * 4 * 4);
    float* Uall = (float*)alloc((size_t)6 * 1024 * 4);
    int* rpt_t = (int*)alloc((size_t)(N + 1) * 4);
    int* rpt_s = (int*)alloc((size_t)(N + 1) * 4);
    int* deg_t = (int*)alloc((size_t)N * 4);
    int* deg_s = (int*)alloc((size_t)N * 4);
    int* cur_t = (int*)alloc((size_t)N * 4);
    int* cur_s = (int*)alloc((size_t)N * 4);
    int* col_t = (int*)alloc((size_t)E * 4);
    int* col_s = (int*)alloc((size_t)E * 4);
    int* row_t = (int*)alloc((size_t)E * 4);
    int* row_s = (int*)alloc((size_t)E * 4);
    float* w_t = (float*)alloc((size_t)E * 4 * 4);
    float* w_s = (float*)alloc((size_t)E * 4 * 4);
    int* bs_t  = (int*)alloc(256 * 4);
    int* bs_s  = (int*)alloc(256 * 4);
    int* bo_t  = (int*)alloc(257 * 4);
    int* bo_s  = (int*)alloc(257 * 4);
    float* Ad  = (float*)alloc((size_t)N * 64 * 4);
    float* Bl  = (float*)alloc((size_t)N * 64 * 4);
    (void)ws_size;

    hipMemsetAsync(deg_t, 0, (size_t)N * 4, stream);
    hipMemsetAsync(deg_s, 0, (size_t)N * 4, stream);
    hipMemsetAsync(cur_t, 0, (size_t)N * 4, stream);
    hipMemsetAsync(cur_s, 0, (size_t)N * 4, stream);

    dim3 blk(256);
    const int nMB = (N + 127) / 128;
    const int nEB = (E + 255) / 256;

    // ---- input splits (planes) ----
    splitX<<<dim3((N * (KdP >> 2) + 255) / 256), blk, 0, stream>>>(x_d, N, Kd, KdP, pxd_in);
    splitX<<<dim3((N * (KlP >> 2) + 255) / 256), blk, 0, stream>>>(x_l, N, Kl, KlP, pxl_in);
    splitBt<<<dim3((128 * KdP + 255) / 256), blk, 0, stream>>>(Wd_lin, Kd, KdP, 128, btWd);
    splitBt<<<dim3((128 * KlP + 255) / 256), blk, 0, stream>>>(Wl_lin, Kl, KlP, 128, btWl);
    for (int g = 0; g < 6; ++g) {
        int J = (g < 4) ? 512 : 128;
        splitBt<<<dim3((J * 128 + 255) / 256), blk, 0, stream>>>(gWs[g], 128, 128, J, btWs[g]);
    }

    {
        UParams up;
        for (int g = 0; g < 6; ++g) {
            up.Ws[g] = gWs[g]; up.Wd[g] = gWd[g];
            up.as_[g] = gas[g]; up.ad_[g] = gad[g];
            up.C[g] = (g < 4) ? 128 : 32;
        }
        compute_U<<<dim3(1536), blk, 0, stream>>>(up, Uall);
    }

    // CSR for both directions
    {
        deg_kernel<<<dim3(nEB), blk, 0, stream>>>(s_arr, t_arr, deg_t, deg_s, E);
        int nb = (N + 255) / 256;
        scan_partial<<<dim3(nb, 2), blk, 0, stream>>>(deg_t, deg_s, rpt_t, rpt_s, bs_t, bs_s, N);
        scan_bsums<<<dim3(1, 2), blk, 0, stream>>>(bs_t, bs_s, bo_t, bo_s, nb);
        scan_add<<<dim3(nb, 2), blk, 0, stream>>>(rpt_t, rpt_s, bo_t, bo_s, N, nb);
        fill_kernel<<<dim3(nEB), blk, 0, stream>>>(s_arr, t_arr, rpt_t, rpt_s,
                                                   cur_t, cur_s, col_t, col_s,
                                                   row_t, row_s, E);
    }

    // ---- input linears (+bias +embedding gather) ----
    gemm_mfma<true><<<dim3(nMB, 1), blk, 0, stream>>>(
        pxd_in, btWd, bd_lin, emb_d, node_id_d, bufd0, N, KdP, 128);
    gemm_mfma<true><<<dim3(nMB, 1), blk, 0, stream>>>(
        pxl_in, btWl, bl_lin, emb_l, node_id_l, bufl0, N, KlP, 128);

    float* xd_cur = bufd0; float* xl_cur = bufl0;
    float* xd_nxt = bufd1; float* xl_nxt = bufl1;

    // ---- layers 1-2: commuted path (aggregate x, then head-GEMM) ----
    for (int L = 0; L < 2; ++L) {
        const int gd = 2 * L, gl = 2 * L + 1;

        es_ed2_kernel<<<dim3((N * 16 + 255) / 256), blk, 0, stream>>>(
            xd_cur, xl_cur, Uall + gd * 1024, Uall + gl * 1024,
            es1, ed1, es2, ed2, N);
        edge_w_kernel<<<dim3(nEB, 2), blk, 0, stream>>>(
            col_t, row_t, col_s, row_s, es1, ed1, es2, ed2, w_t, w_s, E);

        agg_x<<<dim3((N + 3) / 4), blk, 0, stream>>>(
            rpt_t, col_t, w_t, xd_cur, aggp, N);
        gemm_heads<<<dim3(nMB), blk, 0, stream>>>(
            aggp, btWs[gd], gb[gd], xl_nxt, N);

        agg_x<<<dim3((N + 3) / 4), blk, 0, stream>>>(
            rpt_s, col_s, w_s, xl_cur, aggp, N);
        gemm_heads<<<dim3(nMB), blk, 0, stream>>>(
            aggp, btWs[gl], gb[gl], xd_nxt, N);

        float* tmp;
        tmp = xd_cur; xd_cur = xd_nxt; xd_nxt = tmp;
        tmp = xl_cur; xl_cur = xl_nxt; xl_nxt = tmp;
    }

    // ---- layer 3: direct path (hs is only N x 128) ----
    {
        const int gd = 4, gl = 5;
        splitX<<<dim3((N * 32 + 255) / 256), blk, 0, stream>>>(xd_cur, N, 128, 128, pxd);
        splitX<<<dim3((N * 32 + 255) / 256), blk, 0, stream>>>(xl_cur, N, 128, 128, pxl);

        es_ed2_kernel<<<dim3((N * 16 + 255) / 256), blk, 0, stream>>>(
            xd_cur, xl_cur, Uall + gd * 1024, Uall + gl * 1024,
            es1, ed1, es2, ed2, N);
        edge_w_kernel<<<dim3(nEB, 2), blk, 0, stream>>>(
            col_t, row_t, col_s, row_s, es1, ed1, es2, ed2, w_t, w_s, E);

        gemm_mfma<false><<<dim3(nMB, 1), blk, 0, stream>>>(
            pxd, btWs[gd], nullptr, nullptr, nullptr, hs, N, 128, 128);
        gat_agg128<<<dim3((N + 3) / 4), blk, 0, stream>>>(
            rpt_t, col_t, w_t, hs, gb[gd], xl_nxt, N);

        gemm_mfma<false><<<dim3(nMB, 1), blk, 0, stream>>>(
            pxl, btWs[gl], nullptr, nullptr, nullptr, hs, N, 128, 128);
        gat_agg128<<<dim3((N + 3) / 4), blk, 0, stream>>>(
            rpt_s, col_s, w_s, hs, gb[gl], xd_nxt, N);

        float* tmp;
        tmp = xd_cur; xd_cur = xd_nxt; xd_nxt = tmp;
        tmp = xl_cur; xl_cur = xl_nxt; xl_nxt = tmp;
    }

    // classifier: per-node tables (penalty folded), then per-edge gather
    fc1_halves_kernel<<<dim3((2 * N * 64 + 255) / 256), blk, 0, stream>>>(
        xd_cur, xl_cur, fc1W, pen_Wd, pen_bd, pen_Wl, pen_bl, Ad, Bl, N);
    link_kernel<<<dim3((EL + 3) / 4), blk, 0, stream>>>(
        Ad, Bl, eli, fc1b, fc2W, fc2b, (float*)d_out, EL);
}

// Round 7
// 930.977 us; speedup vs baseline: 2.8813x; 1.0707x over previous
//
#include <hip/hip_runtime.h>
#include <hip/hip_bf16.h>
#include <math.h>

typedef unsigned short u16;
typedef __bf16 bf16x8 __attribute__((ext_vector_type(8)));
typedef float f32x4 __attribute__((ext_vector_type(4)));

// ---------------------------------------------------------------------------
// Hetero-GAT forward, bf16 hi/lo split MFMA.
//  - agg<->GEMM commute for layers 1-2 (aggregate 128-dim x, then head-GEMM).
//  - per-edge softmax weights precomputed flat (no-max softmax).
//  - GEMMs: BM=64 tiles (782 blocks, ~3/CU) with fused hi/lo staging: one
//    LDS stage per k-step feeding all 3 split terms (A read exactly once).
// ---------------------------------------------------------------------------

__device__ inline float bfbits2f(u16 u) {
    unsigned int v = ((unsigned int)u) << 16;
    float f;
    __builtin_memcpy(&f, &v, 4);
    return f;
}
__device__ inline u16 f2bf(float x) {
    __hip_bfloat16 h = __float2bfloat16(x);
    u16 u;
    __builtin_memcpy(&u, &h, 2);
    return u;
}

#define GLD16(gp, lp) __builtin_amdgcn_global_load_lds( \
    (__attribute__((address_space(1))) void*)(gp),      \
    (__attribute__((address_space(3))) void*)(lp), 16, 0, 0)

// ---------------- split fp32 -> bf16 hi/lo planes (K padded to Kp) ---------
__global__ void splitX(const float* __restrict__ x, int N, int K, int Kp,
                       u16* __restrict__ hi)
{
    u16* lo = hi + (size_t)N * Kp;
    int nk4 = Kp >> 2;
    int t = blockIdx.x * 256 + threadIdx.x;
    if (t >= N * nk4) return;
    int n = t / nk4;
    int k4 = (t - n * nk4) << 2;
    u16 h[4], l[4];
#pragma unroll
    for (int j = 0; j < 4; ++j) {
        int k = k4 + j;
        float xv = (k < K) ? x[(size_t)n * K + k] : 0.f;
        u16 hb = f2bf(xv);
        h[j] = hb;
        l[j] = f2bf(xv - bfbits2f(hb));
    }
    uint2 hp, lp;
    hp.x = (unsigned)h[0] | ((unsigned)h[1] << 16);
    hp.y = (unsigned)h[2] | ((unsigned)h[3] << 16);
    lp.x = (unsigned)l[0] | ((unsigned)l[1] << 16);
    lp.y = (unsigned)l[2] | ((unsigned)l[3] << 16);
    *reinterpret_cast<uint2*>(&hi[(size_t)n * Kp + k4]) = hp;
    *reinterpret_cast<uint2*>(&lo[(size_t)n * Kp + k4]) = lp;
}

// ---------------- weight: (K x J) fp32 -> transposed bf16 planes (J x Kp) --
__global__ void splitBt(const float* __restrict__ B, int K, int Kp, int J,
                        u16* __restrict__ hi)
{
    int t = blockIdx.x * 256 + threadIdx.x;
    if (t >= J * Kp) return;
    int col = t / Kp, k = t - col * Kp;
    float v = (k < K) ? B[(size_t)k * J + col] : 0.f;
    u16 hb = f2bf(v);
    hi[t] = hb;
    hi[(size_t)J * Kp + t] = f2bf(v - bfbits2f(hb));
}

// ---------------- MFMA GEMM: C(NxJ) = A(NxKp) @ Bt(JxKp)^T -----------------
// BM=64, BN=128, 4 waves each owning 64x32; fused hi/lo staging, 3 terms/step.
template<bool BIAS_EMB>
__global__ __launch_bounds__(256) void gemm_mfma(
    const u16* __restrict__ Ahi,
    const u16* __restrict__ Bhi,
    const float* __restrict__ bias,
    const float* __restrict__ emb,
    const int* __restrict__ ids,
    float* __restrict__ C,
    int N, int Kp, int J)
{
    __shared__ __align__(16) u16 sAh[2048];   // 64 x 32
    __shared__ __align__(16) u16 sAl[2048];
    __shared__ __align__(16) u16 sBh[4096];   // 128 x 32
    __shared__ __align__(16) u16 sBl[4096];
    const int tid = threadIdx.x;
    const int lane = tid & 63;
    const int wid = tid >> 6;
    const int rowbase = blockIdx.x * 64;
    const int colbase = blockIdx.y * 128;

    const u16* Alo = Ahi + (size_t)N * Kp;
    const u16* Blo = Bhi + (size_t)J * Kp;
    const int nk = Kp / 32;

    const int akc = tid & 3;
    const int arow = tid >> 2;               // 0..63
    const int swz = (arow >> 1) & 3;
    int gr = rowbase + arow; if (gr >= N) gr = N - 1;
    const size_t aoff  = (size_t)gr * Kp + (size_t)((akc ^ swz) * 8);
    const size_t boff0 = (size_t)(colbase + arow) * Kp + (size_t)((akc ^ swz) * 8);
    const size_t boff1 = (size_t)(colbase + 64 + arow) * Kp + (size_t)((akc ^ swz) * 8);

    const int kgs = ((lane >> 4) ^ ((lane >> 1) & 3)) * 8;
    const int arow_rd = lane & 15;
    const int brow_rd = wid * 32 + (lane & 15);

    f32x4 acc[4][2] = {};

    for (int ks = 0; ks < nk; ++ks) {
        const int k0 = ks * 32;
        GLD16(Ahi + aoff + k0,  &sAh[(size_t)tid * 8]);
        GLD16(Alo + aoff + k0,  &sAl[(size_t)tid * 8]);
        GLD16(Bhi + boff0 + k0, &sBh[(size_t)tid * 8]);
        GLD16(Bhi + boff1 + k0, &sBh[(size_t)(tid + 256) * 8]);
        GLD16(Blo + boff0 + k0, &sBl[(size_t)tid * 8]);
        GLD16(Blo + boff1 + k0, &sBl[(size_t)(tid + 256) * 8]);
        __syncthreads();
        bf16x8 bh[2], bl[2];
#pragma unroll
        for (int n = 0; n < 2; ++n) {
            bh[n] = *reinterpret_cast<const bf16x8*>(&sBh[(brow_rd + n * 16) * 32 + kgs]);
            bl[n] = *reinterpret_cast<const bf16x8*>(&sBl[(brow_rd + n * 16) * 32 + kgs]);
        }
#pragma unroll
        for (int m = 0; m < 4; ++m) {
            bf16x8 ah = *reinterpret_cast<const bf16x8*>(&sAh[(arow_rd + m * 16) * 32 + kgs]);
            bf16x8 al = *reinterpret_cast<const bf16x8*>(&sAl[(arow_rd + m * 16) * 32 + kgs]);
#pragma unroll
            for (int n = 0; n < 2; ++n) {
                acc[m][n] = __builtin_amdgcn_mfma_f32_16x16x32_bf16(ah, bh[n], acc[m][n], 0, 0, 0);
                acc[m][n] = __builtin_amdgcn_mfma_f32_16x16x32_bf16(ah, bl[n], acc[m][n], 0, 0, 0);
                acc[m][n] = __builtin_amdgcn_mfma_f32_16x16x32_bf16(al, bh[n], acc[m][n], 0, 0, 0);
            }
        }
        __syncthreads();
    }

#pragma unroll
    for (int m = 0; m < 4; ++m) {
        int rb = rowbase + m * 16 + ((lane >> 4) << 2);
#pragma unroll
        for (int i = 0; i < 4; ++i) {
            int r = rb + i;
            if (r >= N) continue;
            const float* ep = nullptr;
            if (BIAS_EMB) ep = emb + (size_t)ids[r] * 128;
#pragma unroll
            for (int n = 0; n < 2; ++n) {
                int col = colbase + wid * 32 + n * 16 + (lane & 15);
                float v = acc[m][n][i];
                if (BIAS_EMB) v += bias[col] + ep[col];
                C[(size_t)r * J + col] = v;
            }
        }
    }
}

// ---------------- head-blocked GEMM with fused relu/head-mean epilogue -----
// BM=64; A planes N x 512 (lo at +N*512), B planes 512 x 128 (btWs).
__global__ __launch_bounds__(256) void gemm_heads(
    const u16* __restrict__ Ahi,
    const u16* __restrict__ Bhi,
    const float* __restrict__ bias,
    float* __restrict__ C,
    int N)
{
    __shared__ __align__(16) u16 sAh[2048];
    __shared__ __align__(16) u16 sAl[2048];
    __shared__ __align__(16) u16 sBh[4096];
    __shared__ __align__(16) u16 sBl[4096];
    const int tid = threadIdx.x;
    const int lane = tid & 63;
    const int wid = tid >> 6;
    const int rowbase = blockIdx.x * 64;

    const u16* Alo = Ahi + (size_t)N * 512;
    const u16* Blo = Bhi + (size_t)512 * 128;

    const int akc = tid & 3;
    const int arow = tid >> 2;
    const int swz = (arow >> 1) & 3;
    int gr = rowbase + arow; if (gr >= N) gr = N - 1;
    const size_t aoff  = (size_t)gr * 512 + (size_t)((akc ^ swz) * 8);
    const size_t boff0 = (size_t)arow * 128 + (size_t)((akc ^ swz) * 8);
    const size_t boff1 = (size_t)(64 + arow) * 128 + (size_t)((akc ^ swz) * 8);

    const int kgs = ((lane >> 4) ^ ((lane >> 1) & 3)) * 8;
    const int arow_rd = lane & 15;
    const int brow_rd = wid * 32 + (lane & 15);

    f32x4 acc[4][2] = {};
    f32x4 runsum[4][2] = {};

    for (int h = 0; h < 4; ++h) {
        const size_t ha = (size_t)h * 128;          // A k-offset
        const size_t hb = (size_t)h * 128 * 128;    // B row-block offset
#pragma unroll
        for (int ks = 0; ks < 4; ++ks) {
            const int k0 = ks * 32;
            GLD16(Ahi + aoff + ha + k0,  &sAh[(size_t)tid * 8]);
            GLD16(Alo + aoff + ha + k0,  &sAl[(size_t)tid * 8]);
            GLD16(Bhi + boff0 + hb + k0, &sBh[(size_t)tid * 8]);
            GLD16(Bhi + boff1 + hb + k0, &sBh[(size_t)(tid + 256) * 8]);
            GLD16(Blo + boff0 + hb + k0, &sBl[(size_t)tid * 8]);
            GLD16(Blo + boff1 + hb + k0, &sBl[(size_t)(tid + 256) * 8]);
            __syncthreads();
            bf16x8 bh[2], bl[2];
#pragma unroll
            for (int n = 0; n < 2; ++n) {
                bh[n] = *reinterpret_cast<const bf16x8*>(&sBh[(brow_rd + n * 16) * 32 + kgs]);
                bl[n] = *reinterpret_cast<const bf16x8*>(&sBl[(brow_rd + n * 16) * 32 + kgs]);
            }
#pragma unroll
            for (int m = 0; m < 4; ++m) {
                bf16x8 ah = *reinterpret_cast<const bf16x8*>(&sAh[(arow_rd + m * 16) * 32 + kgs]);
                bf16x8 al = *reinterpret_cast<const bf16x8*>(&sAl[(arow_rd + m * 16) * 32 + kgs]);
#pragma unroll
                for (int n = 0; n < 2; ++n) {
                    acc[m][n] = __builtin_amdgcn_mfma_f32_16x16x32_bf16(ah, bh[n], acc[m][n], 0, 0, 0);
                    acc[m][n] = __builtin_amdgcn_mfma_f32_16x16x32_bf16(ah, bl[n], acc[m][n], 0, 0, 0);
                    acc[m][n] = __builtin_amdgcn_mfma_f32_16x16x32_bf16(al, bh[n], acc[m][n], 0, 0, 0);
                }
            }
            __syncthreads();
        }
        // head epilogue: +bias, relu, accumulate into runsum; reset acc
#pragma unroll
        for (int m = 0; m < 4; ++m)
#pragma unroll
            for (int n = 0; n < 2; ++n) {
                int col = wid * 32 + n * 16 + (lane & 15);
                float b = bias[h * 128 + col];
#pragma unroll
                for (int i = 0; i < 4; ++i) {
                    runsum[m][n][i] += fmaxf(acc[m][n][i] + b, 0.f);
                    acc[m][n][i] = 0.f;
                }
            }
    }

#pragma unroll
    for (int m = 0; m < 4; ++m) {
        int rb = rowbase + m * 16 + ((lane >> 4) << 2);
#pragma unroll
        for (int i = 0; i < 4; ++i) {
            int r = rb + i;
            if (r >= N) continue;
#pragma unroll
            for (int n = 0; n < 2; ++n) {
                int col = wid * 32 + n * 16 + (lane & 15);
                C[(size_t)r * 128 + col] = 0.25f * runsum[m][n][i];
            }
        }
    }
}

// ---------------- U = [Ws @ a_s | Wd @ a_d] per head: one wave/output -----
struct UParams {
    const float* Ws[6];
    const float* Wd[6];
    const float* as_[6];
    const float* ad_[6];
    int C[6];
};

__global__ __launch_bounds__(256) void compute_U(UParams P, float* __restrict__ U)
{
    int w = (blockIdx.x * 256 + threadIdx.x) >> 6;    // 0..6143
    if (w >= 6144) return;
    int lane = threadIdx.x & 63;
    int g = w >> 10;
    int o = w & 1023;
    int k = o >> 3, j = o & 7, h = j & 3;
    int C = P.C[g];
    int HC = 4 * C;
    const float* W = (j < 4) ? P.Ws[g] : P.Wd[g];
    const float* a = (j < 4) ? P.as_[g] : P.ad_[g];
    float s = 0.f;
    for (int c = lane; c < C; c += 64)
        s = fmaf(W[k * HC + h * C + c], a[h * C + c], s);
#pragma unroll
    for (int off = 32; off >= 1; off >>= 1) s += __shfl_xor(s, off, 64);
    if (lane == 0) U[g * 1024 + o] = s;
}

// ---------------- fused es/ed for BOTH directions of one layer ------------
__global__ void es_ed2_kernel(const float* __restrict__ xd, const float* __restrict__ xl,
                              const float* __restrict__ U1, const float* __restrict__ U2,
                              float* __restrict__ es1, float* __restrict__ ed1,
                              float* __restrict__ es2, float* __restrict__ ed2, int N)
{
    int t = blockIdx.x * blockDim.x + threadIdx.x;
    if (t >= N * 16) return;
    int n = t >> 4, j = t & 15;
    const float4* X4 = reinterpret_cast<const float4*>(((j < 8) ? xd : xl) + (size_t)n * 128);
    const float* U;
    float* dst;
    int col;
    if (j < 4)       { U = U1; col = j;      dst = &es1[n * 4 + j]; }
    else if (j < 8)  { U = U2; col = j;      dst = &ed2[n * 4 + (j - 4)]; }
    else if (j < 12) { U = U1; col = j - 4;  dst = &ed1[n * 4 + (j - 8)]; }
    else             { U = U2; col = j - 12; dst = &es2[n * 4 + (j - 12)]; }
    float s = 0.f;
#pragma unroll 8
    for (int k4 = 0; k4 < 32; ++k4) {
        float4 x = X4[k4];
        s = fmaf(x.x, U[(k4 * 4 + 0) * 8 + col], s);
        s = fmaf(x.y, U[(k4 * 4 + 1) * 8 + col], s);
        s = fmaf(x.z, U[(k4 * 4 + 2) * 8 + col], s);
        s = fmaf(x.w, U[(k4 * 4 + 3) * 8 + col], s);
    }
    *dst = s;
}

// ---------------- CSR build (stores src + dst node per slot) --------------
__global__ void deg_kernel(const int* __restrict__ s, const int* __restrict__ t,
                           int* __restrict__ deg_t, int* __restrict__ deg_s, int E)
{
    int i = blockIdx.x * blockDim.x + threadIdx.x;
    if (i >= E) return;
    atomicAdd(&deg_t[t[i]], 1);
    atomicAdd(&deg_s[s[i]], 1);
}

__global__ void scan_partial(const int* dA, const int* dB, int* eA, int* eB,
                             int* bsA, int* bsB, int N)
{
    __shared__ int lds[256];
    const int* deg = blockIdx.y ? dB : dA;
    int* ex = blockIdx.y ? eB : eA;
    int* bs = blockIdx.y ? bsB : bsA;
    int i = blockIdx.x * 256 + threadIdx.x;
    int v = (i < N) ? deg[i] : 0;
    int x = v;
    lds[threadIdx.x] = x;
    __syncthreads();
    for (int off = 1; off < 256; off <<= 1) {
        int tv = (threadIdx.x >= off) ? lds[threadIdx.x - off] : 0;
        __syncthreads();
        x += tv;
        lds[threadIdx.x] = x;
        __syncthreads();
    }
    if (i < N) ex[i] = x - v;
    if (threadIdx.x == 255) bs[blockIdx.x] = x;
}

__global__ void scan_bsums(int* bsA, int* bsB, int* boA, int* boB, int nb)
{
    __shared__ int lds[256];
    int* bs = blockIdx.y ? bsB : bsA;
    int* bo = blockIdx.y ? boB : boA;
    int v = (threadIdx.x < nb) ? bs[threadIdx.x] : 0;
    int x = v;
    lds[threadIdx.x] = x;
    __syncthreads();
    for (int off = 1; off < 256; off <<= 1) {
        int tv = (threadIdx.x >= off) ? lds[threadIdx.x - off] : 0;
        __syncthreads();
        x += tv;
        lds[threadIdx.x] = x;
        __syncthreads();
    }
    if (threadIdx.x < nb) bo[threadIdx.x] = x - v;
    if (threadIdx.x == 255) bo[nb] = x;
}

__global__ void scan_add(int* eA, int* eB, const int* boA, const int* boB, int N, int nb)
{
    int* ex = blockIdx.y ? eB : eA;
    const int* bo = blockIdx.y ? boB : boA;
    int i = blockIdx.x * 256 + threadIdx.x;
    if (i < N) ex[i] += bo[i >> 8];
    if (i == 0) ex[N] = bo[nb];
}

__global__ void fill_kernel(const int* __restrict__ s, const int* __restrict__ t,
                            const int* __restrict__ rpt_t, const int* __restrict__ rpt_s,
                            int* __restrict__ cur_t, int* __restrict__ cur_s,
                            int* __restrict__ col_t, int* __restrict__ col_s,
                            int* __restrict__ row_t, int* __restrict__ row_s, int E)
{
    int i = blockIdx.x * blockDim.x + threadIdx.x;
    if (i >= E) return;
    int sv = s[i], tv = t[i];
    int p = atomicAdd(&cur_t[tv], 1);
    int pos = rpt_t[tv] + p;
    col_t[pos] = sv; row_t[pos] = tv;
    p = atomicAdd(&cur_s[sv], 1);
    pos = rpt_s[sv] + p;
    col_s[pos] = tv; row_s[pos] = sv;
}

// ---------------- per-edge softmax weights (no-max, CSR order) ------------
__global__ __launch_bounds__(256) void edge_w_kernel(
    const int* __restrict__ col_t, const int* __restrict__ row_t,
    const int* __restrict__ col_s, const int* __restrict__ row_s,
    const float* __restrict__ es1, const float* __restrict__ ed1,
    const float* __restrict__ es2, const float* __restrict__ ed2,
    float* __restrict__ w_t, float* __restrict__ w_s, int E)
{
    int i = blockIdx.x * 256 + threadIdx.x;
    if (i >= E) return;
    const int* col; const int* row; const float* es; const float* ed; float* w;
    if (blockIdx.y == 0) { col = col_t; row = row_t; es = es1; ed = ed1; w = w_t; }
    else                 { col = col_s; row = row_s; es = es2; ed = ed2; w = w_s; }
    int sn = col[i], rn = row[i];
    float4 a = *reinterpret_cast<const float4*>(&es[(size_t)sn * 4]);
    float4 b = *reinterpret_cast<const float4*>(&ed[(size_t)rn * 4]);
    float v0 = a.x + b.x; v0 = v0 > 0.f ? v0 : 0.2f * v0;
    float v1 = a.y + b.y; v1 = v1 > 0.f ? v1 : 0.2f * v1;
    float v2 = a.z + b.z; v2 = v2 > 0.f ? v2 : 0.2f * v2;
    float v3 = a.w + b.w; v3 = v3 > 0.f ? v3 : 0.2f * v3;
    float4 o;
    o.x = __expf(v0); o.y = __expf(v1); o.z = __expf(v2); o.w = __expf(v3);
    *reinterpret_cast<float4*>(&w[(size_t)i * 4]) = o;
}

// ---------------- per-head x-aggregation (layers 1-2), w precomputed ------
__global__ __launch_bounds__(256) void agg_x(
    const int* __restrict__ rowptr, const int* __restrict__ cols,
    const float* __restrict__ wbuf,   // E x 4 (CSR order)
    const float* __restrict__ xsrc,   // Nsrc x 128 fp32
    u16* __restrict__ aggp,           // hi plane; lo at +Ndst*512
    int Ndst)
{
    int n = blockIdx.x * 4 + (threadIdx.x >> 6);
    if (n >= Ndst) return;
    int lane = threadIdx.x & 63;
    int beg = rowptr[n], end = rowptr[n + 1];

    float den0 = 0.f, den1 = 0.f, den2 = 0.f, den3 = 0.f;
    float2 acc[4] = {};

    for (int i = beg; i < end; ++i) {
        float4 w4 = *reinterpret_cast<const float4*>(&wbuf[(size_t)i * 4]);
        den0 += w4.x; den1 += w4.y; den2 += w4.z; den3 += w4.w;
        int sn = cols[i];
        float2 xv = *reinterpret_cast<const float2*>(&xsrc[(size_t)sn * 128 + 2 * lane]);
        acc[0].x = fmaf(w4.x, xv.x, acc[0].x); acc[0].y = fmaf(w4.x, xv.y, acc[0].y);
        acc[1].x = fmaf(w4.y, xv.x, acc[1].x); acc[1].y = fmaf(w4.y, xv.y, acc[1].y);
        acc[2].x = fmaf(w4.z, xv.x, acc[2].x); acc[2].y = fmaf(w4.z, xv.y, acc[2].y);
        acc[3].x = fmaf(w4.w, xv.x, acc[3].x); acc[3].y = fmaf(w4.w, xv.y, acc[3].y);
    }

    float inv[4] = {1.f / (den0 + 1e-16f), 1.f / (den1 + 1e-16f),
                    1.f / (den2 + 1e-16f), 1.f / (den3 + 1e-16f)};
    u16* lo = aggp + (size_t)Ndst * 512;
    size_t base = (size_t)n * 512 + 2 * lane;
#pragma unroll
    for (int h = 0; h < 4; ++h) {
        float v0 = acc[h].x * inv[h];
        float v1 = acc[h].y * inv[h];
        u16 h0 = f2bf(v0), h1 = f2bf(v1);
        *reinterpret_cast<unsigned*>(&aggp[base + h * 128]) =
            (unsigned)h0 | ((unsigned)h1 << 16);
        u16 l0 = f2bf(v0 - bfbits2f(h0)), l1 = f2bf(v1 - bfbits2f(h1));
        *reinterpret_cast<unsigned*>(&lo[base + h * 128]) =
            (unsigned)l0 | ((unsigned)l1 << 16);
    }
}

// ---------------- GAT aggregation for layer 3 (w precomputed) -------------
__global__ __launch_bounds__(256) void gat_agg128(
    const int* __restrict__ rowptr, const int* __restrict__ cols,
    const float* __restrict__ wbuf,
    const float* __restrict__ hs,     // Nsrc x 128
    const float* __restrict__ bias,   // 128
    float* __restrict__ out,          // Ndst x 32
    int Ndst)
{
    int n = blockIdx.x * 4 + (threadIdx.x >> 6);
    if (n >= Ndst) return;
    int lane = threadIdx.x & 63;
    int beg = rowptr[n], end = rowptr[n + 1];

    float den0 = 0.f, den1 = 0.f, den2 = 0.f, den3 = 0.f;
    float acc0 = 0.f, acc1 = 0.f;
    for (int i = beg; i < end; ++i) {
        float4 w4 = *reinterpret_cast<const float4*>(&wbuf[(size_t)i * 4]);
        den0 += w4.x; den1 += w4.y; den2 += w4.z; den3 += w4.w;
        int sn = cols[i];
        const float* hp = hs + (size_t)sn * 128;
        float wA = (lane < 32) ? w4.x : w4.y;
        float wB = (lane < 32) ? w4.z : w4.w;
        acc0 = fmaf(wA, hp[lane], acc0);
        acc1 = fmaf(wB, hp[64 + lane], acc1);
    }
    den0 += 1e-16f; den1 += 1e-16f; den2 += 1e-16f; den3 += 1e-16f;
    float d0 = lane < 32 ? den0 : den1;
    float d1 = lane < 32 ? den2 : den3;
    float v0 = fmaxf(acc0 / d0 + bias[lane], 0.f);
    float v1 = fmaxf(acc1 / d1 + bias[64 + lane], 0.f);
    float sum = v0 + __shfl_xor(v0, 32, 64) + v1 + __shfl_xor(v1, 32, 64);
    if (lane < 32) out[(size_t)n * 32 + lane] = 0.25f * sum;
}

// ---------------- per-node classifier tables (penalty folded in) ----------
__global__ __launch_bounds__(256) void fc1_halves_kernel(
    const float* __restrict__ xd, const float* __restrict__ xl,
    const float* __restrict__ fc1W,
    const float* __restrict__ penWd, const float* __restrict__ penbd,
    const float* __restrict__ penWl, const float* __restrict__ penbl,
    float* __restrict__ Ad, float* __restrict__ Bl, int N)
{
    int wid = (blockIdx.x * 256 + threadIdx.x) >> 6;
    if (wid >= 2 * N) return;
    int lane = threadIdx.x & 63;
    bool isl = wid >= N;
    int n = isl ? wid - N : wid;
    const float* x = (isl ? xl : xd) + (size_t)n * 32;
    const float* pW = isl ? penWl : penWd;
    float pb = isl ? penbl[0] : penbd[0];

    float pp = x[lane & 31] * pW[lane & 31];
    pp += __shfl_xor(pp, 1, 64);
    pp += __shfl_xor(pp, 2, 64);
    pp += __shfl_xor(pp, 4, 64);
    pp += __shfl_xor(pp, 8, 64);
    pp += __shfl_xor(pp, 16, 64);
    float s = expf(pp + pb);

    const float* W = fc1W + (isl ? 32 * 64 : 0);
    float acc = 0.f;
#pragma unroll
    for (int k = 0; k < 32; ++k)
        acc = fmaf(x[k], W[k * 64 + lane], acc);
    (isl ? Bl : Ad)[(size_t)n * 64 + lane] = s * acc;
}

// ---------------- link classifier: table gather + reduce ------------------
__global__ __launch_bounds__(256) void link_kernel(
    const float* __restrict__ Ad, const float* __restrict__ Bl,
    const int* __restrict__ eli,
    const float* __restrict__ fc1b, const float* __restrict__ fc2W,
    const float* __restrict__ fc2b,
    float* __restrict__ out, int EL)
{
    int wid = (blockIdx.x * 256 + threadIdx.x) >> 6;
    if (wid >= EL) return;
    int lane = threadIdx.x & 63;
    int e0 = eli[wid];
    int e1 = eli[EL + wid];
    float v = Ad[(size_t)e0 * 64 + lane] + Bl[(size_t)e1 * 64 + lane] + fc1b[lane];
    v = fmaxf(v, 0.f);
    float p = v * fc2W[lane];
#pragma unroll
    for (int off = 32; off >= 1; off >>= 1) p += __shfl_xor(p, off, 64);
    if (lane == 0) out[wid] = p + fc2b[0];
}

// ---------------------------------------------------------------------------
extern "C" void kernel_launch(void* const* d_in, const int* in_sizes, int n_in,
                              void* d_out, int out_size, void* d_ws, size_t ws_size,
                              hipStream_t stream)
{
    const int N  = in_sizes[6] / 128;
    const int Kd = in_sizes[2] / 128;   // 412
    const int Kl = in_sizes[4] / 128;   // 240
    const int KdP = (Kd + 31) & ~31;    // 416
    const int KlP = (Kl + 31) & ~31;    // 256
    const int E  = in_sizes[48] / 2;
    const int EL = in_sizes[49] / 2;

    const float* x_d    = (const float*)d_in[0];
    const float* x_l    = (const float*)d_in[1];
    const float* Wd_lin = (const float*)d_in[2];
    const float* bd_lin = (const float*)d_in[3];
    const float* Wl_lin = (const float*)d_in[4];
    const float* bl_lin = (const float*)d_in[5];
    const float* emb_d  = (const float*)d_in[6];
    const float* emb_l  = (const float*)d_in[7];

    const float *gWs[6], *gWd[6], *gas[6], *gad[6], *gb[6];
    for (int g = 0; g < 6; ++g) {
        gWs[g] = (const float*)d_in[8 + 5 * g + 0];
        gWd[g] = (const float*)d_in[8 + 5 * g + 1];
        gas[g] = (const float*)d_in[8 + 5 * g + 2];
        gad[g] = (const float*)d_in[8 + 5 * g + 3];
        gb[g]  = (const float*)d_in[8 + 5 * g + 4];
    }
    const float* pen_Wd = (const float*)d_in[38];
    const float* pen_bd = (const float*)d_in[39];
    const float* pen_Wl = (const float*)d_in[40];
    const float* pen_bl = (const float*)d_in[41];
    const float* fc1W   = (const float*)d_in[42];
    const float* fc1b   = (const float*)d_in[43];
    const float* fc2W   = (const float*)d_in[44];
    const float* fc2b   = (const float*)d_in[45];
    const int* node_id_d = (const int*)d_in[46];
    const int* node_id_l = (const int*)d_in[47];
    const int* ei  = (const int*)d_in[48];
    const int* eli = (const int*)d_in[49];
    const int* s_arr = ei;
    const int* t_arr = ei + E;

    // ---- workspace carve-up ----
    char* ws = (char*)d_ws;
    size_t off = 0;
    auto alloc = [&](size_t bytes) -> char* {
        char* p = ws + off;
        off = (off + bytes + 255) & ~(size_t)255;
        return p;
    };
    float* bufd0 = (float*)alloc((size_t)N * 128 * 4);
    float* bufd1 = (float*)alloc((size_t)N * 128 * 4);
    float* bufl0 = (float*)alloc((size_t)N * 128 * 4);
    float* bufl1 = (float*)alloc((size_t)N * 128 * 4);
    // region1 (N*2048 B): input-d planes | agg planes (2 x N*512 u16) | hs (N*128 f32)
    char* region1 = alloc((size_t)N * 512 * 4);
    u16* pxd_in = (u16*)region1;
    u16* aggp   = (u16*)region1;
    float* hs   = (float*)region1;
    // region2 (N*1024 B): input-l planes | layer-3 feature planes
    char* region2 = alloc((size_t)N * 1024);
    u16* pxl_in = (u16*)region2;
    u16* pxd = (u16*)region2;
    u16* pxl = (u16*)(region2 + (size_t)N * 512);
    // weight planes
    u16* btWd = (u16*)alloc((size_t)2 * 128 * KdP * 2);
    u16* btWl = (u16*)alloc((size_t)2 * 128 * KlP * 2);
    u16* btWs[6];
    for (int g = 0; g < 6; ++g) {
        int J = (g < 4) ? 512 : 128;
        btWs[g] = (u16*)alloc((size_t)2 * J * 128 * 2);
    }
    float* es1  = (float*)alloc((size_t)N * 4 * 4);
    float* ed1  = (float*)alloc((size_t)N * 4 * 4);
    float* es2  = (float*)alloc((size_t)N * 4 * 4);
    float* ed2  = (float*)alloc((size_t)N * 4 * 4);
    float* Uall = (float*)alloc((size_t)6 * 1024 * 4);
    int* rpt_t = (int*)alloc((size_t)(N + 1) * 4);
    int* rpt_s = (int*)alloc((size_t)(N + 1) * 4);
    int* deg_t = (int*)alloc((size_t)N * 4);
    int* deg_s = (int*)alloc((size_t)N * 4);
    int* cur_t = (int*)alloc((size_t)N * 4);
    int* cur_s = (int*)alloc((size_t)N * 4);
    int* col_t = (int*)alloc((size_t)E * 4);
    int* col_s = (int*)alloc((size_t)E * 4);
    int* row_t = (int*)alloc((size_t)E * 4);
    int* row_s = (int*)alloc((size_t)E * 4);
    float* w_t = (float*)alloc((size_t)E * 4 * 4);
    float* w_s = (float*)alloc((size_t)E * 4 * 4);
    int* bs_t  = (int*)alloc(256 * 4);
    int* bs_s  = (int*)alloc(256 * 4);
    int* bo_t  = (int*)alloc(257 * 4);
    int* bo_s  = (int*)alloc(257 * 4);
    float* Ad  = (float*)alloc((size_t)N * 64 * 4);
    float* Bl  = (float*)alloc((size_t)N * 64 * 4);
    (void)ws_size;

    hipMemsetAsync(deg_t, 0, (size_t)N * 4, stream);
    hipMemsetAsync(deg_s, 0, (size_t)N * 4, stream);
    hipMemsetAsync(cur_t, 0, (size_t)N * 4, stream);
    hipMemsetAsync(cur_s, 0, (size_t)N * 4, stream);

    dim3 blk(256);
    const int nMB = (N + 63) / 64;        // BM=64 grid
    const int nEB = (E + 255) / 256;

    // ---- input splits (planes) ----
    splitX<<<dim3((N * (KdP >> 2) + 255) / 256), blk, 0, stream>>>(x_d, N, Kd, KdP, pxd_in);
    splitX<<<dim3((N * (KlP >> 2) + 255) / 256), blk, 0, stream>>>(x_l, N, Kl, KlP, pxl_in);
    splitBt<<<dim3((128 * KdP + 255) / 256), blk, 0, stream>>>(Wd_lin, Kd, KdP, 128, btWd);
    splitBt<<<dim3((128 * KlP + 255) / 256), blk, 0, stream>>>(Wl_lin, Kl, KlP, 128, btWl);
    for (int g = 0; g < 6; ++g) {
        int J = (g < 4) ? 512 : 128;
        splitBt<<<dim3((J * 128 + 255) / 256), blk, 0, stream>>>(gWs[g], 128, 128, J, btWs[g]);
    }

    {
        UParams up;
        for (int g = 0; g < 6; ++g) {
            up.Ws[g] = gWs[g]; up.Wd[g] = gWd[g];
            up.as_[g] = gas[g]; up.ad_[g] = gad[g];
            up.C[g] = (g < 4) ? 128 : 32;
        }
        compute_U<<<dim3(1536), blk, 0, stream>>>(up, Uall);
    }

    // CSR for both directions
    {
        deg_kernel<<<dim3(nEB), blk, 0, stream>>>(s_arr, t_arr, deg_t, deg_s, E);
        int nb = (N + 255) / 256;
        scan_partial<<<dim3(nb, 2), blk, 0, stream>>>(deg_t, deg_s, rpt_t, rpt_s, bs_t, bs_s, N);
        scan_bsums<<<dim3(1, 2), blk, 0, stream>>>(bs_t, bs_s, bo_t, bo_s, nb);
        scan_add<<<dim3(nb, 2), blk, 0, stream>>>(rpt_t, rpt_s, bo_t, bo_s, N, nb);
        fill_kernel<<<dim3(nEB), blk, 0, stream>>>(s_arr, t_arr, rpt_t, rpt_s,
                                                   cur_t, cur_s, col_t, col_s,
                                                   row_t, row_s, E);
    }

    // ---- input linears (+bias +embedding gather) ----
    gemm_mfma<true><<<dim3(nMB, 1), blk, 0, stream>>>(
        pxd_in, btWd, bd_lin, emb_d, node_id_d, bufd0, N, KdP, 128);
    gemm_mfma<true><<<dim3(nMB, 1), blk, 0, stream>>>(
        pxl_in, btWl, bl_lin, emb_l, node_id_l, bufl0, N, KlP, 128);

    float* xd_cur = bufd0; float* xl_cur = bufl0;
    float* xd_nxt = bufd1; float* xl_nxt = bufl1;

    // ---- layers 1-2: commuted path (aggregate x, then head-GEMM) ----
    for (int L = 0; L < 2; ++L) {
        const int gd = 2 * L, gl = 2 * L + 1;

        es_ed2_kernel<<<dim3((N * 16 + 255) / 256), blk, 0, stream>>>(
            xd_cur, xl_cur, Uall + gd * 1024, Uall + gl * 1024,
            es1, ed1, es2, ed2, N);
        edge_w_kernel<<<dim3(nEB, 2), blk, 0, stream>>>(
            col_t, row_t, col_s, row_s, es1, ed1, es2, ed2, w_t, w_s, E);

        agg_x<<<dim3((N + 3) / 4), blk, 0, stream>>>(
            rpt_t, col_t, w_t, xd_cur, aggp, N);
        gemm_heads<<<dim3(nMB), blk, 0, stream>>>(
            aggp, btWs[gd], gb[gd], xl_nxt, N);

        agg_x<<<dim3((N + 3) / 4), blk, 0, stream>>>(
            rpt_s, col_s, w_s, xl_cur, aggp, N);
        gemm_heads<<<dim3(nMB), blk, 0, stream>>>(
            aggp, btWs[gl], gb[gl], xd_nxt, N);

        float* tmp;
        tmp = xd_cur; xd_cur = xd_nxt; xd_nxt = tmp;
        tmp = xl_cur; xl_cur = xl_nxt; xl_nxt = tmp;
    }

    // ---- layer 3: direct path (hs is only N x 128) ----
    {
        const int gd = 4, gl = 5;
        splitX<<<dim3((N * 32 + 255) / 256), blk, 0, stream>>>(xd_cur, N, 128, 128, pxd);
        splitX<<<dim3((N * 32 + 255) / 256), blk, 0, stream>>>(xl_cur, N, 128, 128, pxl);

        es_ed2_kernel<<<dim3((N * 16 + 255) / 256), blk, 0, stream>>>(
            xd_cur, xl_cur, Uall + gd * 1024, Uall + gl * 1024,
            es1, ed1, es2, ed2, N);
        edge_w_kernel<<<dim3(nEB, 2), blk, 0, stream>>>(
            col_t, row_t, col_s, row_s, es1, ed1, es2, ed2, w_t, w_s, E);

        gemm_mfma<false><<<dim3(nMB, 1), blk, 0, stream>>>(
            pxd, btWs[gd], nullptr, nullptr, nullptr, hs, N, 128, 128);
        gat_agg128<<<dim3((N + 3) / 4), blk, 0, stream>>>(
            rpt_t, col_t, w_t, hs, gb[gd], xl_nxt, N);

        gemm_mfma<false><<<dim3(nMB, 1), blk, 0, stream>>>(
            pxl, btWs[gl], nullptr, nullptr, nullptr, hs, N, 128, 128);
        gat_agg128<<<dim3((N + 3) / 4), blk, 0, stream>>>(
            rpt_s, col_s, w_s, hs, gb[gl], xd_nxt, N);

        float* tmp;
        tmp = xd_cur; xd_cur = xd_nxt; xd_nxt = tmp;
        tmp = xl_cur; xl_cur = xl_nxt; xl_nxt = tmp;
    }

    // classifier: per-node tables (penalty folded), then per-edge gather
    fc1_halves_kernel<<<dim3((2 * N * 64 + 255) / 256), blk, 0, stream>>>(
        xd_cur, xl_cur, fc1W, pen_Wd, pen_bd, pen_Wl, pen_bl, Ad, Bl, N);
    link_kernel<<<dim3((EL + 3) / 4), blk, 0, stream>>>(
        Ad, Bl, eli, fc1b, fc2W, fc2b, (float*)d_out, EL);
}